// Round 2
// baseline (5006.858 us; speedup 1.0000x reference)
//
#include <hip/hip_runtime.h>

#define DEVINL static __device__ __forceinline__

namespace {

constexpr int NV = 100000;   // variables
constexpr int NC = 50000;    // constraints
constexpr int NK = 20000;    // cuts
constexpr int EVC = 800000;  // var-cons edges
constexpr int EVK = 200000;  // var-cut edges
constexpr int R_TOT = NC + NV + NK + NV;  // 270000 CSR rows (cons | var<-vc | cut | var<-vk)
constexpr int SCAN_CHUNK = 2048;
constexpr int SCAN_NB = (R_TOT + SCAN_CHUNK - 1) / SCAN_CHUNK;  // 132

DEVINL float wave_sum(float v) {
#pragma unroll
  for (int off = 32; off > 0; off >>= 1) v += __shfl_xor(v, off, 64);
  return v;
}

DEVINL float sigmoid_f(float x) { return 1.0f / (1.0f + __expf(-x)); }

// ---- lane=node dense kernels: each lane owns one node, 64 output channels in
// ---- acc[64] VGPRs; weights are wave-uniform -> scalar loads (K$, free pipe).
// ---- K consumed in reg-resident chunks of 16 (no dynamic VGPR indexing).

DEVINL void load_chunk16(const float* __restrict__ p, float* x) {
  const float4* p4 = reinterpret_cast<const float4*>(p);
#pragma unroll
  for (int q = 0; q < 4; ++q) {
    const float4 v = p4[q];
    x[4 * q + 0] = v.x; x[4 * q + 1] = v.y;
    x[4 * q + 2] = v.z; x[4 * q + 3] = v.w;
  }
}

DEVINL void store_row64(float* __restrict__ p, const float* x) {
  float4* p4 = reinterpret_cast<float4*>(p);
#pragma unroll
  for (int q = 0; q < 16; ++q) {
    float4 v;
    v.x = x[4 * q + 0]; v.y = x[4 * q + 1];
    v.z = x[4 * q + 2]; v.w = x[4 * q + 3];
    p4[q] = v;
  }
}

// acc[c] += sum over one K=64 input row (chunked)
DEVINL void gemv_accum64(const float* __restrict__ xrow,
                         const float* __restrict__ W,  // [64][64], row-major
                         float* acc) {
  for (int kc = 0; kc < 4; ++kc) {  // dynamic loop: only memory is indexed
    float x[16];
    load_chunk16(xrow + kc * 16, x);
#pragma unroll
    for (int k = 0; k < 16; ++k) {
      const float xk = x[k];
      const float* wr = W + (kc * 16 + k) * 64;  // wave-uniform -> s_load
#pragma unroll
      for (int c = 0; c < 64; ++c) acc[c] = fmaf(xk, wr[c], acc[c]);
    }
  }
}

// ---------- fused 2-layer node MLP: OUT = relu(X@W1+B1)@W2+B2 ----------
template <int DIN>
__global__ void __launch_bounds__(256) mlp2_node_k(
    const float* __restrict__ X, const float* __restrict__ W1,
    const float* __restrict__ B1, const float* __restrict__ W2,
    const float* __restrict__ B2, float* __restrict__ OUT, int N) {
  const int n = blockIdx.x * 256 + threadIdx.x;
  if (n >= N) return;
  float h[64];
#pragma unroll
  for (int c = 0; c < 64; ++c) h[c] = B1[c];
  if constexpr (DIN == 64) {
    gemv_accum64(X + (size_t)n * 64, W1, h);
  } else {
    float x[DIN];
#pragma unroll
    for (int k = 0; k < DIN; ++k) x[k] = X[(size_t)n * DIN + k];
#pragma unroll
    for (int k = 0; k < DIN; ++k) {
      const float xk = x[k];
      const float* wr = W1 + k * 64;
#pragma unroll
      for (int c = 0; c < 64; ++c) h[c] = fmaf(xk, wr[c], h[c]);
    }
  }
#pragma unroll
  for (int c = 0; c < 64; ++c) h[c] = fmaxf(h[c], 0.0f);

  float o[64];
#pragma unroll
  for (int c = 0; c < 64; ++c) o[c] = B2[c];
  // layer 2: h is in regs; chunk over k with static indices
#pragma unroll 1
  for (int kc = 0; kc < 4; ++kc) {
#pragma unroll
    for (int k = 0; k < 16; ++k) {
      // static index into h via kc*16+k requires full unroll of kc; instead
      // fold: process all 64 k statically (h fully unrolled, 4096 FMA total)
    }
  }
#pragma unroll
  for (int k = 0; k < 64; ++k) {
    const float hk = h[k];
    const float* wr = W2 + k * 64;
#pragma unroll
    for (int c = 0; c < 64; ++c) o[c] = fmaf(hk, wr[c], o[c]);
  }
  store_row64(OUT + (size_t)n * 64, o);
}

// ---------- single-layer GEMV, no bias/act: OUT = X@W (K=64) ----------
__global__ void __launch_bounds__(256) gemv64_k(
    const float* __restrict__ X, const float* __restrict__ W,
    float* __restrict__ OUT, int N) {
  const int n = blockIdx.x * 256 + threadIdx.x;
  if (n >= N) return;
  float acc[64];
#pragma unroll
  for (int c = 0; c < 64; ++c) acc[c] = 0.0f;
  gemv_accum64(X + (size_t)n * 64, W, acc);
  store_row64(OUT + (size_t)n * 64, acc);
}

// ---------- K=128 GEMV over concat([X1,X2]): gate (sigmoid) / upd1 (relu) ----------
template <int ACT>  // 1 = relu, 2 = sigmoid
__global__ void __launch_bounds__(256) gemv128_k(
    const float* __restrict__ X1, const float* __restrict__ X2,
    const float* __restrict__ W, const float* __restrict__ B,
    float* __restrict__ OUT, int N) {
  const int n = blockIdx.x * 256 + threadIdx.x;
  if (n >= N) return;
  float acc[64];
#pragma unroll
  for (int c = 0; c < 64; ++c) acc[c] = B[c];
  gemv_accum64(X1 + (size_t)n * 64, W, acc);
  gemv_accum64(X2 + (size_t)n * 64, W + 64 * 64, acc);
#pragma unroll
  for (int c = 0; c < 64; ++c) {
    if (ACT == 1) acc[c] = fmaxf(acc[c], 0.0f);
    if (ACT == 2) acc[c] = sigmoid_f(acc[c]);
  }
  store_row64(OUT + (size_t)n * 64, acc);
}

// ---------- upd2 + gate-mix + LayerNorm (lane-local, fused epilogue) ----------
__global__ void __launch_bounds__(256) upd2fin_k(
    const float* __restrict__ UH, const float* __restrict__ W2,
    const float* __restrict__ B2, const float* __restrict__ GATE,
    const float* __restrict__ NODE, const float* __restrict__ LNG,
    const float* __restrict__ LNB, float* __restrict__ OUT, int N) {
  const int n = blockIdx.x * 256 + threadIdx.x;
  if (n >= N) return;
  float o[64];
#pragma unroll
  for (int c = 0; c < 64; ++c) o[c] = B2[c];
  gemv_accum64(UH + (size_t)n * 64, W2, o);

  // gate mix, chunk-wise loads of gate and node rows
  const float4* g4 = reinterpret_cast<const float4*>(GATE + (size_t)n * 64);
  const float4* nd4 = reinterpret_cast<const float4*>(NODE + (size_t)n * 64);
#pragma unroll
  for (int q = 0; q < 16; ++q) {
    const float4 g = g4[q];
    const float4 nd = nd4[q];
    o[4 * q + 0] = fmaf(g.x, o[4 * q + 0] - nd.x, nd.x);
    o[4 * q + 1] = fmaf(g.y, o[4 * q + 1] - nd.y, nd.y);
    o[4 * q + 2] = fmaf(g.z, o[4 * q + 2] - nd.z, nd.z);
    o[4 * q + 3] = fmaf(g.w, o[4 * q + 3] - nd.w, nd.w);
  }

  // LayerNorm across the 64 channels -- all in-lane
  float s1 = 0.0f, s2 = 0.0f;
#pragma unroll
  for (int c = 0; c < 64; ++c) { s1 += o[c]; s2 = fmaf(o[c], o[c], s2); }
  const float m = s1 * (1.0f / 64.0f);
  const float var = s2 * (1.0f / 64.0f) - m * m;
  const float r = rsqrtf(var + 1e-3f);
#pragma unroll
  for (int c = 0; c < 64; ++c) o[c] = fmaf((o[c] - m) * r, LNG[c], LNB[c]);
  store_row64(OUT + (size_t)n * 64, o);
}

// ---------- factorized edge weight: sigmoid(relu(pa[s]+pb[d]+ef@W1c+b1)@w2+b2) ----------
__global__ void __launch_bounds__(256) edgew_k(
    const int* __restrict__ S, const int* __restrict__ D,
    const float* __restrict__ EFX, const float* __restrict__ PA,
    const float* __restrict__ PB, const float* __restrict__ W1C,
    const float* __restrict__ B1, const float* __restrict__ W2,
    const float* __restrict__ B2, float* __restrict__ EW, int E) {
  const int j = threadIdx.x & 63;
  const int e = blockIdx.x * 4 + (threadIdx.x >> 6);
  if (e >= E) return;
  float wc[8];
#pragma unroll
  for (int i = 0; i < 8; ++i) wc[i] = W1C[i * 64 + j];
  const int s = S[e], d = D[e];
  float h = PA[s * 64 + j] + PB[d * 64 + j] + B1[j];
  const float efv = (j < 8) ? EFX[e * 8 + j] : 0.0f;
#pragma unroll
  for (int i = 0; i < 8; ++i) {
    const float ef_i =
        __int_as_float(__builtin_amdgcn_readlane(__float_as_int(efv), i));
    h = fmaf(ef_i, wc[i], h);
  }
  h = fmaxf(h, 0.0f);
  const float t = wave_sum(h * W2[j]);
  if (j == 0) EW[e] = sigmoid_f(t + B2[0]);
}

// ---------- CSR aggregation: agg[n] = sum(msg[nbr]*w) / max(sum w, 1) ----------
__global__ void __launch_bounds__(256) agg_k(
    const int* __restrict__ row_ptr, const int* __restrict__ nbr,
    const float* __restrict__ val, const float* __restrict__ MSG,
    float* __restrict__ AGG, int base, int N) {
  const int j = threadIdx.x & 63;
  const int n = blockIdx.x * 4 + (threadIdx.x >> 6);
  if (n >= N) return;
  const int s = row_ptr[base + n], e = row_ptr[base + n + 1];
  float acc = 0.0f, deg = 0.0f;
  for (int p = s; p < e; ++p) {
    const int nb = nbr[p];
    const float w = val[p];
    acc = fmaf(MSG[(size_t)nb * 64 + j], w, acc);
    deg += w;
  }
  AGG[(size_t)n * 64 + j] = acc / fmaxf(deg, 1.0f);
}

// ---------- CSR build: count, scan, fill ----------
__global__ void __launch_bounds__(256) count_k(
    const int* __restrict__ S, const int* __restrict__ D,
    int* __restrict__ counts, int baseD, int baseS, int E) {
  const int e = blockIdx.x * 256 + threadIdx.x;
  if (e >= E) return;
  atomicAdd(&counts[baseD + D[e]], 1);
  atomicAdd(&counts[baseS + S[e]], 1);
}

__global__ void __launch_bounds__(256) fill_k(
    const int* __restrict__ S, const int* __restrict__ D,
    const float* __restrict__ EW, int* __restrict__ cursor,
    int* __restrict__ nbr, float* __restrict__ val,
    int baseD, int baseS, int E) {
  const int e = blockIdx.x * 256 + threadIdx.x;
  if (e >= E) return;
  const int s = S[e], d = D[e];
  const float w = EW[e];
  int p = atomicAdd(&cursor[baseD + d], 1);
  nbr[p] = s;
  val[p] = w;
  p = atomicAdd(&cursor[baseS + s], 1);
  nbr[p] = d;
  val[p] = w;
}

__global__ void __launch_bounds__(256) scan1_k(const int* __restrict__ in,
                                               int* __restrict__ bsum) {
  __shared__ int sd[256];
  const int t = threadIdx.x;
  const int base = blockIdx.x * SCAN_CHUNK + t * 8;
  int s = 0;
#pragma unroll
  for (int i = 0; i < 8; ++i) {
    const int idx = base + i;
    s += (idx < R_TOT) ? in[idx] : 0;
  }
  sd[t] = s;
  __syncthreads();
  for (int off = 128; off > 0; off >>= 1) {
    if (t < off) sd[t] += sd[t + off];
    __syncthreads();
  }
  if (t == 0) bsum[blockIdx.x] = sd[0];
}

__global__ void __launch_bounds__(256) scan2_k(int* __restrict__ bsum,
                                               int* __restrict__ row_ptr) {
  __shared__ int sd[256];
  const int t = threadIdx.x;
  const int v = (t < SCAN_NB) ? bsum[t] : 0;
  sd[t] = v;
  __syncthreads();
  for (int off = 1; off < 256; off <<= 1) {
    const int add = (t >= off) ? sd[t - off] : 0;
    __syncthreads();
    sd[t] += add;
    __syncthreads();
  }
  if (t < SCAN_NB) bsum[t] = sd[t] - v;  // exclusive block offsets
  if (t == 255) row_ptr[R_TOT] = sd[255];
}

__global__ void __launch_bounds__(256) scan3_k(const int* __restrict__ in,
                                               const int* __restrict__ bsum,
                                               int* __restrict__ out) {
  __shared__ int sd[256];
  const int t = threadIdx.x;
  const int base = blockIdx.x * SCAN_CHUNK + t * 8;
  int loc[8];
  int s = 0;
#pragma unroll
  for (int i = 0; i < 8; ++i) {
    loc[i] = s;
    const int idx = base + i;
    s += (idx < R_TOT) ? in[idx] : 0;
  }
  sd[t] = s;
  __syncthreads();
  const int v = s;
  for (int off = 1; off < 256; off <<= 1) {
    const int add = (t >= off) ? sd[t - off] : 0;
    __syncthreads();
    sd[t] += add;
    __syncthreads();
  }
  const int off0 = bsum[blockIdx.x] + (sd[t] - v);
#pragma unroll
  for (int i = 0; i < 8; ++i) {
    const int idx = base + i;
    if (idx < R_TOT) out[idx] = off0 + loc[i];
  }
}

}  // namespace

extern "C" void kernel_launch(void* const* d_in, const int* in_sizes, int n_in,
                              void* d_out, int out_size, void* d_ws, size_t ws_size,
                              hipStream_t stream) {
  (void)in_sizes; (void)n_in; (void)out_size; (void)ws_size;

  // ---- inputs (setup_inputs dict order) ----
  const float* variable_features   = (const float*)d_in[0];
  const float* constraint_features = (const float*)d_in[1];
  const float* cut_features        = (const float*)d_in[2];
  const float* vc_ef = (const float*)d_in[3];
  const float* vk_ef = (const float*)d_in[4];
  const int* vc_edges = (const int*)d_in[5];
  const int* vk_edges = (const int*)d_in[6];
  const int *vc_s = vc_edges, *vc_d = vc_edges + EVC;
  const int *vk_s = vk_edges, *vk_d = vk_edges + EVK;
  const float* var_w1  = (const float*)d_in[7];
  const float* var_b1  = (const float*)d_in[8];
  const float* var_w2  = (const float*)d_in[9];
  const float* var_b2  = (const float*)d_in[10];
  const float* cons_w1 = (const float*)d_in[11];
  const float* cons_b1 = (const float*)d_in[12];
  const float* cons_w2 = (const float*)d_in[13];
  const float* cons_b2 = (const float*)d_in[14];
  const float* cut_w1  = (const float*)d_in[15];
  const float* cut_b1  = (const float*)d_in[16];
  const float* cut_w2  = (const float*)d_in[17];
  const float* cut_b2  = (const float*)d_in[18];
  const float* ewvc_w1 = (const float*)d_in[19];
  const float* ewvc_b1 = (const float*)d_in[20];
  const float* ewvc_w2 = (const float*)d_in[21];
  const float* ewvc_b2 = (const float*)d_in[22];
  const float* ewvk_w1 = (const float*)d_in[23];
  const float* ewvk_b1 = (const float*)d_in[24];
  const float* ewvk_w2 = (const float*)d_in[25];
  const float* ewvk_b2 = (const float*)d_in[26];
  const float* mp_msg_w1 = (const float*)d_in[27];
  const float* mp_msg_b1 = (const float*)d_in[28];
  const float* mp_msg_w2 = (const float*)d_in[29];
  const float* mp_msg_b2 = (const float*)d_in[30];
  const float* mp_gate_w = (const float*)d_in[31];
  const float* mp_gate_b = (const float*)d_in[32];
  const float* mp_upd_w1 = (const float*)d_in[33];
  const float* mp_upd_b1 = (const float*)d_in[34];
  const float* mp_upd_w2 = (const float*)d_in[35];
  const float* mp_upd_b2 = (const float*)d_in[36];
  const float* mp_ln_g   = (const float*)d_in[37];
  const float* mp_ln_b   = (const float*)d_in[38];

  // ---- workspace carve ----
  char* wp = (char*)d_ws;
  auto take = [&](size_t nbytes) {
    char* p = wp;
    wp += (nbytes + 255) & ~(size_t)255;
    return p;
  };
  float* h_var  = (float*)take((size_t)NV * 64 * 4);
  float* h_cons = (float*)take((size_t)NC * 64 * 4);
  float* h_cut  = (float*)take((size_t)NK * 64 * 4);
  float* bufA = (float*)take((size_t)NV * 64 * 4);  // pa | msg
  float* bufB = (float*)take((size_t)NV * 64 * 4);  // pb | agg
  float* bufC = (float*)take((size_t)NV * 64 * 4);  // qa | gate
  float* bufD = (float*)take((size_t)NV * 64 * 4);  // qb | uh
  float* ew_vc = (float*)take((size_t)EVC * 4);
  float* ew_vk = (float*)take((size_t)EVK * 4);
  int* row_ptr = (int*)take((size_t)(R_TOT + 1) * 4);
  int* cursor  = (int*)take((size_t)R_TOT * 4);
  int* counts  = (int*)take((size_t)R_TOT * 4);
  int* bsum    = (int*)take(256 * 4);
  int* nbr     = (int*)take((size_t)(2 * EVC + 2 * EVK) * 4);
  float* val   = (float*)take((size_t)(2 * EVC + 2 * EVK) * 4);

  // ---- CSR counts + scan ----
  hipMemsetAsync(counts, 0, (size_t)R_TOT * 4, stream);
  count_k<<<(EVC + 255) / 256, 256, 0, stream>>>(vc_s, vc_d, counts, 0, NC, EVC);
  count_k<<<(EVK + 255) / 256, 256, 0, stream>>>(vk_s, vk_d, counts, NC + NV,
                                                 NC + NV + NK, EVK);
  scan1_k<<<SCAN_NB, 256, 0, stream>>>(counts, bsum);
  scan2_k<<<1, 256, 0, stream>>>(bsum, row_ptr);
  scan3_k<<<SCAN_NB, 256, 0, stream>>>(counts, bsum, row_ptr);

  // ---- embeddings ----
  mlp2_node_k<19><<<(NV + 255) / 256, 256, 0, stream>>>(
      variable_features, var_w1, var_b1, var_w2, var_b2, h_var, NV);
  mlp2_node_k<5><<<(NC + 255) / 256, 256, 0, stream>>>(
      constraint_features, cons_w1, cons_b1, cons_w2, cons_b2, h_cons, NC);
  mlp2_node_k<30><<<(NK + 255) / 256, 256, 0, stream>>>(
      cut_features, cut_w1, cut_b1, cut_w2, cut_b2, h_cut, NK);

  // ---- edge weights: factorized per-node terms then per-edge combine ----
  gemv64_k<<<(NV + 255) / 256, 256, 0, stream>>>(h_var, ewvc_w1, bufA, NV);
  gemv64_k<<<(NC + 255) / 256, 256, 0, stream>>>(h_cons, ewvc_w1 + 64 * 64, bufB, NC);
  gemv64_k<<<(NV + 255) / 256, 256, 0, stream>>>(h_var, ewvk_w1, bufC, NV);
  gemv64_k<<<(NK + 255) / 256, 256, 0, stream>>>(h_cut, ewvk_w1 + 64 * 64, bufD, NK);
  edgew_k<<<EVC / 4, 256, 0, stream>>>(vc_s, vc_d, vc_ef, bufA, bufB,
                                       ewvc_w1 + 128 * 64, ewvc_b1, ewvc_w2,
                                       ewvc_b2, ew_vc, EVC);
  edgew_k<<<EVK / 4, 256, 0, stream>>>(vk_s, vk_d, vk_ef, bufC, bufD,
                                       ewvk_w1 + 128 * 64, ewvk_b1, ewvk_w2,
                                       ewvk_b2, ew_vk, EVK);

  // ---- CSR fill (stores edge weight as CSR value) ----
  hipMemcpyAsync(cursor, row_ptr, (size_t)R_TOT * 4, hipMemcpyDeviceToDevice, stream);
  fill_k<<<(EVC + 255) / 256, 256, 0, stream>>>(vc_s, vc_d, ew_vc, cursor, nbr,
                                                val, 0, NC, EVC);
  fill_k<<<(EVK + 255) / 256, 256, 0, stream>>>(vk_s, vk_d, ew_vk, cursor, nbr,
                                                val, NC + NV, NC + NV + NK, EVK);

  // ---- 15 message passes (16th only updates h_var -> dead, skipped) ----
  float* msgb = bufA;
  float* aggb = bufB;
  float* gateb = bufC;
  float* uhb = bufD;
  const float* neigh_t[4] = {h_var, h_cons, h_var, h_cut};
  float* node_t[4] = {h_cons, h_var, h_cut, h_var};
  const int Nn_t[4] = {NV, NC, NV, NK};
  const int Nd_t[4] = {NC, NV, NK, NV};
  const int base_t[4] = {0, NC, NC + NV, NC + NV + NK};

  for (int i = 0; i < 15; ++i) {
    const int d = i & 3;
    const float* neigh = neigh_t[d];
    float* node = node_t[d];
    const int Nn = Nn_t[d], Nd = Nd_t[d], base = base_t[d];

    const float* mW1 = mp_msg_w1 + (size_t)i * 4096;
    const float* mB1 = mp_msg_b1 + (size_t)i * 64;
    const float* mW2 = mp_msg_w2 + (size_t)i * 4096;
    const float* mB2 = mp_msg_b2 + (size_t)i * 64;
    const float* gW = mp_gate_w + (size_t)i * 8192;
    const float* gB = mp_gate_b + (size_t)i * 64;
    const float* uW1 = mp_upd_w1 + (size_t)i * 8192;
    const float* uB1 = mp_upd_b1 + (size_t)i * 64;
    const float* uW2 = mp_upd_w2 + (size_t)i * 4096;
    const float* uB2 = mp_upd_b2 + (size_t)i * 64;
    const float* lg = mp_ln_g + (size_t)i * 64;
    const float* lb = mp_ln_b + (size_t)i * 64;

    mlp2_node_k<64><<<(Nn + 255) / 256, 256, 0, stream>>>(neigh, mW1, mB1, mW2,
                                                          mB2, msgb, Nn);
    agg_k<<<(Nd + 3) / 4, 256, 0, stream>>>(row_ptr, nbr, val, msgb, aggb, base, Nd);
    gemv128_k<2><<<(Nd + 255) / 256, 256, 0, stream>>>(aggb, node, gW, gB, gateb, Nd);
    gemv128_k<1><<<(Nd + 255) / 256, 256, 0, stream>>>(aggb, node, uW1, uB1, uhb, Nd);
    float* outp = (i == 14) ? (float*)d_out : node;
    upd2fin_k<<<(Nd + 255) / 256, 256, 0, stream>>>(uhb, uW2, uB2, gateb, node,
                                                    lg, lb, outp, Nd);
  }
}

// Round 3
// 1717.092 us; speedup vs baseline: 2.9159x; 2.9159x over previous
//
#include <hip/hip_runtime.h>

#define DEVINL static __device__ __forceinline__

namespace {

typedef __attribute__((ext_vector_type(8))) short bf16x8;
typedef __attribute__((ext_vector_type(4))) float f32x4;

constexpr int NV = 100000;   // variables
constexpr int NC = 50000;    // constraints
constexpr int NK = 20000;    // cuts
constexpr int EVC = 800000;  // var-cons edges
constexpr int EVK = 200000;  // var-cut edges
constexpr int R_TOT = NC + NV + NK + NV;  // 270000 CSR rows
constexpr int SCAN_CHUNK = 2048;
constexpr int SCAN_NB = (R_TOT + SCAN_CHUNK - 1) / SCAN_CHUNK;  // 132
constexpr int PACK_PER_LAYER = 28672;  // ushort per layer of packed weights

DEVINL unsigned short f2bf(float f) {
  unsigned u = __float_as_uint(f);
  u = u + 0x7fffu + ((u >> 16) & 1u);  // RNE
  return (unsigned short)(u >> 16);
}
DEVINL float bf2f(unsigned short h) {
  return __uint_as_float((unsigned)h << 16);
}

DEVINL float sigmoid_f(float x) { return 1.0f / (1.0f + __expf(-x)); }

// ======================= embeddings (run once, fp32 VALU) ====================
// lane = node; dual-store fp32 + bf16 row-major.
template <int DIN>
__global__ void __launch_bounds__(256) mlp2_node_k(
    const float* __restrict__ X, const float* __restrict__ W1,
    const float* __restrict__ B1, const float* __restrict__ W2,
    const float* __restrict__ B2, float* __restrict__ OUTf,
    unsigned short* __restrict__ OUTb, int N) {
  const int n = blockIdx.x * 256 + threadIdx.x;
  if (n >= N) return;
  float h[64];
#pragma unroll
  for (int c = 0; c < 64; ++c) h[c] = B1[c];
  float x[DIN];
#pragma unroll
  for (int k = 0; k < DIN; ++k) x[k] = X[(size_t)n * DIN + k];
#pragma unroll
  for (int k = 0; k < DIN; ++k) {
    const float xk = x[k];
    const float* wr = W1 + k * 64;
#pragma unroll
    for (int c = 0; c < 64; ++c) h[c] = fmaf(xk, wr[c], h[c]);
  }
#pragma unroll
  for (int c = 0; c < 64; ++c) h[c] = fmaxf(h[c], 0.0f);
  float o[64];
#pragma unroll
  for (int c = 0; c < 64; ++c) o[c] = B2[c];
#pragma unroll
  for (int k = 0; k < 64; ++k) {
    const float hk = h[k];
    const float* wr = W2 + k * 64;
#pragma unroll
    for (int c = 0; c < 64; ++c) o[c] = fmaf(hk, wr[c], o[c]);
  }
  float4* pf = reinterpret_cast<float4*>(OUTf + (size_t)n * 64);
#pragma unroll
  for (int q = 0; q < 16; ++q) {
    float4 v;
    v.x = o[4 * q]; v.y = o[4 * q + 1]; v.z = o[4 * q + 2]; v.w = o[4 * q + 3];
    pf[q] = v;
  }
  unsigned* pb = reinterpret_cast<unsigned*>(OUTb + (size_t)n * 64);
#pragma unroll
  for (int q = 0; q < 32; ++q)
    pb[q] = (unsigned)f2bf(o[2 * q]) | ((unsigned)f2bf(o[2 * q + 1]) << 16);
}

// ---------- single-layer GEMV (edge-weight per-node terms), bf16 out ----------
__global__ void __launch_bounds__(256) gemv64_k(
    const float* __restrict__ X, const float* __restrict__ W,
    unsigned short* __restrict__ OUTb, int N) {
  const int n = blockIdx.x * 256 + threadIdx.x;
  if (n >= N) return;
  float acc[64];
#pragma unroll
  for (int c = 0; c < 64; ++c) acc[c] = 0.0f;
  const float4* x4 = reinterpret_cast<const float4*>(X + (size_t)n * 64);
  for (int kc = 0; kc < 4; ++kc) {
    float x[16];
#pragma unroll
    for (int q = 0; q < 4; ++q) {
      const float4 v = x4[kc * 4 + q];
      x[4 * q] = v.x; x[4 * q + 1] = v.y; x[4 * q + 2] = v.z; x[4 * q + 3] = v.w;
    }
#pragma unroll
    for (int k = 0; k < 16; ++k) {
      const float xk = x[k];
      const float* wr = W + (kc * 16 + k) * 64;
#pragma unroll
      for (int c = 0; c < 64; ++c) acc[c] = fmaf(xk, wr[c], acc[c]);
    }
  }
  unsigned* pb = reinterpret_cast<unsigned*>(OUTb + (size_t)n * 64);
#pragma unroll
  for (int q = 0; q < 32; ++q)
    pb[q] = (unsigned)f2bf(acc[2 * q]) | ((unsigned)f2bf(acc[2 * q + 1]) << 16);
}

// ======================= weight packing (bf16 B-frag stream) =================
// frag index (kb*4+t)*64+lane, 8 bf16 each: value = W[kb*32+(lane>>4)*8+j][t*16+(lane&15)]
__global__ void __launch_bounds__(256) pack_k(
    const float* __restrict__ mW1, const float* __restrict__ mW2,
    const float* __restrict__ gW, const float* __restrict__ uW1,
    const float* __restrict__ uW2, unsigned short* __restrict__ PW) {
  const int layer = blockIdx.x;  // 0..14
  unsigned short* out = PW + (size_t)layer * PACK_PER_LAYER;
  const float* srcs[5] = {mW1 + (size_t)layer * 4096, mW2 + (size_t)layer * 4096,
                          gW + (size_t)layer * 8192, uW1 + (size_t)layer * 8192,
                          uW2 + (size_t)layer * 4096};
  const int Ks[5] = {64, 64, 128, 128, 64};
  const int offs[5] = {0, 4096, 8192, 16384, 24576};
  for (int m = 0; m < 5; ++m) {
    const float* src = srcs[m];
    unsigned short* o = out + offs[m];
    const int ntup = (Ks[m] / 32) * 256;
    for (int tup = threadIdx.x; tup < ntup; tup += 256) {
      const int lane = tup & 63;
      const int t = (tup >> 6) & 3;
      const int kb = tup >> 8;
      const int c = t * 16 + (lane & 15);
      const int k0 = kb * 32 + (lane >> 4) * 8;
#pragma unroll
      for (int jj = 0; jj < 8; ++jj) o[tup * 8 + jj] = f2bf(src[(k0 + jj) * 64 + c]);
    }
  }
}

// ======================= message MLP (MFMA) =================================
// wave = 16 nodes; A-frag: row=lane&15, k=(lane>>4)*8+j; C/D: col=lane&15,
// row=(lane>>4)*4+reg. LDS transpose (stride 72) between the two layers.
__global__ void __launch_bounds__(256) msg_mfma_k(
    const unsigned short* __restrict__ Xb, const unsigned short* __restrict__ Wp,
    const float* __restrict__ B1, const float* __restrict__ B2,
    unsigned short* __restrict__ MSGb, int N) {
  __shared__ unsigned short lds[4][16 * 72];
  const int wave = threadIdx.x >> 6, l = threadIdx.x & 63;
  const int col = l & 15, quad = l >> 4;
  const int n0_raw = blockIdx.x * 64 + wave * 16;
  const bool dead = n0_raw >= N;
  const int n0 = dead ? 0 : n0_raw;

  const unsigned short* xrow = Xb + (size_t)(n0 + col) * 64 + quad * 8;
  const bf16x8 a0 = *(const bf16x8*)xrow;
  const bf16x8 a1 = *(const bf16x8*)(xrow + 32);
  const bf16x8* W1p = (const bf16x8*)Wp;
  const bf16x8* W2p = (const bf16x8*)(Wp + 4096);

  f32x4 acc[4];
#pragma unroll
  for (int t = 0; t < 4; ++t) {
    const float b = B1[col + 16 * t];
    acc[t] = f32x4{b, b, b, b};
  }
#pragma unroll
  for (int t = 0; t < 4; ++t) {
    acc[t] = __builtin_amdgcn_mfma_f32_16x16x32_bf16(a0, W1p[t * 64 + l], acc[t], 0, 0, 0);
    acc[t] = __builtin_amdgcn_mfma_f32_16x16x32_bf16(a1, W1p[(4 + t) * 64 + l], acc[t], 0, 0, 0);
  }
  unsigned short* ld = lds[wave];
#pragma unroll
  for (int t = 0; t < 4; ++t)
#pragma unroll
    for (int r = 0; r < 4; ++r)
      ld[(quad * 4 + r) * 72 + col + 16 * t] = f2bf(fmaxf(acc[t][r], 0.0f));
  __syncthreads();
  const bf16x8 h0 = *(const bf16x8*)&ld[col * 72 + quad * 8];
  const bf16x8 h1 = *(const bf16x8*)&ld[col * 72 + 32 + quad * 8];
  f32x4 o[4];
#pragma unroll
  for (int t = 0; t < 4; ++t) {
    const float b = B2[col + 16 * t];
    o[t] = f32x4{b, b, b, b};
  }
#pragma unroll
  for (int t = 0; t < 4; ++t) {
    o[t] = __builtin_amdgcn_mfma_f32_16x16x32_bf16(h0, W2p[t * 64 + l], o[t], 0, 0, 0);
    o[t] = __builtin_amdgcn_mfma_f32_16x16x32_bf16(h1, W2p[(4 + t) * 64 + l], o[t], 0, 0, 0);
  }
  __syncthreads();
#pragma unroll
  for (int t = 0; t < 4; ++t)
#pragma unroll
    for (int r = 0; r < 4; ++r)
      ld[(quad * 4 + r) * 72 + col + 16 * t] = f2bf(o[t][r]);
  __syncthreads();
  if (!dead) {
#pragma unroll
    for (int cc = 0; cc < 2; ++cc) {
      const bf16x8 v = *(const bf16x8*)&ld[col * 72 + (quad * 2 + cc) * 8];
      *(bf16x8*)(MSGb + (size_t)(n0 + col) * 64 + (quad * 2 + cc) * 8) = v;
    }
  }
}

// ======== fused gate + upd1 + upd2 + gate-mix + LayerNorm (MFMA) ============
__global__ void __launch_bounds__(256) upd_mfma_k(
    const unsigned short* __restrict__ AGGb, const unsigned short* __restrict__ NODEb,
    const float* __restrict__ NODEf, const unsigned short* __restrict__ gWp,
    const unsigned short* __restrict__ uW1p, const unsigned short* __restrict__ uW2p,
    const float* __restrict__ gB, const float* __restrict__ uB1,
    const float* __restrict__ uB2, const float* __restrict__ LNG,
    const float* __restrict__ LNB, float* __restrict__ OUTf,
    unsigned short* __restrict__ OUTb, int N) {
  __shared__ unsigned short lds[4][16 * 72];
  const int wave = threadIdx.x >> 6, l = threadIdx.x & 63;
  const int col = l & 15, quad = l >> 4;
  const int n0_raw = blockIdx.x * 64 + wave * 16;
  const bool dead = n0_raw >= N;
  const int n0 = dead ? 0 : n0_raw;

  const unsigned short* arow = AGGb + (size_t)(n0 + col) * 64 + quad * 8;
  const unsigned short* nrow = NODEb + (size_t)(n0 + col) * 64 + quad * 8;
  const bf16x8 aA0 = *(const bf16x8*)arow;
  const bf16x8 aA1 = *(const bf16x8*)(arow + 32);
  const bf16x8 aN0 = *(const bf16x8*)nrow;
  const bf16x8 aN1 = *(const bf16x8*)(nrow + 32);
  const bf16x8* gW = (const bf16x8*)gWp;
  const bf16x8* uW1 = (const bf16x8*)uW1p;
  const bf16x8* uW2 = (const bf16x8*)uW2p;

  f32x4 g[4], u[4];
#pragma unroll
  for (int t = 0; t < 4; ++t) {
    const float bg = gB[col + 16 * t], bu = uB1[col + 16 * t];
    g[t] = f32x4{bg, bg, bg, bg};
    u[t] = f32x4{bu, bu, bu, bu};
  }
#pragma unroll
  for (int t = 0; t < 4; ++t) {
    g[t] = __builtin_amdgcn_mfma_f32_16x16x32_bf16(aA0, gW[t * 64 + l], g[t], 0, 0, 0);
    g[t] = __builtin_amdgcn_mfma_f32_16x16x32_bf16(aA1, gW[(4 + t) * 64 + l], g[t], 0, 0, 0);
    g[t] = __builtin_amdgcn_mfma_f32_16x16x32_bf16(aN0, gW[(8 + t) * 64 + l], g[t], 0, 0, 0);
    g[t] = __builtin_amdgcn_mfma_f32_16x16x32_bf16(aN1, gW[(12 + t) * 64 + l], g[t], 0, 0, 0);
    u[t] = __builtin_amdgcn_mfma_f32_16x16x32_bf16(aA0, uW1[t * 64 + l], u[t], 0, 0, 0);
    u[t] = __builtin_amdgcn_mfma_f32_16x16x32_bf16(aA1, uW1[(4 + t) * 64 + l], u[t], 0, 0, 0);
    u[t] = __builtin_amdgcn_mfma_f32_16x16x32_bf16(aN0, uW1[(8 + t) * 64 + l], u[t], 0, 0, 0);
    u[t] = __builtin_amdgcn_mfma_f32_16x16x32_bf16(aN1, uW1[(12 + t) * 64 + l], u[t], 0, 0, 0);
  }
#pragma unroll
  for (int t = 0; t < 4; ++t)
#pragma unroll
    for (int r = 0; r < 4; ++r) g[t][r] = sigmoid_f(g[t][r]);

  unsigned short* ld = lds[wave];
#pragma unroll
  for (int t = 0; t < 4; ++t)
#pragma unroll
    for (int r = 0; r < 4; ++r)
      ld[(quad * 4 + r) * 72 + col + 16 * t] = f2bf(fmaxf(u[t][r], 0.0f));
  __syncthreads();
  const bf16x8 h0 = *(const bf16x8*)&ld[col * 72 + quad * 8];
  const bf16x8 h1 = *(const bf16x8*)&ld[col * 72 + 32 + quad * 8];
  f32x4 o[4];
#pragma unroll
  for (int t = 0; t < 4; ++t) {
    const float b = uB2[col + 16 * t];
    o[t] = f32x4{b, b, b, b};
  }
#pragma unroll
  for (int t = 0; t < 4; ++t) {
    o[t] = __builtin_amdgcn_mfma_f32_16x16x32_bf16(h0, uW2[t * 64 + l], o[t], 0, 0, 0);
    o[t] = __builtin_amdgcn_mfma_f32_16x16x32_bf16(h1, uW2[(4 + t) * 64 + l], o[t], 0, 0, 0);
  }
  // gate mix (fp32 node state) + LayerNorm
  float om[4][4];
#pragma unroll
  for (int t = 0; t < 4; ++t)
#pragma unroll
    for (int r = 0; r < 4; ++r) {
      const float nd = NODEf[(size_t)(n0 + quad * 4 + r) * 64 + col + 16 * t];
      om[t][r] = fmaf(g[t][r], o[t][r] - nd, nd);
    }
  float outv[4][4];
#pragma unroll
  for (int r = 0; r < 4; ++r) {
    float s1 = (om[0][r] + om[1][r]) + (om[2][r] + om[3][r]);
    float s2 = fmaf(om[0][r], om[0][r], fmaf(om[1][r], om[1][r],
                fmaf(om[2][r], om[2][r], om[3][r] * om[3][r])));
#pragma unroll
    for (int off = 1; off < 16; off <<= 1) {
      s1 += __shfl_xor(s1, off, 64);
      s2 += __shfl_xor(s2, off, 64);
    }
    const float m = s1 * (1.0f / 64.0f);
    const float var = s2 * (1.0f / 64.0f) - m * m;
    const float rr = rsqrtf(var + 1e-3f);
#pragma unroll
    for (int t = 0; t < 4; ++t)
      outv[t][r] = fmaf((om[t][r] - m) * rr, LNG[col + 16 * t], LNB[col + 16 * t]);
  }
  if (!dead) {
#pragma unroll
    for (int t = 0; t < 4; ++t)
#pragma unroll
      for (int r = 0; r < 4; ++r)
        OUTf[(size_t)(n0 + quad * 4 + r) * 64 + col + 16 * t] = outv[t][r];
  }
  __syncthreads();
#pragma unroll
  for (int t = 0; t < 4; ++t)
#pragma unroll
    for (int r = 0; r < 4; ++r)
      ld[(quad * 4 + r) * 72 + col + 16 * t] = f2bf(outv[t][r]);
  __syncthreads();
  if (!dead) {
#pragma unroll
    for (int cc = 0; cc < 2; ++cc) {
      const bf16x8 v = *(const bf16x8*)&ld[col * 72 + (quad * 2 + cc) * 8];
      *(bf16x8*)(OUTb + (size_t)(n0 + col) * 64 + (quad * 2 + cc) * 8) = v;
    }
  }
}

// ======================= edge weight (bf16 node terms) =======================
__global__ void __launch_bounds__(256) edgew_k(
    const int* __restrict__ S, const int* __restrict__ D,
    const float* __restrict__ EFX, const unsigned short* __restrict__ PA,
    const unsigned short* __restrict__ PB, const float* __restrict__ W1C,
    const float* __restrict__ B1, const float* __restrict__ W2,
    const float* __restrict__ B2, float* __restrict__ EW, int E) {
  const int j = threadIdx.x & 63;
  const int e = blockIdx.x * 4 + (threadIdx.x >> 6);
  if (e >= E) return;
  float wc[8];
#pragma unroll
  for (int i = 0; i < 8; ++i) wc[i] = W1C[i * 64 + j];
  const int s = S[e], d = D[e];
  float h = bf2f(PA[(size_t)s * 64 + j]) + bf2f(PB[(size_t)d * 64 + j]) + B1[j];
  const float efv = (j < 8) ? EFX[(size_t)e * 8 + j] : 0.0f;
#pragma unroll
  for (int i = 0; i < 8; ++i) {
    const float ef_i =
        __int_as_float(__builtin_amdgcn_readlane(__float_as_int(efv), i));
    h = fmaf(ef_i, wc[i], h);
  }
  h = fmaxf(h, 0.0f);
  float t = h * W2[j];
#pragma unroll
  for (int off = 32; off > 0; off >>= 1) t += __shfl_xor(t, off, 64);
  if (j == 0) EW[e] = sigmoid_f(t + B2[0]);
}

// ======================= CSR aggregation (bf16 msg, 4x unroll) ==============
__global__ void __launch_bounds__(256) agg_k(
    const int* __restrict__ row_ptr, const int* __restrict__ nbr,
    const float* __restrict__ val, const unsigned short* __restrict__ MSGb,
    unsigned short* __restrict__ AGGb, int base, int N) {
  const int j = threadIdx.x & 63;
  const int n = blockIdx.x * 4 + (threadIdx.x >> 6);
  if (n >= N) return;
  const int s = row_ptr[base + n], e = row_ptr[base + n + 1];
  float acc = 0.0f, deg = 0.0f;
  int p = s;
  for (; p + 4 <= e; p += 4) {
    const int nb0 = nbr[p], nb1 = nbr[p + 1], nb2 = nbr[p + 2], nb3 = nbr[p + 3];
    const float w0 = val[p], w1 = val[p + 1], w2 = val[p + 2], w3 = val[p + 3];
    const float m0 = bf2f(MSGb[(size_t)nb0 * 64 + j]);
    const float m1 = bf2f(MSGb[(size_t)nb1 * 64 + j]);
    const float m2 = bf2f(MSGb[(size_t)nb2 * 64 + j]);
    const float m3 = bf2f(MSGb[(size_t)nb3 * 64 + j]);
    acc = fmaf(m0, w0, acc);
    acc = fmaf(m1, w1, acc);
    acc = fmaf(m2, w2, acc);
    acc = fmaf(m3, w3, acc);
    deg += (w0 + w1) + (w2 + w3);
  }
  for (; p < e; ++p) {
    const float w = val[p];
    acc = fmaf(bf2f(MSGb[(size_t)nbr[p] * 64 + j]), w, acc);
    deg += w;
  }
  AGGb[(size_t)n * 64 + j] = f2bf(acc / fmaxf(deg, 1.0f));
}

// ======================= CSR build: count, scan, fill ========================
__global__ void __launch_bounds__(256) count_k(
    const int* __restrict__ S, const int* __restrict__ D,
    int* __restrict__ counts, int baseD, int baseS, int E) {
  const int e = blockIdx.x * 256 + threadIdx.x;
  if (e >= E) return;
  atomicAdd(&counts[baseD + D[e]], 1);
  atomicAdd(&counts[baseS + S[e]], 1);
}

__global__ void __launch_bounds__(256) fill_k(
    const int* __restrict__ S, const int* __restrict__ D,
    const float* __restrict__ EW, int* __restrict__ cursor,
    int* __restrict__ nbr, float* __restrict__ val,
    int baseD, int baseS, int E) {
  const int e = blockIdx.x * 256 + threadIdx.x;
  if (e >= E) return;
  const int s = S[e], d = D[e];
  const float w = EW[e];
  int p = atomicAdd(&cursor[baseD + d], 1);
  nbr[p] = s;
  val[p] = w;
  p = atomicAdd(&cursor[baseS + s], 1);
  nbr[p] = d;
  val[p] = w;
}

__global__ void __launch_bounds__(256) scan1_k(const int* __restrict__ in,
                                               int* __restrict__ bsum) {
  __shared__ int sd[256];
  const int t = threadIdx.x;
  const int base = blockIdx.x * SCAN_CHUNK + t * 8;
  int s = 0;
#pragma unroll
  for (int i = 0; i < 8; ++i) {
    const int idx = base + i;
    s += (idx < R_TOT) ? in[idx] : 0;
  }
  sd[t] = s;
  __syncthreads();
  for (int off = 128; off > 0; off >>= 1) {
    if (t < off) sd[t] += sd[t + off];
    __syncthreads();
  }
  if (t == 0) bsum[blockIdx.x] = sd[0];
}

__global__ void __launch_bounds__(256) scan2_k(int* __restrict__ bsum,
                                               int* __restrict__ row_ptr) {
  __shared__ int sd[256];
  const int t = threadIdx.x;
  const int v = (t < SCAN_NB) ? bsum[t] : 0;
  sd[t] = v;
  __syncthreads();
  for (int off = 1; off < 256; off <<= 1) {
    const int add = (t >= off) ? sd[t - off] : 0;
    __syncthreads();
    sd[t] += add;
    __syncthreads();
  }
  if (t < SCAN_NB) bsum[t] = sd[t] - v;
  if (t == 255) row_ptr[R_TOT] = sd[255];
}

__global__ void __launch_bounds__(256) scan3_k(const int* __restrict__ in,
                                               const int* __restrict__ bsum,
                                               int* __restrict__ out) {
  __shared__ int sd[256];
  const int t = threadIdx.x;
  const int base = blockIdx.x * SCAN_CHUNK + t * 8;
  int loc[8];
  int s = 0;
#pragma unroll
  for (int i = 0; i < 8; ++i) {
    loc[i] = s;
    const int idx = base + i;
    s += (idx < R_TOT) ? in[idx] : 0;
  }
  sd[t] = s;
  __syncthreads();
  const int v = s;
  for (int off = 1; off < 256; off <<= 1) {
    const int add = (t >= off) ? sd[t - off] : 0;
    __syncthreads();
    sd[t] += add;
    __syncthreads();
  }
  const int off0 = bsum[blockIdx.x] + (sd[t] - v);
#pragma unroll
  for (int i = 0; i < 8; ++i) {
    const int idx = base + i;
    if (idx < R_TOT) out[idx] = off0 + loc[i];
  }
}

}  // namespace

extern "C" void kernel_launch(void* const* d_in, const int* in_sizes, int n_in,
                              void* d_out, int out_size, void* d_ws, size_t ws_size,
                              hipStream_t stream) {
  (void)in_sizes; (void)n_in; (void)out_size; (void)ws_size;

  const float* variable_features   = (const float*)d_in[0];
  const float* constraint_features = (const float*)d_in[1];
  const float* cut_features        = (const float*)d_in[2];
  const float* vc_ef = (const float*)d_in[3];
  const float* vk_ef = (const float*)d_in[4];
  const int* vc_edges = (const int*)d_in[5];
  const int* vk_edges = (const int*)d_in[6];
  const int *vc_s = vc_edges, *vc_d = vc_edges + EVC;
  const int *vk_s = vk_edges, *vk_d = vk_edges + EVK;
  const float* var_w1  = (const float*)d_in[7];
  const float* var_b1  = (const float*)d_in[8];
  const float* var_w2  = (const float*)d_in[9];
  const float* var_b2  = (const float*)d_in[10];
  const float* cons_w1 = (const float*)d_in[11];
  const float* cons_b1 = (const float*)d_in[12];
  const float* cons_w2 = (const float*)d_in[13];
  const float* cons_b2 = (const float*)d_in[14];
  const float* cut_w1  = (const float*)d_in[15];
  const float* cut_b1  = (const float*)d_in[16];
  const float* cut_w2  = (const float*)d_in[17];
  const float* cut_b2  = (const float*)d_in[18];
  const float* ewvc_w1 = (const float*)d_in[19];
  const float* ewvc_b1 = (const float*)d_in[20];
  const float* ewvc_w2 = (const float*)d_in[21];
  const float* ewvc_b2 = (const float*)d_in[22];
  const float* ewvk_w1 = (const float*)d_in[23];
  const float* ewvk_b1 = (const float*)d_in[24];
  const float* ewvk_w2 = (const float*)d_in[25];
  const float* ewvk_b2 = (const float*)d_in[26];
  const float* mp_msg_w1 = (const float*)d_in[27];
  const float* mp_msg_b1 = (const float*)d_in[28];
  const float* mp_msg_w2 = (const float*)d_in[29];
  const float* mp_msg_b2 = (const float*)d_in[30];
  const float* mp_gate_w = (const float*)d_in[31];
  const float* mp_gate_b = (const float*)d_in[32];
  const float* mp_upd_w1 = (const float*)d_in[33];
  const float* mp_upd_b1 = (const float*)d_in[34];
  const float* mp_upd_w2 = (const float*)d_in[35];
  const float* mp_upd_b2 = (const float*)d_in[36];
  const float* mp_ln_g   = (const float*)d_in[37];
  const float* mp_ln_b   = (const float*)d_in[38];

  // ---- workspace carve ----
  char* wp = (char*)d_ws;
  auto take = [&](size_t nbytes) {
    char* p = wp;
    wp += (nbytes + 255) & ~(size_t)255;
    return p;
  };
  float* h_var_f  = (float*)take((size_t)NV * 64 * 4);
  float* h_cons_f = (float*)take((size_t)NC * 64 * 4);
  float* h_cut_f  = (float*)take((size_t)NK * 64 * 4);
  unsigned short* h_var_b  = (unsigned short*)take((size_t)NV * 64 * 2);
  unsigned short* h_cons_b = (unsigned short*)take((size_t)NC * 64 * 2);
  unsigned short* h_cut_b  = (unsigned short*)take((size_t)NK * 64 * 2);
  unsigned short* msg_b = (unsigned short*)take((size_t)NV * 64 * 2);
  unsigned short* agg_b = (unsigned short*)take((size_t)NV * 64 * 2);
  unsigned short* pa = (unsigned short*)take((size_t)NV * 64 * 2);
  unsigned short* pb = (unsigned short*)take((size_t)NC * 64 * 2);
  unsigned short* qa = (unsigned short*)take((size_t)NV * 64 * 2);
  unsigned short* qb = (unsigned short*)take((size_t)NK * 64 * 2);
  unsigned short* packW = (unsigned short*)take((size_t)15 * PACK_PER_LAYER * 2);
  float* ew_vc = (float*)take((size_t)EVC * 4);
  float* ew_vk = (float*)take((size_t)EVK * 4);
  int* row_ptr = (int*)take((size_t)(R_TOT + 1) * 4);
  int* cursor  = (int*)take((size_t)R_TOT * 4);
  int* counts  = (int*)take((size_t)R_TOT * 4);
  int* bsum    = (int*)take(256 * 4);
  int* nbr     = (int*)take((size_t)(2 * EVC + 2 * EVK) * 4);
  float* val   = (float*)take((size_t)(2 * EVC + 2 * EVK) * 4);

  // ---- CSR counts + scan ----
  hipMemsetAsync(counts, 0, (size_t)R_TOT * 4, stream);
  count_k<<<(EVC + 255) / 256, 256, 0, stream>>>(vc_s, vc_d, counts, 0, NC, EVC);
  count_k<<<(EVK + 255) / 256, 256, 0, stream>>>(vk_s, vk_d, counts, NC + NV,
                                                 NC + NV + NK, EVK);
  scan1_k<<<SCAN_NB, 256, 0, stream>>>(counts, bsum);
  scan2_k<<<1, 256, 0, stream>>>(bsum, row_ptr);
  scan3_k<<<SCAN_NB, 256, 0, stream>>>(counts, bsum, row_ptr);

  // ---- embeddings (dual fp32 + bf16) ----
  mlp2_node_k<19><<<(NV + 255) / 256, 256, 0, stream>>>(
      variable_features, var_w1, var_b1, var_w2, var_b2, h_var_f, h_var_b, NV);
  mlp2_node_k<5><<<(NC + 255) / 256, 256, 0, stream>>>(
      constraint_features, cons_w1, cons_b1, cons_w2, cons_b2, h_cons_f, h_cons_b, NC);
  mlp2_node_k<30><<<(NK + 255) / 256, 256, 0, stream>>>(
      cut_features, cut_w1, cut_b1, cut_w2, cut_b2, h_cut_f, h_cut_b, NK);

  // ---- pack MP weights to bf16 B-frag streams ----
  pack_k<<<15, 256, 0, stream>>>(mp_msg_w1, mp_msg_w2, mp_gate_w, mp_upd_w1,
                                 mp_upd_w2, packW);

  // ---- edge weights: per-node terms (bf16) then per-edge combine ----
  gemv64_k<<<(NV + 255) / 256, 256, 0, stream>>>(h_var_f, ewvc_w1, pa, NV);
  gemv64_k<<<(NC + 255) / 256, 256, 0, stream>>>(h_cons_f, ewvc_w1 + 64 * 64, pb, NC);
  gemv64_k<<<(NV + 255) / 256, 256, 0, stream>>>(h_var_f, ewvk_w1, qa, NV);
  gemv64_k<<<(NK + 255) / 256, 256, 0, stream>>>(h_cut_f, ewvk_w1 + 64 * 64, qb, NK);
  edgew_k<<<EVC / 4, 256, 0, stream>>>(vc_s, vc_d, vc_ef, pa, pb,
                                       ewvc_w1 + 128 * 64, ewvc_b1, ewvc_w2,
                                       ewvc_b2, ew_vc, EVC);
  edgew_k<<<EVK / 4, 256, 0, stream>>>(vk_s, vk_d, vk_ef, qa, qb,
                                       ewvk_w1 + 128 * 64, ewvk_b1, ewvk_w2,
                                       ewvk_b2, ew_vk, EVK);

  // ---- CSR fill ----
  hipMemcpyAsync(cursor, row_ptr, (size_t)R_TOT * 4, hipMemcpyDeviceToDevice, stream);
  fill_k<<<(EVC + 255) / 256, 256, 0, stream>>>(vc_s, vc_d, ew_vc, cursor, nbr,
                                                val, 0, NC, EVC);
  fill_k<<<(EVK + 255) / 256, 256, 0, stream>>>(vk_s, vk_d, ew_vk, cursor, nbr,
                                                val, NC + NV, NC + NV + NK, EVK);

  // ---- 15 message passes (16th only updates h_var -> dead, skipped) ----
  const unsigned short* neigh_t[4] = {h_var_b, h_cons_b, h_var_b, h_cut_b};
  unsigned short* nodeb_t[4] = {h_cons_b, h_var_b, h_cut_b, h_var_b};
  float* nodef_t[4] = {h_cons_f, h_var_f, h_cut_f, h_var_f};
  const int Nn_t[4] = {NV, NC, NV, NK};
  const int Nd_t[4] = {NC, NV, NK, NV};
  const int base_t[4] = {0, NC, NC + NV, NC + NV + NK};

  for (int i = 0; i < 15; ++i) {
    const int d = i & 3;
    const int Nn = Nn_t[d], Nd = Nd_t[d], base = base_t[d];
    const unsigned short* Wl = packW + (size_t)i * PACK_PER_LAYER;

    msg_mfma_k<<<(Nn + 63) / 64, 256, 0, stream>>>(
        neigh_t[d], Wl, mp_msg_b1 + (size_t)i * 64, mp_msg_b2 + (size_t)i * 64,
        msg_b, Nn);
    agg_k<<<(Nd + 3) / 4, 256, 0, stream>>>(row_ptr, nbr, val, msg_b, agg_b,
                                            base, Nd);
    float* outf = (i == 14) ? (float*)d_out : nodef_t[d];
    upd_mfma_k<<<(Nd + 63) / 64, 256, 0, stream>>>(
        agg_b, nodeb_t[d], nodef_t[d], Wl + 8192, Wl + 16384, Wl + 24576,
        mp_gate_b + (size_t)i * 64, mp_upd_b1 + (size_t)i * 64,
        mp_upd_b2 + (size_t)i * 64, mp_ln_g + (size_t)i * 64,
        mp_ln_b + (size_t)i * 64, outf, nodeb_t[d], Nd);
  }
}

// Round 4
// 1596.528 us; speedup vs baseline: 3.1361x; 1.0755x over previous
//
#include <hip/hip_runtime.h>

#define DEVINL static __device__ __forceinline__

namespace {

typedef __attribute__((ext_vector_type(8))) short bf16x8;
typedef __attribute__((ext_vector_type(4))) float f32x4;

constexpr int NV = 100000;   // variables
constexpr int NC = 50000;    // constraints
constexpr int NK = 20000;    // cuts
constexpr int EVC = 800000;  // var-cons edges
constexpr int EVK = 200000;  // var-cut edges
constexpr int R_TOT = NC + NV + NK + NV;  // 270000 CSR rows
constexpr int SCAN_CHUNK = 2048;
constexpr int SCAN_NB = (R_TOT + SCAN_CHUNK - 1) / SCAN_CHUNK;  // 132
constexpr int PACK_PER_LAYER = 28672;  // ushort per layer of packed weights

DEVINL unsigned short f2bf(float f) {
  unsigned u = __float_as_uint(f);
  u = u + 0x7fffu + ((u >> 16) & 1u);  // RNE
  return (unsigned short)(u >> 16);
}
DEVINL float bf2f(unsigned short h) {
  return __uint_as_float((unsigned)h << 16);
}

DEVINL float sigmoid_f(float x) { return 1.0f / (1.0f + __expf(-x)); }

// ======================= embeddings (run once, fp32 VALU) ====================
template <int DIN>
__global__ void __launch_bounds__(256) mlp2_node_k(
    const float* __restrict__ X, const float* __restrict__ W1,
    const float* __restrict__ B1, const float* __restrict__ W2,
    const float* __restrict__ B2, float* __restrict__ OUTf,
    unsigned short* __restrict__ OUTb, int N) {
  const int n = blockIdx.x * 256 + threadIdx.x;
  if (n >= N) return;
  float h[64];
#pragma unroll
  for (int c = 0; c < 64; ++c) h[c] = B1[c];
  float x[DIN];
#pragma unroll
  for (int k = 0; k < DIN; ++k) x[k] = X[(size_t)n * DIN + k];
#pragma unroll
  for (int k = 0; k < DIN; ++k) {
    const float xk = x[k];
    const float* wr = W1 + k * 64;
#pragma unroll
    for (int c = 0; c < 64; ++c) h[c] = fmaf(xk, wr[c], h[c]);
  }
#pragma unroll
  for (int c = 0; c < 64; ++c) h[c] = fmaxf(h[c], 0.0f);
  float o[64];
#pragma unroll
  for (int c = 0; c < 64; ++c) o[c] = B2[c];
#pragma unroll
  for (int k = 0; k < 64; ++k) {
    const float hk = h[k];
    const float* wr = W2 + k * 64;
#pragma unroll
    for (int c = 0; c < 64; ++c) o[c] = fmaf(hk, wr[c], o[c]);
  }
  float4* pf = reinterpret_cast<float4*>(OUTf + (size_t)n * 64);
#pragma unroll
  for (int q = 0; q < 16; ++q) {
    float4 v;
    v.x = o[4 * q]; v.y = o[4 * q + 1]; v.z = o[4 * q + 2]; v.w = o[4 * q + 3];
    pf[q] = v;
  }
  unsigned* pb = reinterpret_cast<unsigned*>(OUTb + (size_t)n * 64);
#pragma unroll
  for (int q = 0; q < 32; ++q)
    pb[q] = (unsigned)f2bf(o[2 * q]) | ((unsigned)f2bf(o[2 * q + 1]) << 16);
}

// ---------- single-layer GEMV (edge-weight per-node terms), bf16 out ----------
__global__ void __launch_bounds__(256) gemv64_k(
    const float* __restrict__ X, const float* __restrict__ W,
    unsigned short* __restrict__ OUTb, int N) {
  const int n = blockIdx.x * 256 + threadIdx.x;
  if (n >= N) return;
  float acc[64];
#pragma unroll
  for (int c = 0; c < 64; ++c) acc[c] = 0.0f;
  const float4* x4 = reinterpret_cast<const float4*>(X + (size_t)n * 64);
  for (int kc = 0; kc < 4; ++kc) {
    float x[16];
#pragma unroll
    for (int q = 0; q < 4; ++q) {
      const float4 v = x4[kc * 4 + q];
      x[4 * q] = v.x; x[4 * q + 1] = v.y; x[4 * q + 2] = v.z; x[4 * q + 3] = v.w;
    }
#pragma unroll
    for (int k = 0; k < 16; ++k) {
      const float xk = x[k];
      const float* wr = W + (kc * 16 + k) * 64;
#pragma unroll
      for (int c = 0; c < 64; ++c) acc[c] = fmaf(xk, wr[c], acc[c]);
    }
  }
  unsigned* pb = reinterpret_cast<unsigned*>(OUTb + (size_t)n * 64);
#pragma unroll
  for (int q = 0; q < 32; ++q)
    pb[q] = (unsigned)f2bf(acc[2 * q]) | ((unsigned)f2bf(acc[2 * q + 1]) << 16);
}

// ======================= weight packing (bf16 B-frag stream) =================
__global__ void __launch_bounds__(256) pack_k(
    const float* __restrict__ mW1, const float* __restrict__ mW2,
    const float* __restrict__ gW, const float* __restrict__ uW1,
    const float* __restrict__ uW2, unsigned short* __restrict__ PW) {
  const int layer = blockIdx.x;  // 0..14
  unsigned short* out = PW + (size_t)layer * PACK_PER_LAYER;
  const float* srcs[5] = {mW1 + (size_t)layer * 4096, mW2 + (size_t)layer * 4096,
                          gW + (size_t)layer * 8192, uW1 + (size_t)layer * 8192,
                          uW2 + (size_t)layer * 4096};
  const int Ks[5] = {64, 64, 128, 128, 64};
  const int offs[5] = {0, 4096, 8192, 16384, 24576};
  for (int m = 0; m < 5; ++m) {
    const float* src = srcs[m];
    unsigned short* o = out + offs[m];
    const int ntup = (Ks[m] / 32) * 256;
    for (int tup = threadIdx.x; tup < ntup; tup += 256) {
      const int lane = tup & 63;
      const int t = (tup >> 6) & 3;
      const int kb = tup >> 8;
      const int c = t * 16 + (lane & 15);
      const int k0 = kb * 32 + (lane >> 4) * 8;
#pragma unroll
      for (int jj = 0; jj < 8; ++jj) o[tup * 8 + jj] = f2bf(src[(k0 + jj) * 64 + c]);
    }
  }
}

// ======================= message MLP (MFMA) =================================
__global__ void __launch_bounds__(256) msg_mfma_k(
    const unsigned short* __restrict__ Xb, const unsigned short* __restrict__ Wp,
    const float* __restrict__ B1, const float* __restrict__ B2,
    unsigned short* __restrict__ MSGb, int N) {
  __shared__ unsigned short lds[4][16 * 72];
  const int wave = threadIdx.x >> 6, l = threadIdx.x & 63;
  const int col = l & 15, quad = l >> 4;
  const int n0_raw = blockIdx.x * 64 + wave * 16;
  const bool dead = n0_raw >= N;
  const int n0 = dead ? 0 : n0_raw;

  const unsigned short* xrow = Xb + (size_t)(n0 + col) * 64 + quad * 8;
  const bf16x8 a0 = *(const bf16x8*)xrow;
  const bf16x8 a1 = *(const bf16x8*)(xrow + 32);
  const bf16x8* W1p = (const bf16x8*)Wp;
  const bf16x8* W2p = (const bf16x8*)(Wp + 4096);

  f32x4 acc[4];
#pragma unroll
  for (int t = 0; t < 4; ++t) {
    const float b = B1[col + 16 * t];
    acc[t] = f32x4{b, b, b, b};
  }
#pragma unroll
  for (int t = 0; t < 4; ++t) {
    acc[t] = __builtin_amdgcn_mfma_f32_16x16x32_bf16(a0, W1p[t * 64 + l], acc[t], 0, 0, 0);
    acc[t] = __builtin_amdgcn_mfma_f32_16x16x32_bf16(a1, W1p[(4 + t) * 64 + l], acc[t], 0, 0, 0);
  }
  unsigned short* ld = lds[wave];
#pragma unroll
  for (int t = 0; t < 4; ++t)
#pragma unroll
    for (int r = 0; r < 4; ++r)
      ld[(quad * 4 + r) * 72 + col + 16 * t] = f2bf(fmaxf(acc[t][r], 0.0f));
  __syncthreads();
  const bf16x8 h0 = *(const bf16x8*)&ld[col * 72 + quad * 8];
  const bf16x8 h1 = *(const bf16x8*)&ld[col * 72 + 32 + quad * 8];
  f32x4 o[4];
#pragma unroll
  for (int t = 0; t < 4; ++t) {
    const float b = B2[col + 16 * t];
    o[t] = f32x4{b, b, b, b};
  }
#pragma unroll
  for (int t = 0; t < 4; ++t) {
    o[t] = __builtin_amdgcn_mfma_f32_16x16x32_bf16(h0, W2p[t * 64 + l], o[t], 0, 0, 0);
    o[t] = __builtin_amdgcn_mfma_f32_16x16x32_bf16(h1, W2p[(4 + t) * 64 + l], o[t], 0, 0, 0);
  }
  __syncthreads();
#pragma unroll
  for (int t = 0; t < 4; ++t)
#pragma unroll
    for (int r = 0; r < 4; ++r)
      ld[(quad * 4 + r) * 72 + col + 16 * t] = f2bf(o[t][r]);
  __syncthreads();
  if (!dead) {
#pragma unroll
    for (int cc = 0; cc < 2; ++cc) {
      const bf16x8 v = *(const bf16x8*)&ld[col * 72 + (quad * 2 + cc) * 8];
      *(bf16x8*)(MSGb + (size_t)(n0 + col) * 64 + (quad * 2 + cc) * 8) = v;
    }
  }
}

// ======== fused gate + upd1 + upd2 + gate-mix + LayerNorm (MFMA) ============
__global__ void __launch_bounds__(256) upd_mfma_k(
    const unsigned short* __restrict__ AGGb, const unsigned short* __restrict__ NODEb,
    const float* __restrict__ NODEf, const unsigned short* __restrict__ gWp,
    const unsigned short* __restrict__ uW1p, const unsigned short* __restrict__ uW2p,
    const float* __restrict__ gB, const float* __restrict__ uB1,
    const float* __restrict__ uB2, const float* __restrict__ LNG,
    const float* __restrict__ LNB, float* __restrict__ OUTf,
    unsigned short* __restrict__ OUTb, int N) {
  __shared__ unsigned short lds[4][16 * 72];
  const int wave = threadIdx.x >> 6, l = threadIdx.x & 63;
  const int col = l & 15, quad = l >> 4;
  const int n0_raw = blockIdx.x * 64 + wave * 16;
  const bool dead = n0_raw >= N;
  const int n0 = dead ? 0 : n0_raw;

  const unsigned short* arow = AGGb + (size_t)(n0 + col) * 64 + quad * 8;
  const unsigned short* nrow = NODEb + (size_t)(n0 + col) * 64 + quad * 8;
  const bf16x8 aA0 = *(const bf16x8*)arow;
  const bf16x8 aA1 = *(const bf16x8*)(arow + 32);
  const bf16x8 aN0 = *(const bf16x8*)nrow;
  const bf16x8 aN1 = *(const bf16x8*)(nrow + 32);
  const bf16x8* gW = (const bf16x8*)gWp;
  const bf16x8* uW1 = (const bf16x8*)uW1p;
  const bf16x8* uW2 = (const bf16x8*)uW2p;

  f32x4 g[4], u[4];
#pragma unroll
  for (int t = 0; t < 4; ++t) {
    const float bg = gB[col + 16 * t], bu = uB1[col + 16 * t];
    g[t] = f32x4{bg, bg, bg, bg};
    u[t] = f32x4{bu, bu, bu, bu};
  }
#pragma unroll
  for (int t = 0; t < 4; ++t) {
    g[t] = __builtin_amdgcn_mfma_f32_16x16x32_bf16(aA0, gW[t * 64 + l], g[t], 0, 0, 0);
    g[t] = __builtin_amdgcn_mfma_f32_16x16x32_bf16(aA1, gW[(4 + t) * 64 + l], g[t], 0, 0, 0);
    g[t] = __builtin_amdgcn_mfma_f32_16x16x32_bf16(aN0, gW[(8 + t) * 64 + l], g[t], 0, 0, 0);
    g[t] = __builtin_amdgcn_mfma_f32_16x16x32_bf16(aN1, gW[(12 + t) * 64 + l], g[t], 0, 0, 0);
    u[t] = __builtin_amdgcn_mfma_f32_16x16x32_bf16(aA0, uW1[t * 64 + l], u[t], 0, 0, 0);
    u[t] = __builtin_amdgcn_mfma_f32_16x16x32_bf16(aA1, uW1[(4 + t) * 64 + l], u[t], 0, 0, 0);
    u[t] = __builtin_amdgcn_mfma_f32_16x16x32_bf16(aN0, uW1[(8 + t) * 64 + l], u[t], 0, 0, 0);
    u[t] = __builtin_amdgcn_mfma_f32_16x16x32_bf16(aN1, uW1[(12 + t) * 64 + l], u[t], 0, 0, 0);
  }
#pragma unroll
  for (int t = 0; t < 4; ++t)
#pragma unroll
    for (int r = 0; r < 4; ++r) g[t][r] = sigmoid_f(g[t][r]);

  unsigned short* ld = lds[wave];
#pragma unroll
  for (int t = 0; t < 4; ++t)
#pragma unroll
    for (int r = 0; r < 4; ++r)
      ld[(quad * 4 + r) * 72 + col + 16 * t] = f2bf(fmaxf(u[t][r], 0.0f));
  __syncthreads();
  const bf16x8 h0 = *(const bf16x8*)&ld[col * 72 + quad * 8];
  const bf16x8 h1 = *(const bf16x8*)&ld[col * 72 + 32 + quad * 8];
  f32x4 o[4];
#pragma unroll
  for (int t = 0; t < 4; ++t) {
    const float b = uB2[col + 16 * t];
    o[t] = f32x4{b, b, b, b};
  }
#pragma unroll
  for (int t = 0; t < 4; ++t) {
    o[t] = __builtin_amdgcn_mfma_f32_16x16x32_bf16(h0, uW2[t * 64 + l], o[t], 0, 0, 0);
    o[t] = __builtin_amdgcn_mfma_f32_16x16x32_bf16(h1, uW2[(4 + t) * 64 + l], o[t], 0, 0, 0);
  }
  // gate mix (fp32 node state) + LayerNorm
  float om[4][4];
#pragma unroll
  for (int t = 0; t < 4; ++t)
#pragma unroll
    for (int r = 0; r < 4; ++r) {
      const float nd = NODEf[(size_t)(n0 + quad * 4 + r) * 64 + col + 16 * t];
      om[t][r] = fmaf(g[t][r], o[t][r] - nd, nd);
    }
  float outv[4][4];
#pragma unroll
  for (int r = 0; r < 4; ++r) {
    float s1 = (om[0][r] + om[1][r]) + (om[2][r] + om[3][r]);
    float s2 = fmaf(om[0][r], om[0][r], fmaf(om[1][r], om[1][r],
                fmaf(om[2][r], om[2][r], om[3][r] * om[3][r])));
#pragma unroll
    for (int off = 1; off < 16; off <<= 1) {
      s1 += __shfl_xor(s1, off, 64);
      s2 += __shfl_xor(s2, off, 64);
    }
    const float m = s1 * (1.0f / 64.0f);
    const float var = s2 * (1.0f / 64.0f) - m * m;
    const float rr = rsqrtf(var + 1e-3f);
#pragma unroll
    for (int t = 0; t < 4; ++t)
      outv[t][r] = fmaf((om[t][r] - m) * rr, LNG[col + 16 * t], LNB[col + 16 * t]);
  }
  if (!dead) {
#pragma unroll
    for (int t = 0; t < 4; ++t)
#pragma unroll
      for (int r = 0; r < 4; ++r)
        OUTf[(size_t)(n0 + quad * 4 + r) * 64 + col + 16 * t] = outv[t][r];
  }
  __syncthreads();
#pragma unroll
  for (int t = 0; t < 4; ++t)
#pragma unroll
    for (int r = 0; r < 4; ++r)
      ld[(quad * 4 + r) * 72 + col + 16 * t] = f2bf(outv[t][r]);
  __syncthreads();
  if (!dead) {
#pragma unroll
    for (int cc = 0; cc < 2; ++cc) {
      const bf16x8 v = *(const bf16x8*)&ld[col * 72 + (quad * 2 + cc) * 8];
      *(bf16x8*)(OUTb + (size_t)(n0 + col) * 64 + (quad * 2 + cc) * 8) = v;
    }
  }
}

// ======================= edge weight: 8 edges x 8 chunks per wave ============
// lane l: edge slot g=l>>3, channel chunk c=l&7 (channels c*8..c*8+7)
__global__ void __launch_bounds__(256) edgew_k(
    const int* __restrict__ S, const int* __restrict__ D,
    const float* __restrict__ EFX, const unsigned short* __restrict__ PA,
    const unsigned short* __restrict__ PB, const float* __restrict__ W1C,
    const float* __restrict__ B1, const float* __restrict__ W2,
    const float* __restrict__ B2, float* __restrict__ EW, int E) {
  const int l = threadIdx.x & 63;
  const int g = l >> 3, c = l & 7;
  // per-lane weight sub-block for its 8 channels (amortized over grid-stride)
  float wc[8][8];
#pragma unroll
  for (int i = 0; i < 8; ++i) {
    const float4 v0 = *(const float4*)(W1C + i * 64 + c * 8);
    const float4 v1 = *(const float4*)(W1C + i * 64 + c * 8 + 4);
    wc[i][0] = v0.x; wc[i][1] = v0.y; wc[i][2] = v0.z; wc[i][3] = v0.w;
    wc[i][4] = v1.x; wc[i][5] = v1.y; wc[i][6] = v1.z; wc[i][7] = v1.w;
  }
  float w2c[8], b1c[8];
  {
    const float4 a0 = *(const float4*)(W2 + c * 8);
    const float4 a1 = *(const float4*)(W2 + c * 8 + 4);
    w2c[0] = a0.x; w2c[1] = a0.y; w2c[2] = a0.z; w2c[3] = a0.w;
    w2c[4] = a1.x; w2c[5] = a1.y; w2c[6] = a1.z; w2c[7] = a1.w;
    const float4 b0 = *(const float4*)(B1 + c * 8);
    const float4 b1 = *(const float4*)(B1 + c * 8 + 4);
    b1c[0] = b0.x; b1c[1] = b0.y; b1c[2] = b0.z; b1c[3] = b0.w;
    b1c[4] = b1.x; b1c[5] = b1.y; b1c[6] = b1.z; b1c[7] = b1.w;
  }
  const float b2 = B2[0];
  const int wave_id = blockIdx.x * 4 + (threadIdx.x >> 6);
  const int nwaves = gridDim.x * 4;
  for (int t0 = wave_id * 8; t0 < E; t0 += nwaves * 8) {
    const int e = t0 + g;
    const bool ok = e < E;
    const int ee = ok ? e : E - 1;
    const int s = S[ee], d = D[ee];
    const bf16x8 pa = *(const bf16x8*)(PA + (size_t)s * 64 + c * 8);
    const bf16x8 pb = *(const bf16x8*)(PB + (size_t)d * 64 + c * 8);
    const float4 ef0 = *(const float4*)(EFX + (size_t)ee * 8);
    const float4 ef1 = *(const float4*)(EFX + (size_t)ee * 8 + 4);
    const unsigned* pau = (const unsigned*)&pa;
    const unsigned* pbu = (const unsigned*)&pb;
    float h[8];
#pragma unroll
    for (int q = 0; q < 4; ++q) {
      h[2 * q] = __uint_as_float(pau[q] << 16) +
                 __uint_as_float(pbu[q] << 16) + b1c[2 * q];
      h[2 * q + 1] = __uint_as_float(pau[q] & 0xffff0000u) +
                     __uint_as_float(pbu[q] & 0xffff0000u) + b1c[2 * q + 1];
    }
    const float ef[8] = {ef0.x, ef0.y, ef0.z, ef0.w, ef1.x, ef1.y, ef1.z, ef1.w};
#pragma unroll
    for (int i = 0; i < 8; ++i)
#pragma unroll
      for (int j = 0; j < 8; ++j) h[j] = fmaf(ef[i], wc[i][j], h[j]);
    float t = 0.0f;
#pragma unroll
    for (int j = 0; j < 8; ++j) t = fmaf(fmaxf(h[j], 0.0f), w2c[j], t);
#pragma unroll
    for (int off = 1; off < 8; off <<= 1) t += __shfl_xor(t, off, 64);
    if (ok && c == 0) EW[e] = sigmoid_f(t + b2);
  }
}

// ======================= CSR aggregation: 8 edges x 8 chunks per wave ========
__global__ void __launch_bounds__(256) agg_k(
    const int* __restrict__ row_ptr, const int2* __restrict__ adj,
    const float* __restrict__ degi, const unsigned short* __restrict__ MSGb,
    unsigned short* __restrict__ AGGb, int base, int N) {
  const int l = threadIdx.x & 63;
  const int n = blockIdx.x * 4 + (threadIdx.x >> 6);
  if (n >= N) return;
  const int g = l >> 3, c = l & 7;
  const int s = row_ptr[base + n], e = row_ptr[base + n + 1];
  float acc[8];
#pragma unroll
  for (int j = 0; j < 8; ++j) acc[j] = 0.0f;
  for (int p0 = s; p0 < e; p0 += 8) {
    const int pe = p0 + g;
    const bool ok = pe < e;
    const int2 av = adj[ok ? pe : s];
    const float w = ok ? __int_as_float(av.y) : 0.0f;
    const bf16x8 m = *(const bf16x8*)(MSGb + (size_t)av.x * 64 + c * 8);
    const unsigned* mu = (const unsigned*)&m;
#pragma unroll
    for (int q = 0; q < 4; ++q) {
      const float lo = __uint_as_float(mu[q] << 16);
      const float hi = __uint_as_float(mu[q] & 0xffff0000u);
      acc[2 * q] = fmaf(lo, w, acc[2 * q]);
      acc[2 * q + 1] = fmaf(hi, w, acc[2 * q + 1]);
    }
  }
  // reduce across the 8 edge slots (lanes 8,16,32 apart share a chunk)
#pragma unroll
  for (int off = 8; off < 64; off <<= 1)
#pragma unroll
    for (int j = 0; j < 8; ++j) acc[j] += __shfl_xor(acc[j], off, 64);
  if (g == 0) {
    const float di = degi[base + n];
    unsigned out[4];
#pragma unroll
    for (int q = 0; q < 4; ++q)
      out[q] = (unsigned)f2bf(acc[2 * q] * di) |
               ((unsigned)f2bf(acc[2 * q + 1] * di) << 16);
    *(uint4*)(AGGb + (size_t)n * 64 + c * 8) =
        make_uint4(out[0], out[1], out[2], out[3]);
  }
}

// ======================= CSR build: count, scan, fill, deg ===================
__global__ void __launch_bounds__(256) count_k(
    const int* __restrict__ S, const int* __restrict__ D,
    int* __restrict__ counts, int baseD, int baseS, int E) {
  const int e = blockIdx.x * 256 + threadIdx.x;
  if (e >= E) return;
  atomicAdd(&counts[baseD + D[e]], 1);
  atomicAdd(&counts[baseS + S[e]], 1);
}

__global__ void __launch_bounds__(256) fill_k(
    const int* __restrict__ S, const int* __restrict__ D,
    const float* __restrict__ EW, int* __restrict__ cursor,
    int2* __restrict__ adj, int baseD, int baseS, int E) {
  const int e = blockIdx.x * 256 + threadIdx.x;
  if (e >= E) return;
  const int s = S[e], d = D[e];
  const int wb = __float_as_int(EW[e]);
  int p = atomicAdd(&cursor[baseD + d], 1);
  adj[p] = make_int2(s, wb);
  p = atomicAdd(&cursor[baseS + s], 1);
  adj[p] = make_int2(d, wb);
}

__global__ void __launch_bounds__(256) degi_k(const int* __restrict__ row_ptr,
                                             const int2* __restrict__ adj,
                                             float* __restrict__ degi) {
  const int r = blockIdx.x * 256 + threadIdx.x;
  if (r >= R_TOT) return;
  const int s = row_ptr[r], e = row_ptr[r + 1];
  float d = 0.0f;
  for (int p = s; p < e; ++p) d += __int_as_float(adj[p].y);
  degi[r] = 1.0f / fmaxf(d, 1.0f);
}

__global__ void __launch_bounds__(256) scan1_k(const int* __restrict__ in,
                                               int* __restrict__ bsum) {
  __shared__ int sd[256];
  const int t = threadIdx.x;
  const int base = blockIdx.x * SCAN_CHUNK + t * 8;
  int s = 0;
#pragma unroll
  for (int i = 0; i < 8; ++i) {
    const int idx = base + i;
    s += (idx < R_TOT) ? in[idx] : 0;
  }
  sd[t] = s;
  __syncthreads();
  for (int off = 128; off > 0; off >>= 1) {
    if (t < off) sd[t] += sd[t + off];
    __syncthreads();
  }
  if (t == 0) bsum[blockIdx.x] = sd[0];
}

__global__ void __launch_bounds__(256) scan2_k(int* __restrict__ bsum,
                                               int* __restrict__ row_ptr) {
  __shared__ int sd[256];
  const int t = threadIdx.x;
  const int v = (t < SCAN_NB) ? bsum[t] : 0;
  sd[t] = v;
  __syncthreads();
  for (int off = 1; off < 256; off <<= 1) {
    const int add = (t >= off) ? sd[t - off] : 0;
    __syncthreads();
    sd[t] += add;
    __syncthreads();
  }
  if (t < SCAN_NB) bsum[t] = sd[t] - v;
  if (t == 255) row_ptr[R_TOT] = sd[255];
}

__global__ void __launch_bounds__(256) scan3_k(const int* __restrict__ in,
                                               const int* __restrict__ bsum,
                                               int* __restrict__ out) {
  __shared__ int sd[256];
  const int t = threadIdx.x;
  const int base = blockIdx.x * SCAN_CHUNK + t * 8;
  int loc[8];
  int s = 0;
#pragma unroll
  for (int i = 0; i < 8; ++i) {
    loc[i] = s;
    const int idx = base + i;
    s += (idx < R_TOT) ? in[idx] : 0;
  }
  sd[t] = s;
  __syncthreads();
  const int v = s;
  for (int off = 1; off < 256; off <<= 1) {
    const int add = (t >= off) ? sd[t - off] : 0;
    __syncthreads();
    sd[t] += add;
    __syncthreads();
  }
  const int off0 = bsum[blockIdx.x] + (sd[t] - v);
#pragma unroll
  for (int i = 0; i < 8; ++i) {
    const int idx = base + i;
    if (idx < R_TOT) out[idx] = off0 + loc[i];
  }
}

}  // namespace

extern "C" void kernel_launch(void* const* d_in, const int* in_sizes, int n_in,
                              void* d_out, int out_size, void* d_ws, size_t ws_size,
                              hipStream_t stream) {
  (void)in_sizes; (void)n_in; (void)out_size; (void)ws_size;

  const float* variable_features   = (const float*)d_in[0];
  const float* constraint_features = (const float*)d_in[1];
  const float* cut_features        = (const float*)d_in[2];
  const float* vc_ef = (const float*)d_in[3];
  const float* vk_ef = (const float*)d_in[4];
  const int* vc_edges = (const int*)d_in[5];
  const int* vk_edges = (const int*)d_in[6];
  const int *vc_s = vc_edges, *vc_d = vc_edges + EVC;
  const int *vk_s = vk_edges, *vk_d = vk_edges + EVK;
  const float* var_w1  = (const float*)d_in[7];
  const float* var_b1  = (const float*)d_in[8];
  const float* var_w2  = (const float*)d_in[9];
  const float* var_b2  = (const float*)d_in[10];
  const float* cons_w1 = (const float*)d_in[11];
  const float* cons_b1 = (const float*)d_in[12];
  const float* cons_w2 = (const float*)d_in[13];
  const float* cons_b2 = (const float*)d_in[14];
  const float* cut_w1  = (const float*)d_in[15];
  const float* cut_b1  = (const float*)d_in[16];
  const float* cut_w2  = (const float*)d_in[17];
  const float* cut_b2  = (const float*)d_in[18];
  const float* ewvc_w1 = (const float*)d_in[19];
  const float* ewvc_b1 = (const float*)d_in[20];
  const float* ewvc_w2 = (const float*)d_in[21];
  const float* ewvc_b2 = (const float*)d_in[22];
  const float* ewvk_w1 = (const float*)d_in[23];
  const float* ewvk_b1 = (const float*)d_in[24];
  const float* ewvk_w2 = (const float*)d_in[25];
  const float* ewvk_b2 = (const float*)d_in[26];
  const float* mp_msg_w1 = (const float*)d_in[27];
  const float* mp_msg_b1 = (const float*)d_in[28];
  const float* mp_msg_w2 = (const float*)d_in[29];
  const float* mp_msg_b2 = (const float*)d_in[30];
  const float* mp_gate_w = (const float*)d_in[31];
  const float* mp_gate_b = (const float*)d_in[32];
  const float* mp_upd_w1 = (const float*)d_in[33];
  const float* mp_upd_b1 = (const float*)d_in[34];
  const float* mp_upd_w2 = (const float*)d_in[35];
  const float* mp_upd_b2 = (const float*)d_in[36];
  const float* mp_ln_g   = (const float*)d_in[37];
  const float* mp_ln_b   = (const float*)d_in[38];

  // ---- workspace carve ----
  char* wp = (char*)d_ws;
  auto take = [&](size_t nbytes) {
    char* p = wp;
    wp += (nbytes + 255) & ~(size_t)255;
    return p;
  };
  float* h_var_f  = (float*)take((size_t)NV * 64 * 4);
  float* h_cons_f = (float*)take((size_t)NC * 64 * 4);
  float* h_cut_f  = (float*)take((size_t)NK * 64 * 4);
  unsigned short* h_var_b  = (unsigned short*)take((size_t)NV * 64 * 2);
  unsigned short* h_cons_b = (unsigned short*)take((size_t)NC * 64 * 2);
  unsigned short* h_cut_b  = (unsigned short*)take((size_t)NK * 64 * 2);
  unsigned short* msg_b = (unsigned short*)take((size_t)NV * 64 * 2);
  unsigned short* agg_b = (unsigned short*)take((size_t)NV * 64 * 2);
  unsigned short* pa = (unsigned short*)take((size_t)NV * 64 * 2);
  unsigned short* pb = (unsigned short*)take((size_t)NC * 64 * 2);
  unsigned short* qa = (unsigned short*)take((size_t)NV * 64 * 2);
  unsigned short* qb = (unsigned short*)take((size_t)NK * 64 * 2);
  unsigned short* packW = (unsigned short*)take((size_t)15 * PACK_PER_LAYER * 2);
  float* ew_vc = (float*)take((size_t)EVC * 4);
  float* ew_vk = (float*)take((size_t)EVK * 4);
  int* row_ptr = (int*)take((size_t)(R_TOT + 1) * 4);
  int* cursor  = (int*)take((size_t)R_TOT * 4);
  int* counts  = (int*)take((size_t)R_TOT * 4);
  int* bsum    = (int*)take(256 * 4);
  float* degi  = (float*)take((size_t)R_TOT * 4);
  int2* adj    = (int2*)take((size_t)(2 * EVC + 2 * EVK) * 8);

  // ---- CSR counts + scan ----
  hipMemsetAsync(counts, 0, (size_t)R_TOT * 4, stream);
  count_k<<<(EVC + 255) / 256, 256, 0, stream>>>(vc_s, vc_d, counts, 0, NC, EVC);
  count_k<<<(EVK + 255) / 256, 256, 0, stream>>>(vk_s, vk_d, counts, NC + NV,
                                                 NC + NV + NK, EVK);
  scan1_k<<<SCAN_NB, 256, 0, stream>>>(counts, bsum);
  scan2_k<<<1, 256, 0, stream>>>(bsum, row_ptr);
  scan3_k<<<SCAN_NB, 256, 0, stream>>>(counts, bsum, row_ptr);

  // ---- embeddings (dual fp32 + bf16) ----
  mlp2_node_k<19><<<(NV + 255) / 256, 256, 0, stream>>>(
      variable_features, var_w1, var_b1, var_w2, var_b2, h_var_f, h_var_b, NV);
  mlp2_node_k<5><<<(NC + 255) / 256, 256, 0, stream>>>(
      constraint_features, cons_w1, cons_b1, cons_w2, cons_b2, h_cons_f, h_cons_b, NC);
  mlp2_node_k<30><<<(NK + 255) / 256, 256, 0, stream>>>(
      cut_features, cut_w1, cut_b1, cut_w2, cut_b2, h_cut_f, h_cut_b, NK);

  // ---- pack MP weights to bf16 B-frag streams ----
  pack_k<<<15, 256, 0, stream>>>(mp_msg_w1, mp_msg_w2, mp_gate_w, mp_upd_w1,
                                 mp_upd_w2, packW);

  // ---- edge weights: per-node terms (bf16) then per-edge combine ----
  gemv64_k<<<(NV + 255) / 256, 256, 0, stream>>>(h_var_f, ewvc_w1, pa, NV);
  gemv64_k<<<(NC + 255) / 256, 256, 0, stream>>>(h_cons_f, ewvc_w1 + 64 * 64, pb, NC);
  gemv64_k<<<(NV + 255) / 256, 256, 0, stream>>>(h_var_f, ewvk_w1, qa, NV);
  gemv64_k<<<(NK + 255) / 256, 256, 0, stream>>>(h_cut_f, ewvk_w1 + 64 * 64, qb, NK);
  edgew_k<<<1024, 256, 0, stream>>>(vc_s, vc_d, vc_ef, pa, pb,
                                    ewvc_w1 + 128 * 64, ewvc_b1, ewvc_w2,
                                    ewvc_b2, ew_vc, EVC);
  edgew_k<<<512, 256, 0, stream>>>(vk_s, vk_d, vk_ef, qa, qb,
                                   ewvk_w1 + 128 * 64, ewvk_b1, ewvk_w2,
                                   ewvk_b2, ew_vk, EVK);

  // ---- CSR fill + per-row 1/deg ----
  hipMemcpyAsync(cursor, row_ptr, (size_t)R_TOT * 4, hipMemcpyDeviceToDevice, stream);
  fill_k<<<(EVC + 255) / 256, 256, 0, stream>>>(vc_s, vc_d, ew_vc, cursor, adj,
                                                0, NC, EVC);
  fill_k<<<(EVK + 255) / 256, 256, 0, stream>>>(vk_s, vk_d, ew_vk, cursor, adj,
                                                NC + NV, NC + NV + NK, EVK);
  degi_k<<<(R_TOT + 255) / 256, 256, 0, stream>>>(row_ptr, adj, degi);

  // ---- 15 message passes (16th only updates h_var -> dead, skipped) ----
  const unsigned short* neigh_t[4] = {h_var_b, h_cons_b, h_var_b, h_cut_b};
  unsigned short* nodeb_t[4] = {h_cons_b, h_var_b, h_cut_b, h_var_b};
  float* nodef_t[4] = {h_cons_f, h_var_f, h_cut_f, h_var_f};
  const int Nn_t[4] = {NV, NC, NV, NK};
  const int Nd_t[4] = {NC, NV, NK, NV};
  const int base_t[4] = {0, NC, NC + NV, NC + NV + NK};

  for (int i = 0; i < 15; ++i) {
    const int d = i & 3;
    const int Nn = Nn_t[d], Nd = Nd_t[d], base = base_t[d];
    const unsigned short* Wl = packW + (size_t)i * PACK_PER_LAYER;

    msg_mfma_k<<<(Nn + 63) / 64, 256, 0, stream>>>(
        neigh_t[d], Wl, mp_msg_b1 + (size_t)i * 64, mp_msg_b2 + (size_t)i * 64,
        msg_b, Nn);
    agg_k<<<(Nd + 3) / 4, 256, 0, stream>>>(row_ptr, adj, degi, msg_b, agg_b,
                                            base, Nd);
    float* outf = (i == 14) ? (float*)d_out : nodef_t[d];
    upd_mfma_k<<<(Nd + 63) / 64, 256, 0, stream>>>(
        agg_b, nodeb_t[d], nodef_t[d], Wl + 8192, Wl + 16384, Wl + 24576,
        mp_gate_b + (size_t)i * 64, mp_upd_b1 + (size_t)i * 64,
        mp_upd_b2 + (size_t)i * 64, mp_ln_g + (size_t)i * 64,
        mp_ln_b + (size_t)i * 64, outf, nodeb_t[d], Nd);
  }
}

// Round 5
// 1554.132 us; speedup vs baseline: 3.2216x; 1.0273x over previous
//
#include <hip/hip_runtime.h>

#define DEVINL static __device__ __forceinline__

namespace {

typedef __attribute__((ext_vector_type(8))) short bf16x8;
typedef __attribute__((ext_vector_type(4))) float f32x4;

constexpr int NV = 100000;   // variables
constexpr int NC = 50000;    // constraints
constexpr int NK = 20000;    // cuts
constexpr int EVC = 800000;  // var-cons edges
constexpr int EVK = 200000;  // var-cut edges
constexpr int R_TOT = NC + NV + NK + NV;  // 270000 CSR rows
constexpr int SCAN_CHUNK = 2048;
constexpr int SCAN_NB = (R_TOT + SCAN_CHUNK - 1) / SCAN_CHUNK;  // 132
constexpr int PACK_PER_LAYER = 28672;  // ushort per layer of packed weights
constexpr float WQ_SCALE = 16383.0f;
constexpr float WQ_INV = 1.0f / 16383.0f;

DEVINL unsigned short f2bf(float f) {
  unsigned u = __float_as_uint(f);
  u = u + 0x7fffu + ((u >> 16) & 1u);  // RNE
  return (unsigned short)(u >> 16);
}
DEVINL float bf2f(unsigned short h) {
  return __uint_as_float((unsigned)h << 16);
}

DEVINL float sigmoid_f(float x) { return 1.0f / (1.0f + __expf(-x)); }

// ======================= embeddings (run once, fp32 VALU, bf16 out) ==========
template <int DIN>
__global__ void __launch_bounds__(256) mlp2_node_k(
    const float* __restrict__ X, const float* __restrict__ W1,
    const float* __restrict__ B1, const float* __restrict__ W2,
    const float* __restrict__ B2, unsigned short* __restrict__ OUTb, int N) {
  const int n = blockIdx.x * 256 + threadIdx.x;
  if (n >= N) return;
  float h[64];
#pragma unroll
  for (int c = 0; c < 64; ++c) h[c] = B1[c];
  float x[DIN];
#pragma unroll
  for (int k = 0; k < DIN; ++k) x[k] = X[(size_t)n * DIN + k];
#pragma unroll
  for (int k = 0; k < DIN; ++k) {
    const float xk = x[k];
    const float* wr = W1 + k * 64;
#pragma unroll
    for (int c = 0; c < 64; ++c) h[c] = fmaf(xk, wr[c], h[c]);
  }
#pragma unroll
  for (int c = 0; c < 64; ++c) h[c] = fmaxf(h[c], 0.0f);
  float o[64];
#pragma unroll
  for (int c = 0; c < 64; ++c) o[c] = B2[c];
#pragma unroll
  for (int k = 0; k < 64; ++k) {
    const float hk = h[k];
    const float* wr = W2 + k * 64;
#pragma unroll
    for (int c = 0; c < 64; ++c) o[c] = fmaf(hk, wr[c], o[c]);
  }
  unsigned* pb = reinterpret_cast<unsigned*>(OUTb + (size_t)n * 64);
#pragma unroll
  for (int q = 0; q < 32; ++q)
    pb[q] = (unsigned)f2bf(o[2 * q]) | ((unsigned)f2bf(o[2 * q + 1]) << 16);
}

// ---- single-layer GEMV (edge-weight per-node terms), bf16 in/out, opt bias --
__global__ void __launch_bounds__(256) gemv64_k(
    const unsigned short* __restrict__ Xb, const float* __restrict__ W,
    const float* __restrict__ Bias, unsigned short* __restrict__ OUTb, int N) {
  const int n = blockIdx.x * 256 + threadIdx.x;
  if (n >= N) return;
  float acc[64];
  if (Bias) {
#pragma unroll
    for (int c = 0; c < 64; ++c) acc[c] = Bias[c];
  } else {
#pragma unroll
    for (int c = 0; c < 64; ++c) acc[c] = 0.0f;
  }
  const unsigned short* xr = Xb + (size_t)n * 64;
  for (int kc = 0; kc < 8; ++kc) {
    const bf16x8 xv = *(const bf16x8*)(xr + kc * 8);
    const unsigned* xu = (const unsigned*)&xv;
    float x[8];
#pragma unroll
    for (int q = 0; q < 4; ++q) {
      x[2 * q] = __uint_as_float(xu[q] << 16);
      x[2 * q + 1] = __uint_as_float(xu[q] & 0xffff0000u);
    }
#pragma unroll
    for (int k = 0; k < 8; ++k) {
      const float xk = x[k];
      const float* wr = W + (kc * 8 + k) * 64;
#pragma unroll
      for (int c = 0; c < 64; ++c) acc[c] = fmaf(xk, wr[c], acc[c]);
    }
  }
  unsigned* pb = reinterpret_cast<unsigned*>(OUTb + (size_t)n * 64);
#pragma unroll
  for (int q = 0; q < 32; ++q)
    pb[q] = (unsigned)f2bf(acc[2 * q]) | ((unsigned)f2bf(acc[2 * q + 1]) << 16);
}

// ======================= weight packing (bf16 B-frag stream) =================
__global__ void __launch_bounds__(256) pack_k(
    const float* __restrict__ mW1, const float* __restrict__ mW2,
    const float* __restrict__ gW, const float* __restrict__ uW1,
    const float* __restrict__ uW2, unsigned short* __restrict__ PW) {
  const int layer = blockIdx.x;  // 0..14
  unsigned short* out = PW + (size_t)layer * PACK_PER_LAYER;
  const float* srcs[5] = {mW1 + (size_t)layer * 4096, mW2 + (size_t)layer * 4096,
                          gW + (size_t)layer * 8192, uW1 + (size_t)layer * 8192,
                          uW2 + (size_t)layer * 4096};
  const int Ks[5] = {64, 64, 128, 128, 64};
  const int offs[5] = {0, 4096, 8192, 16384, 24576};
  for (int m = 0; m < 5; ++m) {
    const float* src = srcs[m];
    unsigned short* o = out + offs[m];
    const int ntup = (Ks[m] / 32) * 256;
    for (int tup = threadIdx.x; tup < ntup; tup += 256) {
      const int lane = tup & 63;
      const int t = (tup >> 6) & 3;
      const int kb = tup >> 8;
      const int c = t * 16 + (lane & 15);
      const int k0 = kb * 32 + (lane >> 4) * 8;
#pragma unroll
      for (int jj = 0; jj < 8; ++jj) o[tup * 8 + jj] = f2bf(src[(k0 + jj) * 64 + c]);
    }
  }
}

// ======================= message MLP (MFMA) =================================
__global__ void __launch_bounds__(256) msg_mfma_k(
    const unsigned short* __restrict__ Xb, const unsigned short* __restrict__ Wp,
    const float* __restrict__ B1, const float* __restrict__ B2,
    unsigned short* __restrict__ MSGb, int N) {
  __shared__ unsigned short lds[4][16 * 72];
  const int wave = threadIdx.x >> 6, l = threadIdx.x & 63;
  const int col = l & 15, quad = l >> 4;
  const int n0_raw = blockIdx.x * 64 + wave * 16;
  const bool dead = n0_raw >= N;
  const int n0 = dead ? 0 : n0_raw;

  const unsigned short* xrow = Xb + (size_t)(n0 + col) * 64 + quad * 8;
  const bf16x8 a0 = *(const bf16x8*)xrow;
  const bf16x8 a1 = *(const bf16x8*)(xrow + 32);
  const bf16x8* W1p = (const bf16x8*)Wp;
  const bf16x8* W2p = (const bf16x8*)(Wp + 4096);

  f32x4 acc[4];
#pragma unroll
  for (int t = 0; t < 4; ++t) {
    const float b = B1[col + 16 * t];
    acc[t] = f32x4{b, b, b, b};
  }
#pragma unroll
  for (int t = 0; t < 4; ++t) {
    acc[t] = __builtin_amdgcn_mfma_f32_16x16x32_bf16(a0, W1p[t * 64 + l], acc[t], 0, 0, 0);
    acc[t] = __builtin_amdgcn_mfma_f32_16x16x32_bf16(a1, W1p[(4 + t) * 64 + l], acc[t], 0, 0, 0);
  }
  unsigned short* ld = lds[wave];
#pragma unroll
  for (int t = 0; t < 4; ++t)
#pragma unroll
    for (int r = 0; r < 4; ++r)
      ld[(quad * 4 + r) * 72 + col + 16 * t] = f2bf(fmaxf(acc[t][r], 0.0f));
  __syncthreads();
  const bf16x8 h0 = *(const bf16x8*)&ld[col * 72 + quad * 8];
  const bf16x8 h1 = *(const bf16x8*)&ld[col * 72 + 32 + quad * 8];
  f32x4 o[4];
#pragma unroll
  for (int t = 0; t < 4; ++t) {
    const float b = B2[col + 16 * t];
    o[t] = f32x4{b, b, b, b};
  }
#pragma unroll
  for (int t = 0; t < 4; ++t) {
    o[t] = __builtin_amdgcn_mfma_f32_16x16x32_bf16(h0, W2p[t * 64 + l], o[t], 0, 0, 0);
    o[t] = __builtin_amdgcn_mfma_f32_16x16x32_bf16(h1, W2p[(4 + t) * 64 + l], o[t], 0, 0, 0);
  }
  __syncthreads();
#pragma unroll
  for (int t = 0; t < 4; ++t)
#pragma unroll
    for (int r = 0; r < 4; ++r)
      ld[(quad * 4 + r) * 72 + col + 16 * t] = f2bf(o[t][r]);
  __syncthreads();
  if (!dead) {
#pragma unroll
    for (int cc = 0; cc < 2; ++cc) {
      const bf16x8 v = *(const bf16x8*)&ld[col * 72 + (quad * 2 + cc) * 8];
      *(bf16x8*)(MSGb + (size_t)(n0 + col) * 64 + (quad * 2 + cc) * 8) = v;
    }
  }
}

// ======== fused gate + upd1 + upd2 + gate-mix + LayerNorm (MFMA) ============
// node carry is bf16; fp32 output written only when OUTf != nullptr (final pass)
__global__ void __launch_bounds__(256) upd_mfma_k(
    const unsigned short* __restrict__ AGGb, const unsigned short* __restrict__ NODEb,
    const unsigned short* __restrict__ gWp, const unsigned short* __restrict__ uW1p,
    const unsigned short* __restrict__ uW2p, const float* __restrict__ gB,
    const float* __restrict__ uB1, const float* __restrict__ uB2,
    const float* __restrict__ LNG, const float* __restrict__ LNB,
    float* __restrict__ OUTf, unsigned short* __restrict__ OUTb, int N) {
  __shared__ unsigned short lds[4][16 * 72];
  const int wave = threadIdx.x >> 6, l = threadIdx.x & 63;
  const int col = l & 15, quad = l >> 4;
  const int n0_raw = blockIdx.x * 64 + wave * 16;
  const bool dead = n0_raw >= N;
  const int n0 = dead ? 0 : n0_raw;

  const unsigned short* arow = AGGb + (size_t)(n0 + col) * 64 + quad * 8;
  const unsigned short* nrow = NODEb + (size_t)(n0 + col) * 64 + quad * 8;
  const bf16x8 aA0 = *(const bf16x8*)arow;
  const bf16x8 aA1 = *(const bf16x8*)(arow + 32);
  const bf16x8 aN0 = *(const bf16x8*)nrow;
  const bf16x8 aN1 = *(const bf16x8*)(nrow + 32);
  const bf16x8* gW = (const bf16x8*)gWp;
  const bf16x8* uW1 = (const bf16x8*)uW1p;
  const bf16x8* uW2 = (const bf16x8*)uW2p;

  f32x4 g[4], u[4];
#pragma unroll
  for (int t = 0; t < 4; ++t) {
    const float bg = gB[col + 16 * t], bu = uB1[col + 16 * t];
    g[t] = f32x4{bg, bg, bg, bg};
    u[t] = f32x4{bu, bu, bu, bu};
  }
#pragma unroll
  for (int t = 0; t < 4; ++t) {
    g[t] = __builtin_amdgcn_mfma_f32_16x16x32_bf16(aA0, gW[t * 64 + l], g[t], 0, 0, 0);
    g[t] = __builtin_amdgcn_mfma_f32_16x16x32_bf16(aA1, gW[(4 + t) * 64 + l], g[t], 0, 0, 0);
    g[t] = __builtin_amdgcn_mfma_f32_16x16x32_bf16(aN0, gW[(8 + t) * 64 + l], g[t], 0, 0, 0);
    g[t] = __builtin_amdgcn_mfma_f32_16x16x32_bf16(aN1, gW[(12 + t) * 64 + l], g[t], 0, 0, 0);
    u[t] = __builtin_amdgcn_mfma_f32_16x16x32_bf16(aA0, uW1[t * 64 + l], u[t], 0, 0, 0);
    u[t] = __builtin_amdgcn_mfma_f32_16x16x32_bf16(aA1, uW1[(4 + t) * 64 + l], u[t], 0, 0, 0);
    u[t] = __builtin_amdgcn_mfma_f32_16x16x32_bf16(aN0, uW1[(8 + t) * 64 + l], u[t], 0, 0, 0);
    u[t] = __builtin_amdgcn_mfma_f32_16x16x32_bf16(aN1, uW1[(12 + t) * 64 + l], u[t], 0, 0, 0);
  }
#pragma unroll
  for (int t = 0; t < 4; ++t)
#pragma unroll
    for (int r = 0; r < 4; ++r) g[t][r] = sigmoid_f(g[t][r]);

  unsigned short* ld = lds[wave];
#pragma unroll
  for (int t = 0; t < 4; ++t)
#pragma unroll
    for (int r = 0; r < 4; ++r)
      ld[(quad * 4 + r) * 72 + col + 16 * t] = f2bf(fmaxf(u[t][r], 0.0f));
  __syncthreads();
  const bf16x8 h0 = *(const bf16x8*)&ld[col * 72 + quad * 8];
  const bf16x8 h1 = *(const bf16x8*)&ld[col * 72 + 32 + quad * 8];
  f32x4 o[4];
#pragma unroll
  for (int t = 0; t < 4; ++t) {
    const float b = uB2[col + 16 * t];
    o[t] = f32x4{b, b, b, b};
  }
#pragma unroll
  for (int t = 0; t < 4; ++t) {
    o[t] = __builtin_amdgcn_mfma_f32_16x16x32_bf16(h0, uW2[t * 64 + l], o[t], 0, 0, 0);
    o[t] = __builtin_amdgcn_mfma_f32_16x16x32_bf16(h1, uW2[(4 + t) * 64 + l], o[t], 0, 0, 0);
  }
  // gate mix (bf16 node carry, C-layout gather) + LayerNorm
  float om[4][4];
#pragma unroll
  for (int t = 0; t < 4; ++t)
#pragma unroll
    for (int r = 0; r < 4; ++r) {
      const float nd =
          bf2f(NODEb[(size_t)(n0 + quad * 4 + r) * 64 + col + 16 * t]);
      om[t][r] = fmaf(g[t][r], o[t][r] - nd, nd);
    }
  float outv[4][4];
#pragma unroll
  for (int r = 0; r < 4; ++r) {
    float s1 = (om[0][r] + om[1][r]) + (om[2][r] + om[3][r]);
    float s2 = fmaf(om[0][r], om[0][r], fmaf(om[1][r], om[1][r],
                fmaf(om[2][r], om[2][r], om[3][r] * om[3][r])));
#pragma unroll
    for (int off = 1; off < 16; off <<= 1) {
      s1 += __shfl_xor(s1, off, 64);
      s2 += __shfl_xor(s2, off, 64);
    }
    const float m = s1 * (1.0f / 64.0f);
    const float var = s2 * (1.0f / 64.0f) - m * m;
    const float rr = rsqrtf(var + 1e-3f);
#pragma unroll
    for (int t = 0; t < 4; ++t)
      outv[t][r] = fmaf((om[t][r] - m) * rr, LNG[col + 16 * t], LNB[col + 16 * t]);
  }
  if (OUTf != nullptr && !dead) {
#pragma unroll
    for (int t = 0; t < 4; ++t)
#pragma unroll
      for (int r = 0; r < 4; ++r)
        OUTf[(size_t)(n0 + quad * 4 + r) * 64 + col + 16 * t] = outv[t][r];
  }
  __syncthreads();
#pragma unroll
  for (int t = 0; t < 4; ++t)
#pragma unroll
    for (int r = 0; r < 4; ++r)
      ld[(quad * 4 + r) * 72 + col + 16 * t] = f2bf(outv[t][r]);
  __syncthreads();
  if (!dead) {
#pragma unroll
    for (int cc = 0; cc < 2; ++cc) {
      const bf16x8 v = *(const bf16x8*)&ld[col * 72 + (quad * 2 + cc) * 8];
      *(bf16x8*)(OUTb + (size_t)(n0 + col) * 64 + (quad * 2 + cc) * 8) = v;
    }
  }
}

// ======================= edge weight: 8 edges x 8 chunks per wave ============
// lane l: edge slot g=l>>3, channel chunk c=l&7; B1 pre-folded into PB
__global__ void __launch_bounds__(256) edgew_k(
    const int* __restrict__ S, const int* __restrict__ D,
    const float* __restrict__ EFX, const unsigned short* __restrict__ PA,
    const unsigned short* __restrict__ PB, const float* __restrict__ W1C,
    const float* __restrict__ W2, const float* __restrict__ B2,
    float* __restrict__ EW, int E) {
  const int l = threadIdx.x & 63;
  const int g = l >> 3, c = l & 7;
  float wc[8][8];
#pragma unroll
  for (int i = 0; i < 8; ++i) {
    const float4 v0 = *(const float4*)(W1C + i * 64 + c * 8);
    const float4 v1 = *(const float4*)(W1C + i * 64 + c * 8 + 4);
    wc[i][0] = v0.x; wc[i][1] = v0.y; wc[i][2] = v0.z; wc[i][3] = v0.w;
    wc[i][4] = v1.x; wc[i][5] = v1.y; wc[i][6] = v1.z; wc[i][7] = v1.w;
  }
  float w2c[8];
  {
    const float4 a0 = *(const float4*)(W2 + c * 8);
    const float4 a1 = *(const float4*)(W2 + c * 8 + 4);
    w2c[0] = a0.x; w2c[1] = a0.y; w2c[2] = a0.z; w2c[3] = a0.w;
    w2c[4] = a1.x; w2c[5] = a1.y; w2c[6] = a1.z; w2c[7] = a1.w;
  }
  const float b2 = B2[0];
  const int wave_id = blockIdx.x * 4 + (threadIdx.x >> 6);
  const int nwaves = gridDim.x * 4;
  for (int t0 = wave_id * 8; t0 < E; t0 += nwaves * 8) {
    const int e = t0 + g;
    const bool ok = e < E;
    const int ee = ok ? e : E - 1;
    const int s = S[ee], d = D[ee];
    const bf16x8 pa = *(const bf16x8*)(PA + (size_t)s * 64 + c * 8);
    const bf16x8 pb = *(const bf16x8*)(PB + (size_t)d * 64 + c * 8);
    const float4 ef0 = *(const float4*)(EFX + (size_t)ee * 8);
    const float4 ef1 = *(const float4*)(EFX + (size_t)ee * 8 + 4);
    const unsigned* pau = (const unsigned*)&pa;
    const unsigned* pbu = (const unsigned*)&pb;
    float h[8];
#pragma unroll
    for (int q = 0; q < 4; ++q) {
      h[2 * q] = __uint_as_float(pau[q] << 16) + __uint_as_float(pbu[q] << 16);
      h[2 * q + 1] = __uint_as_float(pau[q] & 0xffff0000u) +
                     __uint_as_float(pbu[q] & 0xffff0000u);
    }
    const float ef[8] = {ef0.x, ef0.y, ef0.z, ef0.w, ef1.x, ef1.y, ef1.z, ef1.w};
#pragma unroll
    for (int i = 0; i < 8; ++i)
#pragma unroll
      for (int j = 0; j < 8; ++j) h[j] = fmaf(ef[i], wc[i][j], h[j]);
    float t = 0.0f;
#pragma unroll
    for (int j = 0; j < 8; ++j) t = fmaf(fmaxf(h[j], 0.0f), w2c[j], t);
#pragma unroll
    for (int off = 1; off < 8; off <<= 1) t += __shfl_xor(t, off, 64);
    if (ok && c == 0) EW[e] = sigmoid_f(t + b2);
  }
}

// ======================= CSR aggregation: 8 edges x 8 chunks per wave ========
// adj entry: (nbr << 14) | w14  (w14 = weight * 16383, weight in (0,1))
__global__ void __launch_bounds__(256) agg_k(
    const int* __restrict__ row_ptr, const unsigned* __restrict__ adj,
    const float* __restrict__ degi, const unsigned short* __restrict__ MSGb,
    unsigned short* __restrict__ AGGb, int base, int N) {
  const int l = threadIdx.x & 63;
  const int n = blockIdx.x * 4 + (threadIdx.x >> 6);
  if (n >= N) return;
  const int g = l >> 3, c = l & 7;
  const int s = row_ptr[base + n], e = row_ptr[base + n + 1];
  float acc[8];
#pragma unroll
  for (int j = 0; j < 8; ++j) acc[j] = 0.0f;
  for (int p0 = s; p0 < e; p0 += 8) {
    const int pe = p0 + g;
    const bool ok = pe < e;
    const unsigned av = adj[ok ? pe : s];
    const float w = ok ? (float)(av & 16383u) * WQ_INV : 0.0f;
    const bf16x8 m = *(const bf16x8*)(MSGb + (size_t)(av >> 14) * 64 + c * 8);
    const unsigned* mu = (const unsigned*)&m;
#pragma unroll
    for (int q = 0; q < 4; ++q) {
      const float lo = __uint_as_float(mu[q] << 16);
      const float hi = __uint_as_float(mu[q] & 0xffff0000u);
      acc[2 * q] = fmaf(lo, w, acc[2 * q]);
      acc[2 * q + 1] = fmaf(hi, w, acc[2 * q + 1]);
    }
  }
#pragma unroll
  for (int off = 8; off < 64; off <<= 1)
#pragma unroll
    for (int j = 0; j < 8; ++j) acc[j] += __shfl_xor(acc[j], off, 64);
  if (g == 0) {
    const float di = degi[base + n];
    unsigned out[4];
#pragma unroll
    for (int q = 0; q < 4; ++q)
      out[q] = (unsigned)f2bf(acc[2 * q] * di) |
               ((unsigned)f2bf(acc[2 * q + 1] * di) << 16);
    *(uint4*)(AGGb + (size_t)n * 64 + c * 8) =
        make_uint4(out[0], out[1], out[2], out[3]);
  }
}

// ======================= CSR build: count, scan, fill, deg ===================
__global__ void __launch_bounds__(256) count_k(
    const int* __restrict__ S, const int* __restrict__ D,
    int* __restrict__ counts, int baseD, int baseS, int E) {
  const int e = blockIdx.x * 256 + threadIdx.x;
  if (e >= E) return;
  atomicAdd(&counts[baseD + D[e]], 1);
  atomicAdd(&counts[baseS + S[e]], 1);
}

__global__ void __launch_bounds__(256) fill_k(
    const int* __restrict__ S, const int* __restrict__ D,
    const float* __restrict__ EW, int* __restrict__ cursor,
    unsigned* __restrict__ adj, int baseD, int baseS, int E) {
  const int e = blockIdx.x * 256 + threadIdx.x;
  if (e >= E) return;
  const int s = S[e], d = D[e];
  const unsigned w14 = (unsigned)(EW[e] * WQ_SCALE + 0.5f);
  int p = atomicAdd(&cursor[baseD + d], 1);
  adj[p] = ((unsigned)s << 14) | w14;
  p = atomicAdd(&cursor[baseS + s], 1);
  adj[p] = ((unsigned)d << 14) | w14;
}

__global__ void __launch_bounds__(256) degi_k(const int* __restrict__ row_ptr,
                                             const unsigned* __restrict__ adj,
                                             float* __restrict__ degi) {
  const int r = blockIdx.x * 256 + threadIdx.x;
  if (r >= R_TOT) return;
  const int s = row_ptr[r], e = row_ptr[r + 1];
  float d = 0.0f;
  for (int p = s; p < e; ++p) d += (float)(adj[p] & 16383u) * WQ_INV;
  degi[r] = 1.0f / fmaxf(d, 1.0f);
}

__global__ void __launch_bounds__(256) scan1_k(const int* __restrict__ in,
                                               int* __restrict__ bsum) {
  __shared__ int sd[256];
  const int t = threadIdx.x;
  const int base = blockIdx.x * SCAN_CHUNK + t * 8;
  int s = 0;
#pragma unroll
  for (int i = 0; i < 8; ++i) {
    const int idx = base + i;
    s += (idx < R_TOT) ? in[idx] : 0;
  }
  sd[t] = s;
  __syncthreads();
  for (int off = 128; off > 0; off >>= 1) {
    if (t < off) sd[t] += sd[t + off];
    __syncthreads();
  }
  if (t == 0) bsum[blockIdx.x] = sd[0];
}

__global__ void __launch_bounds__(256) scan2_k(int* __restrict__ bsum,
                                               int* __restrict__ row_ptr) {
  __shared__ int sd[256];
  const int t = threadIdx.x;
  const int v = (t < SCAN_NB) ? bsum[t] : 0;
  sd[t] = v;
  __syncthreads();
  for (int off = 1; off < 256; off <<= 1) {
    const int add = (t >= off) ? sd[t - off] : 0;
    __syncthreads();
    sd[t] += add;
    __syncthreads();
  }
  if (t < SCAN_NB) bsum[t] = sd[t] - v;
  if (t == 255) row_ptr[R_TOT] = sd[255];
}

__global__ void __launch_bounds__(256) scan3_k(const int* __restrict__ in,
                                               const int* __restrict__ bsum,
                                               int* __restrict__ out) {
  __shared__ int sd[256];
  const int t = threadIdx.x;
  const int base = blockIdx.x * SCAN_CHUNK + t * 8;
  int loc[8];
  int s = 0;
#pragma unroll
  for (int i = 0; i < 8; ++i) {
    loc[i] = s;
    const int idx = base + i;
    s += (idx < R_TOT) ? in[idx] : 0;
  }
  sd[t] = s;
  __syncthreads();
  const int v = s;
  for (int off = 1; off < 256; off <<= 1) {
    const int add = (t >= off) ? sd[t - off] : 0;
    __syncthreads();
    sd[t] += add;
    __syncthreads();
  }
  const int off0 = bsum[blockIdx.x] + (sd[t] - v);
#pragma unroll
  for (int i = 0; i < 8; ++i) {
    const int idx = base + i;
    if (idx < R_TOT) out[idx] = off0 + loc[i];
  }
}

}  // namespace

extern "C" void kernel_launch(void* const* d_in, const int* in_sizes, int n_in,
                              void* d_out, int out_size, void* d_ws, size_t ws_size,
                              hipStream_t stream) {
  (void)in_sizes; (void)n_in; (void)out_size; (void)ws_size;

  const float* variable_features   = (const float*)d_in[0];
  const float* constraint_features = (const float*)d_in[1];
  const float* cut_features        = (const float*)d_in[2];
  const float* vc_ef = (const float*)d_in[3];
  const float* vk_ef = (const float*)d_in[4];
  const int* vc_edges = (const int*)d_in[5];
  const int* vk_edges = (const int*)d_in[6];
  const int *vc_s = vc_edges, *vc_d = vc_edges + EVC;
  const int *vk_s = vk_edges, *vk_d = vk_edges + EVK;
  const float* var_w1  = (const float*)d_in[7];
  const float* var_b1  = (const float*)d_in[8];
  const float* var_w2  = (const float*)d_in[9];
  const float* var_b2  = (const float*)d_in[10];
  const float* cons_w1 = (const float*)d_in[11];
  const float* cons_b1 = (const float*)d_in[12];
  const float* cons_w2 = (const float*)d_in[13];
  const float* cons_b2 = (const float*)d_in[14];
  const float* cut_w1  = (const float*)d_in[15];
  const float* cut_b1  = (const float*)d_in[16];
  const float* cut_w2  = (const float*)d_in[17];
  const float* cut_b2  = (const float*)d_in[18];
  const float* ewvc_w1 = (const float*)d_in[19];
  const float* ewvc_b1 = (const float*)d_in[20];
  const float* ewvc_w2 = (const float*)d_in[21];
  const float* ewvc_b2 = (const float*)d_in[22];
  const float* ewvk_w1 = (const float*)d_in[23];
  const float* ewvk_b1 = (const float*)d_in[24];
  const float* ewvk_w2 = (const float*)d_in[25];
  const float* ewvk_b2 = (const float*)d_in[26];
  const float* mp_msg_w1 = (const float*)d_in[27];
  const float* mp_msg_b1 = (const float*)d_in[28];
  const float* mp_msg_w2 = (const float*)d_in[29];
  const float* mp_msg_b2 = (const float*)d_in[30];
  const float* mp_gate_w = (const float*)d_in[31];
  const float* mp_gate_b = (const float*)d_in[32];
  const float* mp_upd_w1 = (const float*)d_in[33];
  const float* mp_upd_b1 = (const float*)d_in[34];
  const float* mp_upd_w2 = (const float*)d_in[35];
  const float* mp_upd_b2 = (const float*)d_in[36];
  const float* mp_ln_g   = (const float*)d_in[37];
  const float* mp_ln_b   = (const float*)d_in[38];

  // ---- workspace carve ----
  char* wp = (char*)d_ws;
  auto take = [&](size_t nbytes) {
    char* p = wp;
    wp += (nbytes + 255) & ~(size_t)255;
    return p;
  };
  unsigned short* h_var_b  = (unsigned short*)take((size_t)NV * 64 * 2);
  unsigned short* h_cons_b = (unsigned short*)take((size_t)NC * 64 * 2);
  unsigned short* h_cut_b  = (unsigned short*)take((size_t)NK * 64 * 2);
  unsigned short* msg_b = (unsigned short*)take((size_t)NV * 64 * 2);
  unsigned short* agg_b = (unsigned short*)take((size_t)NV * 64 * 2);
  unsigned short* pa = (unsigned short*)take((size_t)NV * 64 * 2);
  unsigned short* pb = (unsigned short*)take((size_t)NC * 64 * 2);
  unsigned short* qa = (unsigned short*)take((size_t)NV * 64 * 2);
  unsigned short* qb = (unsigned short*)take((size_t)NK * 64 * 2);
  unsigned short* packW = (unsigned short*)take((size_t)15 * PACK_PER_LAYER * 2);
  float* ew_vc = (float*)take((size_t)EVC * 4);
  float* ew_vk = (float*)take((size_t)EVK * 4);
  int* row_ptr = (int*)take((size_t)(R_TOT + 1) * 4);
  int* cursor  = (int*)take((size_t)R_TOT * 4);
  int* counts  = (int*)take((size_t)R_TOT * 4);
  int* bsum    = (int*)take(256 * 4);
  float* degi  = (float*)take((size_t)R_TOT * 4);
  unsigned* adj = (unsigned*)take((size_t)(2 * EVC + 2 * EVK) * 4);

  // ---- CSR counts + scan ----
  hipMemsetAsync(counts, 0, (size_t)R_TOT * 4, stream);
  count_k<<<(EVC + 255) / 256, 256, 0, stream>>>(vc_s, vc_d, counts, 0, NC, EVC);
  count_k<<<(EVK + 255) / 256, 256, 0, stream>>>(vk_s, vk_d, counts, NC + NV,
                                                 NC + NV + NK, EVK);
  scan1_k<<<SCAN_NB, 256, 0, stream>>>(counts, bsum);
  scan2_k<<<1, 256, 0, stream>>>(bsum, row_ptr);
  scan3_k<<<SCAN_NB, 256, 0, stream>>>(counts, bsum, row_ptr);

  // ---- embeddings (bf16) ----
  mlp2_node_k<19><<<(NV + 255) / 256, 256, 0, stream>>>(
      variable_features, var_w1, var_b1, var_w2, var_b2, h_var_b, NV);
  mlp2_node_k<5><<<(NC + 255) / 256, 256, 0, stream>>>(
      constraint_features, cons_w1, cons_b1, cons_w2, cons_b2, h_cons_b, NC);
  mlp2_node_k<30><<<(NK + 255) / 256, 256, 0, stream>>>(
      cut_features, cut_w1, cut_b1, cut_w2, cut_b2, h_cut_b, NK);

  // ---- pack MP weights to bf16 B-frag streams ----
  pack_k<<<15, 256, 0, stream>>>(mp_msg_w1, mp_msg_w2, mp_gate_w, mp_upd_w1,
                                 mp_upd_w2, packW);

  // ---- edge weights: per-node terms (B1 folded into dst term) ----
  gemv64_k<<<(NV + 255) / 256, 256, 0, stream>>>(h_var_b, ewvc_w1, nullptr, pa, NV);
  gemv64_k<<<(NC + 255) / 256, 256, 0, stream>>>(h_cons_b, ewvc_w1 + 64 * 64,
                                                 ewvc_b1, pb, NC);
  gemv64_k<<<(NV + 255) / 256, 256, 0, stream>>>(h_var_b, ewvk_w1, nullptr, qa, NV);
  gemv64_k<<<(NK + 255) / 256, 256, 0, stream>>>(h_cut_b, ewvk_w1 + 64 * 64,
                                                 ewvk_b1, qb, NK);
  edgew_k<<<1024, 256, 0, stream>>>(vc_s, vc_d, vc_ef, pa, pb,
                                    ewvc_w1 + 128 * 64, ewvc_w2, ewvc_b2,
                                    ew_vc, EVC);
  edgew_k<<<512, 256, 0, stream>>>(vk_s, vk_d, vk_ef, qa, qb,
                                   ewvk_w1 + 128 * 64, ewvk_w2, ewvk_b2,
                                   ew_vk, EVK);

  // ---- CSR fill (4 B packed adj) + per-row 1/deg ----
  hipMemcpyAsync(cursor, row_ptr, (size_t)R_TOT * 4, hipMemcpyDeviceToDevice, stream);
  fill_k<<<(EVC + 255) / 256, 256, 0, stream>>>(vc_s, vc_d, ew_vc, cursor, adj,
                                                0, NC, EVC);
  fill_k<<<(EVK + 255) / 256, 256, 0, stream>>>(vk_s, vk_d, ew_vk, cursor, adj,
                                                NC + NV, NC + NV + NK, EVK);
  degi_k<<<(R_TOT + 255) / 256, 256, 0, stream>>>(row_ptr, adj, degi);

  // ---- 15 message passes (16th only updates h_var -> dead, skipped) ----
  const unsigned short* neigh_t[4] = {h_var_b, h_cons_b, h_var_b, h_cut_b};
  unsigned short* nodeb_t[4] = {h_cons_b, h_var_b, h_cut_b, h_var_b};
  const int Nn_t[4] = {NV, NC, NV, NK};
  const int Nd_t[4] = {NC, NV, NK, NV};
  const int base_t[4] = {0, NC, NC + NV, NC + NV + NK};

  for (int i = 0; i < 15; ++i) {
    const int d = i & 3;
    const int Nn = Nn_t[d], Nd = Nd_t[d], base = base_t[d];
    const unsigned short* Wl = packW + (size_t)i * PACK_PER_LAYER;

    msg_mfma_k<<<(Nn + 63) / 64, 256, 0, stream>>>(
        neigh_t[d], Wl, mp_msg_b1 + (size_t)i * 64, mp_msg_b2 + (size_t)i * 64,
        msg_b, Nn);
    agg_k<<<(Nd + 3) / 4, 256, 0, stream>>>(row_ptr, adj, degi, msg_b, agg_b,
                                            base, Nd);
    float* outf = (i == 14) ? (float*)d_out : nullptr;
    upd_mfma_k<<<(Nd + 63) / 64, 256, 0, stream>>>(
        agg_b, nodeb_t[d], Wl + 8192, Wl + 16384, Wl + 24576,
        mp_gate_b + (size_t)i * 64, mp_upd_b1 + (size_t)i * 64,
        mp_upd_b2 + (size_t)i * 64, mp_ln_g + (size_t)i * 64,
        mp_ln_b + (size_t)i * 64, outf, nodeb_t[d], Nd);
  }
}

// Round 6
// 1499.545 us; speedup vs baseline: 3.3389x; 1.0364x over previous
//
#include <hip/hip_runtime.h>

#define DEVINL static __device__ __forceinline__

namespace {

typedef __attribute__((ext_vector_type(8))) short bf16x8;
typedef __attribute__((ext_vector_type(4))) float f32x4;

constexpr int NV = 100000;   // variables
constexpr int NC = 50000;    // constraints
constexpr int NK = 20000;    // cuts
constexpr int EVC = 800000;  // var-cons edges
constexpr int EVK = 200000;  // var-cut edges
constexpr int R_TOT = NC + NV + NK + NV;  // 270000 CSR rows
constexpr int SCAN_CHUNK = 2048;
constexpr int SCAN_NB = (R_TOT + SCAN_CHUNK - 1) / SCAN_CHUNK;  // 132
constexpr int PACK_PER_LAYER = 28672;  // ushort per layer of packed weights
constexpr float WQ_SCALE = 16383.0f;
constexpr float WQ_INV = 1.0f / 16383.0f;

DEVINL unsigned short f2bf(float f) {
  unsigned u = __float_as_uint(f);
  u = u + 0x7fffu + ((u >> 16) & 1u);  // RNE
  return (unsigned short)(u >> 16);
}
DEVINL float bf2f(unsigned short h) {
  return __uint_as_float((unsigned)h << 16);
}

DEVINL float sigmoid_f(float x) { return 1.0f / (1.0f + __expf(-x)); }

// ======================= embeddings (run once, fp32 VALU, bf16 out) ==========
template <int DIN>
__global__ void __launch_bounds__(256) mlp2_node_k(
    const float* __restrict__ X, const float* __restrict__ W1,
    const float* __restrict__ B1, const float* __restrict__ W2,
    const float* __restrict__ B2, unsigned short* __restrict__ OUTb, int N) {
  const int n = blockIdx.x * 256 + threadIdx.x;
  if (n >= N) return;
  float h[64];
#pragma unroll
  for (int c = 0; c < 64; ++c) h[c] = B1[c];
  float x[DIN];
#pragma unroll
  for (int k = 0; k < DIN; ++k) x[k] = X[(size_t)n * DIN + k];
#pragma unroll
  for (int k = 0; k < DIN; ++k) {
    const float xk = x[k];
    const float* wr = W1 + k * 64;
#pragma unroll
    for (int c = 0; c < 64; ++c) h[c] = fmaf(xk, wr[c], h[c]);
  }
#pragma unroll
  for (int c = 0; c < 64; ++c) h[c] = fmaxf(h[c], 0.0f);
  float o[64];
#pragma unroll
  for (int c = 0; c < 64; ++c) o[c] = B2[c];
#pragma unroll
  for (int k = 0; k < 64; ++k) {
    const float hk = h[k];
    const float* wr = W2 + k * 64;
#pragma unroll
    for (int c = 0; c < 64; ++c) o[c] = fmaf(hk, wr[c], o[c]);
  }
  unsigned* pb = reinterpret_cast<unsigned*>(OUTb + (size_t)n * 64);
#pragma unroll
  for (int q = 0; q < 32; ++q)
    pb[q] = (unsigned)f2bf(o[2 * q]) | ((unsigned)f2bf(o[2 * q + 1]) << 16);
}

// ---- single-layer GEMV (edge-weight per-node terms), bf16 in/out, opt bias --
__global__ void __launch_bounds__(256) gemv64_k(
    const unsigned short* __restrict__ Xb, const float* __restrict__ W,
    const float* __restrict__ Bias, unsigned short* __restrict__ OUTb, int N) {
  const int n = blockIdx.x * 256 + threadIdx.x;
  if (n >= N) return;
  float acc[64];
  if (Bias) {
#pragma unroll
    for (int c = 0; c < 64; ++c) acc[c] = Bias[c];
  } else {
#pragma unroll
    for (int c = 0; c < 64; ++c) acc[c] = 0.0f;
  }
  const unsigned short* xr = Xb + (size_t)n * 64;
  for (int kc = 0; kc < 8; ++kc) {
    const bf16x8 xv = *(const bf16x8*)(xr + kc * 8);
    const unsigned* xu = (const unsigned*)&xv;
    float x[8];
#pragma unroll
    for (int q = 0; q < 4; ++q) {
      x[2 * q] = __uint_as_float(xu[q] << 16);
      x[2 * q + 1] = __uint_as_float(xu[q] & 0xffff0000u);
    }
#pragma unroll
    for (int k = 0; k < 8; ++k) {
      const float xk = x[k];
      const float* wr = W + (kc * 8 + k) * 64;
#pragma unroll
      for (int c = 0; c < 64; ++c) acc[c] = fmaf(xk, wr[c], acc[c]);
    }
  }
  unsigned* pb = reinterpret_cast<unsigned*>(OUTb + (size_t)n * 64);
#pragma unroll
  for (int q = 0; q < 32; ++q)
    pb[q] = (unsigned)f2bf(acc[2 * q]) | ((unsigned)f2bf(acc[2 * q + 1]) << 16);
}

// ======================= weight packing (bf16 B-frag stream) =================
__global__ void __launch_bounds__(256) pack_k(
    const float* __restrict__ mW1, const float* __restrict__ mW2,
    const float* __restrict__ gW, const float* __restrict__ uW1,
    const float* __restrict__ uW2, unsigned short* __restrict__ PW) {
  const int layer = blockIdx.x;  // 0..14
  unsigned short* out = PW + (size_t)layer * PACK_PER_LAYER;
  const float* srcs[5] = {mW1 + (size_t)layer * 4096, mW2 + (size_t)layer * 4096,
                          gW + (size_t)layer * 8192, uW1 + (size_t)layer * 8192,
                          uW2 + (size_t)layer * 4096};
  const int Ks[5] = {64, 64, 128, 128, 64};
  const int offs[5] = {0, 4096, 8192, 16384, 24576};
  for (int m = 0; m < 5; ++m) {
    const float* src = srcs[m];
    unsigned short* o = out + offs[m];
    const int ntup = (Ks[m] / 32) * 256;
    for (int tup = threadIdx.x; tup < ntup; tup += 256) {
      const int lane = tup & 63;
      const int t = (tup >> 6) & 3;
      const int kb = tup >> 8;
      const int c = t * 16 + (lane & 15);
      const int k0 = kb * 32 + (lane >> 4) * 8;
#pragma unroll
      for (int jj = 0; jj < 8; ++jj) o[tup * 8 + jj] = f2bf(src[(k0 + jj) * 64 + c]);
    }
  }
}

// ======================= message MLP (MFMA) — used once for pass 0 ===========
__global__ void __launch_bounds__(256) msg_mfma_k(
    const unsigned short* __restrict__ Xb, const unsigned short* __restrict__ Wp,
    const float* __restrict__ B1, const float* __restrict__ B2,
    unsigned short* __restrict__ MSGb, int N) {
  __shared__ unsigned short lds[4][16 * 72];
  const int wave = threadIdx.x >> 6, l = threadIdx.x & 63;
  const int col = l & 15, quad = l >> 4;
  const int n0_raw = blockIdx.x * 64 + wave * 16;
  const bool dead = n0_raw >= N;
  const int n0 = dead ? 0 : n0_raw;

  const unsigned short* xrow = Xb + (size_t)(n0 + col) * 64 + quad * 8;
  const bf16x8 a0 = *(const bf16x8*)xrow;
  const bf16x8 a1 = *(const bf16x8*)(xrow + 32);
  const bf16x8* W1p = (const bf16x8*)Wp;
  const bf16x8* W2p = (const bf16x8*)(Wp + 4096);

  f32x4 acc[4];
#pragma unroll
  for (int t = 0; t < 4; ++t) {
    const float b = B1[col + 16 * t];
    acc[t] = f32x4{b, b, b, b};
  }
#pragma unroll
  for (int t = 0; t < 4; ++t) {
    acc[t] = __builtin_amdgcn_mfma_f32_16x16x32_bf16(a0, W1p[t * 64 + l], acc[t], 0, 0, 0);
    acc[t] = __builtin_amdgcn_mfma_f32_16x16x32_bf16(a1, W1p[(4 + t) * 64 + l], acc[t], 0, 0, 0);
  }
  unsigned short* ld = lds[wave];
#pragma unroll
  for (int t = 0; t < 4; ++t)
#pragma unroll
    for (int r = 0; r < 4; ++r)
      ld[(quad * 4 + r) * 72 + col + 16 * t] = f2bf(fmaxf(acc[t][r], 0.0f));
  __syncthreads();
  const bf16x8 h0 = *(const bf16x8*)&ld[col * 72 + quad * 8];
  const bf16x8 h1 = *(const bf16x8*)&ld[col * 72 + 32 + quad * 8];
  f32x4 o[4];
#pragma unroll
  for (int t = 0; t < 4; ++t) {
    const float b = B2[col + 16 * t];
    o[t] = f32x4{b, b, b, b};
  }
#pragma unroll
  for (int t = 0; t < 4; ++t) {
    o[t] = __builtin_amdgcn_mfma_f32_16x16x32_bf16(h0, W2p[t * 64 + l], o[t], 0, 0, 0);
    o[t] = __builtin_amdgcn_mfma_f32_16x16x32_bf16(h1, W2p[(4 + t) * 64 + l], o[t], 0, 0, 0);
  }
  __syncthreads();
#pragma unroll
  for (int t = 0; t < 4; ++t)
#pragma unroll
    for (int r = 0; r < 4; ++r)
      ld[(quad * 4 + r) * 72 + col + 16 * t] = f2bf(o[t][r]);
  __syncthreads();
  if (!dead) {
#pragma unroll
    for (int cc = 0; cc < 2; ++cc) {
      const bf16x8 v = *(const bf16x8*)&ld[col * 72 + (quad * 2 + cc) * 8];
      *(bf16x8*)(MSGb + (size_t)(n0 + col) * 64 + (quad * 2 + cc) * 8) = v;
    }
  }
}

// ==== fused: upd(i) [gate+upd1+upd2+mix+LN] + msg(i+1) over the same rows ====
// WITH_MSG=1: after writing the updated node, immediately run the NEXT layer's
// message MLP on it (node rows are already in LDS in A-frag order).
template <int WITH_MSG>
__global__ void __launch_bounds__(256) updmsg_mfma_k(
    const unsigned short* __restrict__ AGGb, const unsigned short* __restrict__ NODEb,
    const unsigned short* __restrict__ gWp, const unsigned short* __restrict__ uW1p,
    const unsigned short* __restrict__ uW2p, const float* __restrict__ gB,
    const float* __restrict__ uB1, const float* __restrict__ uB2,
    const float* __restrict__ LNG, const float* __restrict__ LNB,
    const unsigned short* __restrict__ mWp,  // next layer msg W1|W2 (packed)
    const float* __restrict__ mB1, const float* __restrict__ mB2,
    float* __restrict__ OUTf, unsigned short* __restrict__ OUTb,
    unsigned short* __restrict__ MSGb, int N) {
  __shared__ unsigned short lds[4][16 * 72];
  const int wave = threadIdx.x >> 6, l = threadIdx.x & 63;
  const int col = l & 15, quad = l >> 4;
  const int n0_raw = blockIdx.x * 64 + wave * 16;
  const bool dead = n0_raw >= N;
  const int n0 = dead ? 0 : n0_raw;

  const unsigned short* arow = AGGb + (size_t)(n0 + col) * 64 + quad * 8;
  const unsigned short* nrow = NODEb + (size_t)(n0 + col) * 64 + quad * 8;
  const bf16x8 aA0 = *(const bf16x8*)arow;
  const bf16x8 aA1 = *(const bf16x8*)(arow + 32);
  const bf16x8 aN0 = *(const bf16x8*)nrow;
  const bf16x8 aN1 = *(const bf16x8*)(nrow + 32);
  const bf16x8* gW = (const bf16x8*)gWp;
  const bf16x8* uW1 = (const bf16x8*)uW1p;
  const bf16x8* uW2 = (const bf16x8*)uW2p;

  f32x4 g[4], u[4];
#pragma unroll
  for (int t = 0; t < 4; ++t) {
    const float bg = gB[col + 16 * t], bu = uB1[col + 16 * t];
    g[t] = f32x4{bg, bg, bg, bg};
    u[t] = f32x4{bu, bu, bu, bu};
  }
#pragma unroll
  for (int t = 0; t < 4; ++t) {
    g[t] = __builtin_amdgcn_mfma_f32_16x16x32_bf16(aA0, gW[t * 64 + l], g[t], 0, 0, 0);
    g[t] = __builtin_amdgcn_mfma_f32_16x16x32_bf16(aA1, gW[(4 + t) * 64 + l], g[t], 0, 0, 0);
    g[t] = __builtin_amdgcn_mfma_f32_16x16x32_bf16(aN0, gW[(8 + t) * 64 + l], g[t], 0, 0, 0);
    g[t] = __builtin_amdgcn_mfma_f32_16x16x32_bf16(aN1, gW[(12 + t) * 64 + l], g[t], 0, 0, 0);
    u[t] = __builtin_amdgcn_mfma_f32_16x16x32_bf16(aA0, uW1[t * 64 + l], u[t], 0, 0, 0);
    u[t] = __builtin_amdgcn_mfma_f32_16x16x32_bf16(aA1, uW1[(4 + t) * 64 + l], u[t], 0, 0, 0);
    u[t] = __builtin_amdgcn_mfma_f32_16x16x32_bf16(aN0, uW1[(8 + t) * 64 + l], u[t], 0, 0, 0);
    u[t] = __builtin_amdgcn_mfma_f32_16x16x32_bf16(aN1, uW1[(12 + t) * 64 + l], u[t], 0, 0, 0);
  }
#pragma unroll
  for (int t = 0; t < 4; ++t)
#pragma unroll
    for (int r = 0; r < 4; ++r) g[t][r] = sigmoid_f(g[t][r]);

  unsigned short* ld = lds[wave];
#pragma unroll
  for (int t = 0; t < 4; ++t)
#pragma unroll
    for (int r = 0; r < 4; ++r)
      ld[(quad * 4 + r) * 72 + col + 16 * t] = f2bf(fmaxf(u[t][r], 0.0f));
  __syncthreads();
  const bf16x8 h0 = *(const bf16x8*)&ld[col * 72 + quad * 8];
  const bf16x8 h1 = *(const bf16x8*)&ld[col * 72 + 32 + quad * 8];
  f32x4 o[4];
#pragma unroll
  for (int t = 0; t < 4; ++t) {
    const float b = uB2[col + 16 * t];
    o[t] = f32x4{b, b, b, b};
  }
#pragma unroll
  for (int t = 0; t < 4; ++t) {
    o[t] = __builtin_amdgcn_mfma_f32_16x16x32_bf16(h0, uW2[t * 64 + l], o[t], 0, 0, 0);
    o[t] = __builtin_amdgcn_mfma_f32_16x16x32_bf16(h1, uW2[(4 + t) * 64 + l], o[t], 0, 0, 0);
  }
  // gate mix (bf16 node carry, C-layout gather) + LayerNorm
  float om[4][4];
#pragma unroll
  for (int t = 0; t < 4; ++t)
#pragma unroll
    for (int r = 0; r < 4; ++r) {
      const float nd =
          bf2f(NODEb[(size_t)(n0 + quad * 4 + r) * 64 + col + 16 * t]);
      om[t][r] = fmaf(g[t][r], o[t][r] - nd, nd);
    }
  float outv[4][4];
#pragma unroll
  for (int r = 0; r < 4; ++r) {
    float s1 = (om[0][r] + om[1][r]) + (om[2][r] + om[3][r]);
    float s2 = fmaf(om[0][r], om[0][r], fmaf(om[1][r], om[1][r],
                fmaf(om[2][r], om[2][r], om[3][r] * om[3][r])));
#pragma unroll
    for (int off = 1; off < 16; off <<= 1) {
      s1 += __shfl_xor(s1, off, 64);
      s2 += __shfl_xor(s2, off, 64);
    }
    const float m = s1 * (1.0f / 64.0f);
    const float var = s2 * (1.0f / 64.0f) - m * m;
    const float rr = rsqrtf(var + 1e-3f);
#pragma unroll
    for (int t = 0; t < 4; ++t)
      outv[t][r] = fmaf((om[t][r] - m) * rr, LNG[col + 16 * t], LNB[col + 16 * t]);
  }
  if (OUTf != nullptr && !dead) {
#pragma unroll
    for (int t = 0; t < 4; ++t)
#pragma unroll
      for (int r = 0; r < 4; ++r)
        OUTf[(size_t)(n0 + quad * 4 + r) * 64 + col + 16 * t] = outv[t][r];
  }
  __syncthreads();
#pragma unroll
  for (int t = 0; t < 4; ++t)
#pragma unroll
    for (int r = 0; r < 4; ++r)
      ld[(quad * 4 + r) * 72 + col + 16 * t] = f2bf(outv[t][r]);
  __syncthreads();
  if (OUTb != nullptr && !dead) {
#pragma unroll
    for (int cc = 0; cc < 2; ++cc) {
      const bf16x8 v = *(const bf16x8*)&ld[col * 72 + (quad * 2 + cc) * 8];
      *(bf16x8*)(OUTb + (size_t)(n0 + col) * 64 + (quad * 2 + cc) * 8) = v;
    }
  }

  if constexpr (WITH_MSG) {
    // next layer's message MLP on the just-updated node rows (A-frags in LDS)
    const bf16x8 x0 = *(const bf16x8*)&ld[col * 72 + quad * 8];
    const bf16x8 x1 = *(const bf16x8*)&ld[col * 72 + 32 + quad * 8];
    const bf16x8* W1p = (const bf16x8*)mWp;
    const bf16x8* W2p = (const bf16x8*)(mWp + 4096);
    f32x4 macc[4];
#pragma unroll
    for (int t = 0; t < 4; ++t) {
      const float b = mB1[col + 16 * t];
      macc[t] = f32x4{b, b, b, b};
    }
#pragma unroll
    for (int t = 0; t < 4; ++t) {
      macc[t] = __builtin_amdgcn_mfma_f32_16x16x32_bf16(x0, W1p[t * 64 + l], macc[t], 0, 0, 0);
      macc[t] = __builtin_amdgcn_mfma_f32_16x16x32_bf16(x1, W1p[(4 + t) * 64 + l], macc[t], 0, 0, 0);
    }
    __syncthreads();
#pragma unroll
    for (int t = 0; t < 4; ++t)
#pragma unroll
      for (int r = 0; r < 4; ++r)
        ld[(quad * 4 + r) * 72 + col + 16 * t] = f2bf(fmaxf(macc[t][r], 0.0f));
    __syncthreads();
    const bf16x8 mh0 = *(const bf16x8*)&ld[col * 72 + quad * 8];
    const bf16x8 mh1 = *(const bf16x8*)&ld[col * 72 + 32 + quad * 8];
    f32x4 mo[4];
#pragma unroll
    for (int t = 0; t < 4; ++t) {
      const float b = mB2[col + 16 * t];
      mo[t] = f32x4{b, b, b, b};
    }
#pragma unroll
    for (int t = 0; t < 4; ++t) {
      mo[t] = __builtin_amdgcn_mfma_f32_16x16x32_bf16(mh0, W2p[t * 64 + l], mo[t], 0, 0, 0);
      mo[t] = __builtin_amdgcn_mfma_f32_16x16x32_bf16(mh1, W2p[(4 + t) * 64 + l], mo[t], 0, 0, 0);
    }
    __syncthreads();
#pragma unroll
    for (int t = 0; t < 4; ++t)
#pragma unroll
      for (int r = 0; r < 4; ++r)
        ld[(quad * 4 + r) * 72 + col + 16 * t] = f2bf(mo[t][r]);
    __syncthreads();
    if (!dead) {
#pragma unroll
      for (int cc = 0; cc < 2; ++cc) {
        const bf16x8 v = *(const bf16x8*)&ld[col * 72 + (quad * 2 + cc) * 8];
        *(bf16x8*)(MSGb + (size_t)(n0 + col) * 64 + (quad * 2 + cc) * 8) = v;
      }
    }
  }
}

// ======================= edge weight: 8 edges x 8 chunks per wave ============
__global__ void __launch_bounds__(256) edgew_k(
    const int* __restrict__ S, const int* __restrict__ D,
    const float* __restrict__ EFX, const unsigned short* __restrict__ PA,
    const unsigned short* __restrict__ PB, const float* __restrict__ W1C,
    const float* __restrict__ W2, const float* __restrict__ B2,
    float* __restrict__ EW, int E) {
  const int l = threadIdx.x & 63;
  const int g = l >> 3, c = l & 7;
  float wc[8][8];
#pragma unroll
  for (int i = 0; i < 8; ++i) {
    const float4 v0 = *(const float4*)(W1C + i * 64 + c * 8);
    const float4 v1 = *(const float4*)(W1C + i * 64 + c * 8 + 4);
    wc[i][0] = v0.x; wc[i][1] = v0.y; wc[i][2] = v0.z; wc[i][3] = v0.w;
    wc[i][4] = v1.x; wc[i][5] = v1.y; wc[i][6] = v1.z; wc[i][7] = v1.w;
  }
  float w2c[8];
  {
    const float4 a0 = *(const float4*)(W2 + c * 8);
    const float4 a1 = *(const float4*)(W2 + c * 8 + 4);
    w2c[0] = a0.x; w2c[1] = a0.y; w2c[2] = a0.z; w2c[3] = a0.w;
    w2c[4] = a1.x; w2c[5] = a1.y; w2c[6] = a1.z; w2c[7] = a1.w;
  }
  const float b2 = B2[0];
  const int wave_id = blockIdx.x * 4 + (threadIdx.x >> 6);
  const int nwaves = gridDim.x * 4;
  for (int t0 = wave_id * 8; t0 < E; t0 += nwaves * 8) {
    const int e = t0 + g;
    const bool ok = e < E;
    const int ee = ok ? e : E - 1;
    const int s = S[ee], d = D[ee];
    const bf16x8 pa = *(const bf16x8*)(PA + (size_t)s * 64 + c * 8);
    const bf16x8 pb = *(const bf16x8*)(PB + (size_t)d * 64 + c * 8);
    const float4 ef0 = *(const float4*)(EFX + (size_t)ee * 8);
    const float4 ef1 = *(const float4*)(EFX + (size_t)ee * 8 + 4);
    const unsigned* pau = (const unsigned*)&pa;
    const unsigned* pbu = (const unsigned*)&pb;
    float h[8];
#pragma unroll
    for (int q = 0; q < 4; ++q) {
      h[2 * q] = __uint_as_float(pau[q] << 16) + __uint_as_float(pbu[q] << 16);
      h[2 * q + 1] = __uint_as_float(pau[q] & 0xffff0000u) +
                     __uint_as_float(pbu[q] & 0xffff0000u);
    }
    const float ef[8] = {ef0.x, ef0.y, ef0.z, ef0.w, ef1.x, ef1.y, ef1.z, ef1.w};
#pragma unroll
    for (int i = 0; i < 8; ++i)
#pragma unroll
      for (int j = 0; j < 8; ++j) h[j] = fmaf(ef[i], wc[i][j], h[j]);
    float t = 0.0f;
#pragma unroll
    for (int j = 0; j < 8; ++j) t = fmaf(fmaxf(h[j], 0.0f), w2c[j], t);
#pragma unroll
    for (int off = 1; off < 8; off <<= 1) t += __shfl_xor(t, off, 64);
    if (ok && c == 0) EW[e] = sigmoid_f(t + b2);
  }
}

// ======================= CSR aggregation: 8 edges x 8 chunks per wave ========
// adj entry: (nbr << 14) | w14
__global__ void __launch_bounds__(256) agg_k(
    const int* __restrict__ row_ptr, const unsigned* __restrict__ adj,
    const float* __restrict__ degi, const unsigned short* __restrict__ MSGb,
    unsigned short* __restrict__ AGGb, int base, int N) {
  const int l = threadIdx.x & 63;
  const int n = blockIdx.x * 4 + (threadIdx.x >> 6);
  if (n >= N) return;
  const int g = l >> 3, c = l & 7;
  const int s = row_ptr[base + n], e = row_ptr[base + n + 1];
  float acc[8];
#pragma unroll
  for (int j = 0; j < 8; ++j) acc[j] = 0.0f;
  for (int p0 = s; p0 < e; p0 += 8) {
    const int pe = p0 + g;
    const bool ok = pe < e;
    const unsigned av = adj[ok ? pe : s];
    const float w = ok ? (float)(av & 16383u) * WQ_INV : 0.0f;
    const bf16x8 m = *(const bf16x8*)(MSGb + (size_t)(av >> 14) * 64 + c * 8);
    const unsigned* mu = (const unsigned*)&m;
#pragma unroll
    for (int q = 0; q < 4; ++q) {
      const float lo = __uint_as_float(mu[q] << 16);
      const float hi = __uint_as_float(mu[q] & 0xffff0000u);
      acc[2 * q] = fmaf(lo, w, acc[2 * q]);
      acc[2 * q + 1] = fmaf(hi, w, acc[2 * q + 1]);
    }
  }
#pragma unroll
  for (int off = 8; off < 64; off <<= 1)
#pragma unroll
    for (int j = 0; j < 8; ++j) acc[j] += __shfl_xor(acc[j], off, 64);
  if (g == 0) {
    const float di = degi[base + n];
    unsigned out[4];
#pragma unroll
    for (int q = 0; q < 4; ++q)
      out[q] = (unsigned)f2bf(acc[2 * q] * di) |
               ((unsigned)f2bf(acc[2 * q + 1] * di) << 16);
    *(uint4*)(AGGb + (size_t)n * 64 + c * 8) =
        make_uint4(out[0], out[1], out[2], out[3]);
  }
}

// ======================= CSR build: count, scan, fill, deg ===================
__global__ void __launch_bounds__(256) count_k(
    const int* __restrict__ S, const int* __restrict__ D,
    int* __restrict__ counts, int baseD, int baseS, int E) {
  const int e = blockIdx.x * 256 + threadIdx.x;
  if (e >= E) return;
  atomicAdd(&counts[baseD + D[e]], 1);
  atomicAdd(&counts[baseS + S[e]], 1);
}

__global__ void __launch_bounds__(256) fill_k(
    const int* __restrict__ S, const int* __restrict__ D,
    const float* __restrict__ EW, int* __restrict__ cursor,
    unsigned* __restrict__ adj, int baseD, int baseS, int E) {
  const int e = blockIdx.x * 256 + threadIdx.x;
  if (e >= E) return;
  const int s = S[e], d = D[e];
  const unsigned w14 = (unsigned)(EW[e] * WQ_SCALE + 0.5f);
  int p = atomicAdd(&cursor[baseD + d], 1);
  adj[p] = ((unsigned)s << 14) | w14;
  p = atomicAdd(&cursor[baseS + s], 1);
  adj[p] = ((unsigned)d << 14) | w14;
}

__global__ void __launch_bounds__(256) degi_k(const int* __restrict__ row_ptr,
                                             const unsigned* __restrict__ adj,
                                             float* __restrict__ degi) {
  const int r = blockIdx.x * 256 + threadIdx.x;
  if (r >= R_TOT) return;
  const int s = row_ptr[r], e = row_ptr[r + 1];
  float d = 0.0f;
  for (int p = s; p < e; ++p) d += (float)(adj[p] & 16383u) * WQ_INV;
  degi[r] = 1.0f / fmaxf(d, 1.0f);
}

__global__ void __launch_bounds__(256) scan1_k(const int* __restrict__ in,
                                               int* __restrict__ bsum) {
  __shared__ int sd[256];
  const int t = threadIdx.x;
  const int base = blockIdx.x * SCAN_CHUNK + t * 8;
  int s = 0;
#pragma unroll
  for (int i = 0; i < 8; ++i) {
    const int idx = base + i;
    s += (idx < R_TOT) ? in[idx] : 0;
  }
  sd[t] = s;
  __syncthreads();
  for (int off = 128; off > 0; off >>= 1) {
    if (t < off) sd[t] += sd[t + off];
    __syncthreads();
  }
  if (t == 0) bsum[blockIdx.x] = sd[0];
}

__global__ void __launch_bounds__(256) scan2_k(int* __restrict__ bsum,
                                               int* __restrict__ row_ptr) {
  __shared__ int sd[256];
  const int t = threadIdx.x;
  const int v = (t < SCAN_NB) ? bsum[t] : 0;
  sd[t] = v;
  __syncthreads();
  for (int off = 1; off < 256; off <<= 1) {
    const int add = (t >= off) ? sd[t - off] : 0;
    __syncthreads();
    sd[t] += add;
    __syncthreads();
  }
  if (t < SCAN_NB) bsum[t] = sd[t] - v;
  if (t == 255) row_ptr[R_TOT] = sd[255];
}

__global__ void __launch_bounds__(256) scan3_k(const int* __restrict__ in,
                                               const int* __restrict__ bsum,
                                               int* __restrict__ out) {
  __shared__ int sd[256];
  const int t = threadIdx.x;
  const int base = blockIdx.x * SCAN_CHUNK + t * 8;
  int loc[8];
  int s = 0;
#pragma unroll
  for (int i = 0; i < 8; ++i) {
    loc[i] = s;
    const int idx = base + i;
    s += (idx < R_TOT) ? in[idx] : 0;
  }
  sd[t] = s;
  __syncthreads();
  const int v = s;
  for (int off = 1; off < 256; off <<= 1) {
    const int add = (t >= off) ? sd[t - off] : 0;
    __syncthreads();
    sd[t] += add;
    __syncthreads();
  }
  const int off0 = bsum[blockIdx.x] + (sd[t] - v);
#pragma unroll
  for (int i = 0; i < 8; ++i) {
    const int idx = base + i;
    if (idx < R_TOT) out[idx] = off0 + loc[i];
  }
}

}  // namespace

extern "C" void kernel_launch(void* const* d_in, const int* in_sizes, int n_in,
                              void* d_out, int out_size, void* d_ws, size_t ws_size,
                              hipStream_t stream) {
  (void)in_sizes; (void)n_in; (void)out_size; (void)ws_size;

  const float* variable_features   = (const float*)d_in[0];
  const float* constraint_features = (const float*)d_in[1];
  const float* cut_features        = (const float*)d_in[2];
  const float* vc_ef = (const float*)d_in[3];
  const float* vk_ef = (const float*)d_in[4];
  const int* vc_edges = (const int*)d_in[5];
  const int* vk_edges = (const int*)d_in[6];
  const int *vc_s = vc_edges, *vc_d = vc_edges + EVC;
  const int *vk_s = vk_edges, *vk_d = vk_edges + EVK;
  const float* var_w1  = (const float*)d_in[7];
  const float* var_b1  = (const float*)d_in[8];
  const float* var_w2  = (const float*)d_in[9];
  const float* var_b2  = (const float*)d_in[10];
  const float* cons_w1 = (const float*)d_in[11];
  const float* cons_b1 = (const float*)d_in[12];
  const float* cons_w2 = (const float*)d_in[13];
  const float* cons_b2 = (const float*)d_in[14];
  const float* cut_w1  = (const float*)d_in[15];
  const float* cut_b1  = (const float*)d_in[16];
  const float* cut_w2  = (const float*)d_in[17];
  const float* cut_b2  = (const float*)d_in[18];
  const float* ewvc_w1 = (const float*)d_in[19];
  const float* ewvc_b1 = (const float*)d_in[20];
  const float* ewvc_w2 = (const float*)d_in[21];
  const float* ewvc_b2 = (const float*)d_in[22];
  const float* ewvk_w1 = (const float*)d_in[23];
  const float* ewvk_b1 = (const float*)d_in[24];
  const float* ewvk_w2 = (const float*)d_in[25];
  const float* ewvk_b2 = (const float*)d_in[26];
  const float* mp_msg_w1 = (const float*)d_in[27];
  const float* mp_msg_b1 = (const float*)d_in[28];
  const float* mp_msg_w2 = (const float*)d_in[29];
  const float* mp_msg_b2 = (const float*)d_in[30];
  const float* mp_gate_w = (const float*)d_in[31];
  const float* mp_gate_b = (const float*)d_in[32];
  const float* mp_upd_w1 = (const float*)d_in[33];
  const float* mp_upd_b1 = (const float*)d_in[34];
  const float* mp_upd_w2 = (const float*)d_in[35];
  const float* mp_upd_b2 = (const float*)d_in[36];
  const float* mp_ln_g   = (const float*)d_in[37];
  const float* mp_ln_b   = (const float*)d_in[38];

  // ---- workspace carve ----
  char* wp = (char*)d_ws;
  auto take = [&](size_t nbytes) {
    char* p = wp;
    wp += (nbytes + 255) & ~(size_t)255;
    return p;
  };
  unsigned short* h_var_b  = (unsigned short*)take((size_t)NV * 64 * 2);
  unsigned short* h_cons_b = (unsigned short*)take((size_t)NC * 64 * 2);
  unsigned short* h_cut_b  = (unsigned short*)take((size_t)NK * 64 * 2);
  unsigned short* msg_b = (unsigned short*)take((size_t)NV * 64 * 2);
  unsigned short* agg_b = (unsigned short*)take((size_t)NV * 64 * 2);
  unsigned short* pa = (unsigned short*)take((size_t)NV * 64 * 2);
  unsigned short* pb = (unsigned short*)take((size_t)NC * 64 * 2);
  unsigned short* qa = (unsigned short*)take((size_t)NV * 64 * 2);
  unsigned short* qb = (unsigned short*)take((size_t)NK * 64 * 2);
  unsigned short* packW = (unsigned short*)take((size_t)15 * PACK_PER_LAYER * 2);
  float* ew_vc = (float*)take((size_t)EVC * 4);
  float* ew_vk = (float*)take((size_t)EVK * 4);
  int* row_ptr = (int*)take((size_t)(R_TOT + 1) * 4);
  int* cursor  = (int*)take((size_t)R_TOT * 4);
  int* counts  = (int*)take((size_t)R_TOT * 4);
  int* bsum    = (int*)take(256 * 4);
  float* degi  = (float*)take((size_t)R_TOT * 4);
  unsigned* adj = (unsigned*)take((size_t)(2 * EVC + 2 * EVK) * 4);

  // ---- CSR counts + scan ----
  hipMemsetAsync(counts, 0, (size_t)R_TOT * 4, stream);
  count_k<<<(EVC + 255) / 256, 256, 0, stream>>>(vc_s, vc_d, counts, 0, NC, EVC);
  count_k<<<(EVK + 255) / 256, 256, 0, stream>>>(vk_s, vk_d, counts, NC + NV,
                                                 NC + NV + NK, EVK);
  scan1_k<<<SCAN_NB, 256, 0, stream>>>(counts, bsum);
  scan2_k<<<1, 256, 0, stream>>>(bsum, row_ptr);
  scan3_k<<<SCAN_NB, 256, 0, stream>>>(counts, bsum, row_ptr);

  // ---- embeddings (bf16) ----
  mlp2_node_k<19><<<(NV + 255) / 256, 256, 0, stream>>>(
      variable_features, var_w1, var_b1, var_w2, var_b2, h_var_b, NV);
  mlp2_node_k<5><<<(NC + 255) / 256, 256, 0, stream>>>(
      constraint_features, cons_w1, cons_b1, cons_w2, cons_b2, h_cons_b, NC);
  mlp2_node_k<30><<<(NK + 255) / 256, 256, 0, stream>>>(
      cut_features, cut_w1, cut_b1, cut_w2, cut_b2, h_cut_b, NK);

  // ---- pack MP weights to bf16 B-frag streams ----
  pack_k<<<15, 256, 0, stream>>>(mp_msg_w1, mp_msg_w2, mp_gate_w, mp_upd_w1,
                                 mp_upd_w2, packW);

  // ---- edge weights: per-node terms (B1 folded into dst term) ----
  gemv64_k<<<(NV + 255) / 256, 256, 0, stream>>>(h_var_b, ewvc_w1, nullptr, pa, NV);
  gemv64_k<<<(NC + 255) / 256, 256, 0, stream>>>(h_cons_b, ewvc_w1 + 64 * 64,
                                                 ewvc_b1, pb, NC);
  gemv64_k<<<(NV + 255) / 256, 256, 0, stream>>>(h_var_b, ewvk_w1, nullptr, qa, NV);
  gemv64_k<<<(NK + 255) / 256, 256, 0, stream>>>(h_cut_b, ewvk_w1 + 64 * 64,
                                                 ewvk_b1, qb, NK);
  edgew_k<<<1024, 256, 0, stream>>>(vc_s, vc_d, vc_ef, pa, pb,
                                    ewvc_w1 + 128 * 64, ewvc_w2, ewvc_b2,
                                    ew_vc, EVC);
  edgew_k<<<512, 256, 0, stream>>>(vk_s, vk_d, vk_ef, qa, qb,
                                   ewvk_w1 + 128 * 64, ewvk_w2, ewvk_b2,
                                   ew_vk, EVK);

  // ---- CSR fill (4 B packed adj) + per-row 1/deg ----
  hipMemcpyAsync(cursor, row_ptr, (size_t)R_TOT * 4, hipMemcpyDeviceToDevice, stream);
  fill_k<<<(EVC + 255) / 256, 256, 0, stream>>>(vc_s, vc_d, ew_vc, cursor, adj,
                                                0, NC, EVC);
  fill_k<<<(EVK + 255) / 256, 256, 0, stream>>>(vk_s, vk_d, ew_vk, cursor, adj,
                                                NC + NV, NC + NV + NK, EVK);
  degi_k<<<(R_TOT + 255) / 256, 256, 0, stream>>>(row_ptr, adj, degi);

  // ---- 15 message passes; upd(i) fused with msg(i+1) ----
  unsigned short* nodeb_t[4] = {h_cons_b, h_var_b, h_cut_b, h_var_b};
  const int Nd_t[4] = {NC, NV, NK, NV};
  const int base_t[4] = {0, NC, NC + NV, NC + NV + NK};

  // msg(0): over h_var with layer-0 msg weights
  msg_mfma_k<<<(NV + 63) / 64, 256, 0, stream>>>(
      h_var_b, packW, mp_msg_b1, mp_msg_b2, msg_b, NV);

  for (int i = 0; i < 15; ++i) {
    const int d = i & 3;
    const int Nd = Nd_t[d], base = base_t[d];
    const unsigned short* Wl = packW + (size_t)i * PACK_PER_LAYER;

    agg_k<<<(Nd + 3) / 4, 256, 0, stream>>>(row_ptr, adj, degi, msg_b, agg_b,
                                            base, Nd);
    if (i < 14) {
      const unsigned short* Wn = packW + (size_t)(i + 1) * PACK_PER_LAYER;
      updmsg_mfma_k<1><<<(Nd + 63) / 64, 256, 0, stream>>>(
          agg_b, nodeb_t[d], Wl + 8192, Wl + 16384, Wl + 24576,
          mp_gate_b + (size_t)i * 64, mp_upd_b1 + (size_t)i * 64,
          mp_upd_b2 + (size_t)i * 64, mp_ln_g + (size_t)i * 64,
          mp_ln_b + (size_t)i * 64, Wn, mp_msg_b1 + (size_t)(i + 1) * 64,
          mp_msg_b2 + (size_t)(i + 1) * 64, nullptr, nodeb_t[d], msg_b, Nd);
    } else {
      // final pass: write fp32 d_out only (node/message no longer needed)
      updmsg_mfma_k<0><<<(Nd + 63) / 64, 256, 0, stream>>>(
          agg_b, nodeb_t[d], Wl + 8192, Wl + 16384, Wl + 24576,
          mp_gate_b + (size_t)i * 64, mp_upd_b1 + (size_t)i * 64,
          mp_upd_b2 + (size_t)i * 64, mp_ln_g + (size_t)i * 64,
          mp_ln_b + (size_t)i * 64, nullptr, nullptr, nullptr,
          (float*)d_out, nullptr, nullptr, Nd);
    }
  }
}

// Round 7
// 1453.342 us; speedup vs baseline: 3.4451x; 1.0318x over previous
//
#include <hip/hip_runtime.h>

#define DEVINL static __device__ __forceinline__

namespace {

typedef __attribute__((ext_vector_type(8))) short bf16x8;
typedef __attribute__((ext_vector_type(4))) float f32x4;

constexpr int NV = 100000;   // variables
constexpr int NC = 50000;    // constraints
constexpr int NK = 20000;    // cuts
constexpr int EVC = 800000;  // var-cons edges
constexpr int EVK = 200000;  // var-cut edges
constexpr int R_TOT = NC + NV + NK + NV;  // 270000 CSR rows
constexpr int SCAN_CHUNK = 2048;
constexpr int SCAN_NB = (R_TOT + SCAN_CHUNK - 1) / SCAN_CHUNK;  // 132
constexpr int PACK_PER_LAYER = 28672;  // ushort per layer of packed weights
constexpr float WQ_SCALE = 16383.0f;
constexpr float WQ_INV = 1.0f / 16383.0f;
constexpr int NBIN = 8;  // fill bins; blockIdx%8 aligns with XCD round-robin

DEVINL unsigned short f2bf(float f) {
  unsigned u = __float_as_uint(f);
  u = u + 0x7fffu + ((u >> 16) & 1u);  // RNE
  return (unsigned short)(u >> 16);
}
DEVINL float bf2f(unsigned short h) {
  return __uint_as_float((unsigned)h << 16);
}

DEVINL float sigmoid_f(float x) { return 1.0f / (1.0f + __expf(-x)); }

// ======================= embeddings (run once, fp32 VALU, bf16 out) ==========
template <int DIN>
__global__ void __launch_bounds__(256) mlp2_node_k(
    const float* __restrict__ X, const float* __restrict__ W1,
    const float* __restrict__ B1, const float* __restrict__ W2,
    const float* __restrict__ B2, unsigned short* __restrict__ OUTb, int N) {
  const int n = blockIdx.x * 256 + threadIdx.x;
  if (n >= N) return;
  float h[64];
#pragma unroll
  for (int c = 0; c < 64; ++c) h[c] = B1[c];
  float x[DIN];
#pragma unroll
  for (int k = 0; k < DIN; ++k) x[k] = X[(size_t)n * DIN + k];
#pragma unroll
  for (int k = 0; k < DIN; ++k) {
    const float xk = x[k];
    const float* wr = W1 + k * 64;
#pragma unroll
    for (int c = 0; c < 64; ++c) h[c] = fmaf(xk, wr[c], h[c]);
  }
#pragma unroll
  for (int c = 0; c < 64; ++c) h[c] = fmaxf(h[c], 0.0f);
  float o[64];
#pragma unroll
  for (int c = 0; c < 64; ++c) o[c] = B2[c];
#pragma unroll
  for (int k = 0; k < 64; ++k) {
    const float hk = h[k];
    const float* wr = W2 + k * 64;
#pragma unroll
    for (int c = 0; c < 64; ++c) o[c] = fmaf(hk, wr[c], o[c]);
  }
  unsigned* pb = reinterpret_cast<unsigned*>(OUTb + (size_t)n * 64);
#pragma unroll
  for (int q = 0; q < 32; ++q)
    pb[q] = (unsigned)f2bf(o[2 * q]) | ((unsigned)f2bf(o[2 * q + 1]) << 16);
}

// ---- single-layer GEMV (edge-weight per-node terms), bf16 in/out, opt bias --
__global__ void __launch_bounds__(256) gemv64_k(
    const unsigned short* __restrict__ Xb, const float* __restrict__ W,
    const float* __restrict__ Bias, unsigned short* __restrict__ OUTb, int N) {
  const int n = blockIdx.x * 256 + threadIdx.x;
  if (n >= N) return;
  float acc[64];
  if (Bias) {
#pragma unroll
    for (int c = 0; c < 64; ++c) acc[c] = Bias[c];
  } else {
#pragma unroll
    for (int c = 0; c < 64; ++c) acc[c] = 0.0f;
  }
  const unsigned short* xr = Xb + (size_t)n * 64;
  for (int kc = 0; kc < 8; ++kc) {
    const bf16x8 xv = *(const bf16x8*)(xr + kc * 8);
    const unsigned* xu = (const unsigned*)&xv;
    float x[8];
#pragma unroll
    for (int q = 0; q < 4; ++q) {
      x[2 * q] = __uint_as_float(xu[q] << 16);
      x[2 * q + 1] = __uint_as_float(xu[q] & 0xffff0000u);
    }
#pragma unroll
    for (int k = 0; k < 8; ++k) {
      const float xk = x[k];
      const float* wr = W + (kc * 8 + k) * 64;
#pragma unroll
      for (int c = 0; c < 64; ++c) acc[c] = fmaf(xk, wr[c], acc[c]);
    }
  }
  unsigned* pb = reinterpret_cast<unsigned*>(OUTb + (size_t)n * 64);
#pragma unroll
  for (int q = 0; q < 32; ++q)
    pb[q] = (unsigned)f2bf(acc[2 * q]) | ((unsigned)f2bf(acc[2 * q + 1]) << 16);
}

// ======================= weight packing (bf16 B-frag stream) =================
__global__ void __launch_bounds__(256) pack_k(
    const float* __restrict__ mW1, const float* __restrict__ mW2,
    const float* __restrict__ gW, const float* __restrict__ uW1,
    const float* __restrict__ uW2, unsigned short* __restrict__ PW) {
  const int layer = blockIdx.x;  // 0..14
  unsigned short* out = PW + (size_t)layer * PACK_PER_LAYER;
  const float* srcs[5] = {mW1 + (size_t)layer * 4096, mW2 + (size_t)layer * 4096,
                          gW + (size_t)layer * 8192, uW1 + (size_t)layer * 8192,
                          uW2 + (size_t)layer * 4096};
  const int Ks[5] = {64, 64, 128, 128, 64};
  const int offs[5] = {0, 4096, 8192, 16384, 24576};
  for (int m = 0; m < 5; ++m) {
    const float* src = srcs[m];
    unsigned short* o = out + offs[m];
    const int ntup = (Ks[m] / 32) * 256;
    for (int tup = threadIdx.x; tup < ntup; tup += 256) {
      const int lane = tup & 63;
      const int t = (tup >> 6) & 3;
      const int kb = tup >> 8;
      const int c = t * 16 + (lane & 15);
      const int k0 = kb * 32 + (lane >> 4) * 8;
#pragma unroll
      for (int jj = 0; jj < 8; ++jj) o[tup * 8 + jj] = f2bf(src[(k0 + jj) * 64 + c]);
    }
  }
}

// ======================= message MLP (MFMA) — used once for pass 0 ===========
__global__ void __launch_bounds__(256) msg_mfma_k(
    const unsigned short* __restrict__ Xb, const unsigned short* __restrict__ Wp,
    const float* __restrict__ B1, const float* __restrict__ B2,
    unsigned short* __restrict__ MSGb, int N) {
  __shared__ unsigned short lds[4][16 * 72];
  const int wave = threadIdx.x >> 6, l = threadIdx.x & 63;
  const int col = l & 15, quad = l >> 4;
  const int n0_raw = blockIdx.x * 64 + wave * 16;
  const bool dead = n0_raw >= N;
  const int n0 = dead ? 0 : n0_raw;

  const unsigned short* xrow = Xb + (size_t)(n0 + col) * 64 + quad * 8;
  const bf16x8 a0 = *(const bf16x8*)xrow;
  const bf16x8 a1 = *(const bf16x8*)(xrow + 32);
  const bf16x8* W1p = (const bf16x8*)Wp;
  const bf16x8* W2p = (const bf16x8*)(Wp + 4096);

  f32x4 acc[4];
#pragma unroll
  for (int t = 0; t < 4; ++t) {
    const float b = B1[col + 16 * t];
    acc[t] = f32x4{b, b, b, b};
  }
#pragma unroll
  for (int t = 0; t < 4; ++t) {
    acc[t] = __builtin_amdgcn_mfma_f32_16x16x32_bf16(a0, W1p[t * 64 + l], acc[t], 0, 0, 0);
    acc[t] = __builtin_amdgcn_mfma_f32_16x16x32_bf16(a1, W1p[(4 + t) * 64 + l], acc[t], 0, 0, 0);
  }
  unsigned short* ld = lds[wave];
#pragma unroll
  for (int t = 0; t < 4; ++t)
#pragma unroll
    for (int r = 0; r < 4; ++r)
      ld[(quad * 4 + r) * 72 + col + 16 * t] = f2bf(fmaxf(acc[t][r], 0.0f));
  __syncthreads();
  const bf16x8 h0 = *(const bf16x8*)&ld[col * 72 + quad * 8];
  const bf16x8 h1 = *(const bf16x8*)&ld[col * 72 + 32 + quad * 8];
  f32x4 o[4];
#pragma unroll
  for (int t = 0; t < 4; ++t) {
    const float b = B2[col + 16 * t];
    o[t] = f32x4{b, b, b, b};
  }
#pragma unroll
  for (int t = 0; t < 4; ++t) {
    o[t] = __builtin_amdgcn_mfma_f32_16x16x32_bf16(h0, W2p[t * 64 + l], o[t], 0, 0, 0);
    o[t] = __builtin_amdgcn_mfma_f32_16x16x32_bf16(h1, W2p[(4 + t) * 64 + l], o[t], 0, 0, 0);
  }
  __syncthreads();
#pragma unroll
  for (int t = 0; t < 4; ++t)
#pragma unroll
    for (int r = 0; r < 4; ++r)
      ld[(quad * 4 + r) * 72 + col + 16 * t] = f2bf(o[t][r]);
  __syncthreads();
  if (!dead) {
#pragma unroll
    for (int cc = 0; cc < 2; ++cc) {
      const bf16x8 v = *(const bf16x8*)&ld[col * 72 + (quad * 2 + cc) * 8];
      *(bf16x8*)(MSGb + (size_t)(n0 + col) * 64 + (quad * 2 + cc) * 8) = v;
    }
  }
}

// ==== fused: upd(i) [gate+upd1+upd2+mix+LN] + msg(i+1) over the same rows ====
template <int WITH_MSG>
__global__ void __launch_bounds__(256) updmsg_mfma_k(
    const unsigned short* __restrict__ AGGb, const unsigned short* __restrict__ NODEb,
    const unsigned short* __restrict__ gWp, const unsigned short* __restrict__ uW1p,
    const unsigned short* __restrict__ uW2p, const float* __restrict__ gB,
    const float* __restrict__ uB1, const float* __restrict__ uB2,
    const float* __restrict__ LNG, const float* __restrict__ LNB,
    const unsigned short* __restrict__ mWp,  // next layer msg W1|W2 (packed)
    const float* __restrict__ mB1, const float* __restrict__ mB2,
    float* __restrict__ OUTf, unsigned short* __restrict__ OUTb,
    unsigned short* __restrict__ MSGb, int N) {
  __shared__ unsigned short lds[4][16 * 72];
  const int wave = threadIdx.x >> 6, l = threadIdx.x & 63;
  const int col = l & 15, quad = l >> 4;
  const int n0_raw = blockIdx.x * 64 + wave * 16;
  const bool dead = n0_raw >= N;
  const int n0 = dead ? 0 : n0_raw;

  const unsigned short* arow = AGGb + (size_t)(n0 + col) * 64 + quad * 8;
  const unsigned short* nrow = NODEb + (size_t)(n0 + col) * 64 + quad * 8;
  const bf16x8 aA0 = *(const bf16x8*)arow;
  const bf16x8 aA1 = *(const bf16x8*)(arow + 32);
  const bf16x8 aN0 = *(const bf16x8*)nrow;
  const bf16x8 aN1 = *(const bf16x8*)(nrow + 32);
  const bf16x8* gW = (const bf16x8*)gWp;
  const bf16x8* uW1 = (const bf16x8*)uW1p;
  const bf16x8* uW2 = (const bf16x8*)uW2p;

  f32x4 g[4], u[4];
#pragma unroll
  for (int t = 0; t < 4; ++t) {
    const float bg = gB[col + 16 * t], bu = uB1[col + 16 * t];
    g[t] = f32x4{bg, bg, bg, bg};
    u[t] = f32x4{bu, bu, bu, bu};
  }
#pragma unroll
  for (int t = 0; t < 4; ++t) {
    g[t] = __builtin_amdgcn_mfma_f32_16x16x32_bf16(aA0, gW[t * 64 + l], g[t], 0, 0, 0);
    g[t] = __builtin_amdgcn_mfma_f32_16x16x32_bf16(aA1, gW[(4 + t) * 64 + l], g[t], 0, 0, 0);
    g[t] = __builtin_amdgcn_mfma_f32_16x16x32_bf16(aN0, gW[(8 + t) * 64 + l], g[t], 0, 0, 0);
    g[t] = __builtin_amdgcn_mfma_f32_16x16x32_bf16(aN1, gW[(12 + t) * 64 + l], g[t], 0, 0, 0);
    u[t] = __builtin_amdgcn_mfma_f32_16x16x32_bf16(aA0, uW1[t * 64 + l], u[t], 0, 0, 0);
    u[t] = __builtin_amdgcn_mfma_f32_16x16x32_bf16(aA1, uW1[(4 + t) * 64 + l], u[t], 0, 0, 0);
    u[t] = __builtin_amdgcn_mfma_f32_16x16x32_bf16(aN0, uW1[(8 + t) * 64 + l], u[t], 0, 0, 0);
    u[t] = __builtin_amdgcn_mfma_f32_16x16x32_bf16(aN1, uW1[(12 + t) * 64 + l], u[t], 0, 0, 0);
  }
#pragma unroll
  for (int t = 0; t < 4; ++t)
#pragma unroll
    for (int r = 0; r < 4; ++r) g[t][r] = sigmoid_f(g[t][r]);

  unsigned short* ld = lds[wave];
#pragma unroll
  for (int t = 0; t < 4; ++t)
#pragma unroll
    for (int r = 0; r < 4; ++r)
      ld[(quad * 4 + r) * 72 + col + 16 * t] = f2bf(fmaxf(u[t][r], 0.0f));
  __syncthreads();
  const bf16x8 h0 = *(const bf16x8*)&ld[col * 72 + quad * 8];
  const bf16x8 h1 = *(const bf16x8*)&ld[col * 72 + 32 + quad * 8];
  f32x4 o[4];
#pragma unroll
  for (int t = 0; t < 4; ++t) {
    const float b = uB2[col + 16 * t];
    o[t] = f32x4{b, b, b, b};
  }
#pragma unroll
  for (int t = 0; t < 4; ++t) {
    o[t] = __builtin_amdgcn_mfma_f32_16x16x32_bf16(h0, uW2[t * 64 + l], o[t], 0, 0, 0);
    o[t] = __builtin_amdgcn_mfma_f32_16x16x32_bf16(h1, uW2[(4 + t) * 64 + l], o[t], 0, 0, 0);
  }
  // gate mix (bf16 node carry, C-layout gather) + LayerNorm
  float om[4][4];
#pragma unroll
  for (int t = 0; t < 4; ++t)
#pragma unroll
    for (int r = 0; r < 4; ++r) {
      const float nd =
          bf2f(NODEb[(size_t)(n0 + quad * 4 + r) * 64 + col + 16 * t]);
      om[t][r] = fmaf(g[t][r], o[t][r] - nd, nd);
    }
  float outv[4][4];
#pragma unroll
  for (int r = 0; r < 4; ++r) {
    float s1 = (om[0][r] + om[1][r]) + (om[2][r] + om[3][r]);
    float s2 = fmaf(om[0][r], om[0][r], fmaf(om[1][r], om[1][r],
                fmaf(om[2][r], om[2][r], om[3][r] * om[3][r])));
#pragma unroll
    for (int off = 1; off < 16; off <<= 1) {
      s1 += __shfl_xor(s1, off, 64);
      s2 += __shfl_xor(s2, off, 64);
    }
    const float m = s1 * (1.0f / 64.0f);
    const float var = s2 * (1.0f / 64.0f) - m * m;
    const float rr = rsqrtf(var + 1e-3f);
#pragma unroll
    for (int t = 0; t < 4; ++t)
      outv[t][r] = fmaf((om[t][r] - m) * rr, LNG[col + 16 * t], LNB[col + 16 * t]);
  }
  if (OUTf != nullptr && !dead) {
#pragma unroll
    for (int t = 0; t < 4; ++t)
#pragma unroll
      for (int r = 0; r < 4; ++r)
        OUTf[(size_t)(n0 + quad * 4 + r) * 64 + col + 16 * t] = outv[t][r];
  }
  __syncthreads();
#pragma unroll
  for (int t = 0; t < 4; ++t)
#pragma unroll
    for (int r = 0; r < 4; ++r)
      ld[(quad * 4 + r) * 72 + col + 16 * t] = f2bf(outv[t][r]);
  __syncthreads();
  if (OUTb != nullptr && !dead) {
#pragma unroll
    for (int cc = 0; cc < 2; ++cc) {
      const bf16x8 v = *(const bf16x8*)&ld[col * 72 + (quad * 2 + cc) * 8];
      *(bf16x8*)(OUTb + (size_t)(n0 + col) * 64 + (quad * 2 + cc) * 8) = v;
    }
  }

  if constexpr (WITH_MSG) {
    const bf16x8 x0 = *(const bf16x8*)&ld[col * 72 + quad * 8];
    const bf16x8 x1 = *(const bf16x8*)&ld[col * 72 + 32 + quad * 8];
    const bf16x8* W1p = (const bf16x8*)mWp;
    const bf16x8* W2p = (const bf16x8*)(mWp + 4096);
    f32x4 macc[4];
#pragma unroll
    for (int t = 0; t < 4; ++t) {
      const float b = mB1[col + 16 * t];
      macc[t] = f32x4{b, b, b, b};
    }
#pragma unroll
    for (int t = 0; t < 4; ++t) {
      macc[t] = __builtin_amdgcn_mfma_f32_16x16x32_bf16(x0, W1p[t * 64 + l], macc[t], 0, 0, 0);
      macc[t] = __builtin_amdgcn_mfma_f32_16x16x32_bf16(x1, W1p[(4 + t) * 64 + l], macc[t], 0, 0, 0);
    }
    __syncthreads();
#pragma unroll
    for (int t = 0; t < 4; ++t)
#pragma unroll
      for (int r = 0; r < 4; ++r)
        ld[(quad * 4 + r) * 72 + col + 16 * t] = f2bf(fmaxf(macc[t][r], 0.0f));
    __syncthreads();
    const bf16x8 mh0 = *(const bf16x8*)&ld[col * 72 + quad * 8];
    const bf16x8 mh1 = *(const bf16x8*)&ld[col * 72 + 32 + quad * 8];
    f32x4 mo[4];
#pragma unroll
    for (int t = 0; t < 4; ++t) {
      const float b = mB2[col + 16 * t];
      mo[t] = f32x4{b, b, b, b};
    }
#pragma unroll
    for (int t = 0; t < 4; ++t) {
      mo[t] = __builtin_amdgcn_mfma_f32_16x16x32_bf16(mh0, W2p[t * 64 + l], mo[t], 0, 0, 0);
      mo[t] = __builtin_amdgcn_mfma_f32_16x16x32_bf16(mh1, W2p[(4 + t) * 64 + l], mo[t], 0, 0, 0);
    }
    __syncthreads();
#pragma unroll
    for (int t = 0; t < 4; ++t)
#pragma unroll
      for (int r = 0; r < 4; ++r)
        ld[(quad * 4 + r) * 72 + col + 16 * t] = f2bf(mo[t][r]);
    __syncthreads();
    if (!dead) {
#pragma unroll
      for (int cc = 0; cc < 2; ++cc) {
        const bf16x8 v = *(const bf16x8*)&ld[col * 72 + (quad * 2 + cc) * 8];
        *(bf16x8*)(MSGb + (size_t)(n0 + col) * 64 + (quad * 2 + cc) * 8) = v;
      }
    }
  }
}

// ======================= edge weight: 8 edges x 8 chunks per wave ============
__global__ void __launch_bounds__(256) edgew_k(
    const int* __restrict__ S, const int* __restrict__ D,
    const float* __restrict__ EFX, const unsigned short* __restrict__ PA,
    const unsigned short* __restrict__ PB, const float* __restrict__ W1C,
    const float* __restrict__ W2, const float* __restrict__ B2,
    float* __restrict__ EW, int E) {
  const int l = threadIdx.x & 63;
  const int g = l >> 3, c = l & 7;
  float wc[8][8];
#pragma unroll
  for (int i = 0; i < 8; ++i) {
    const float4 v0 = *(const float4*)(W1C + i * 64 + c * 8);
    const float4 v1 = *(const float4*)(W1C + i * 64 + c * 8 + 4);
    wc[i][0] = v0.x; wc[i][1] = v0.y; wc[i][2] = v0.z; wc[i][3] = v0.w;
    wc[i][4] = v1.x; wc[i][5] = v1.y; wc[i][6] = v1.z; wc[i][7] = v1.w;
  }
  float w2c[8];
  {
    const float4 a0 = *(const float4*)(W2 + c * 8);
    const float4 a1 = *(const float4*)(W2 + c * 8 + 4);
    w2c[0] = a0.x; w2c[1] = a0.y; w2c[2] = a0.z; w2c[3] = a0.w;
    w2c[4] = a1.x; w2c[5] = a1.y; w2c[6] = a1.z; w2c[7] = a1.w;
  }
  const float b2 = B2[0];
  const int wave_id = blockIdx.x * 4 + (threadIdx.x >> 6);
  const int nwaves = gridDim.x * 4;
  for (int t0 = wave_id * 8; t0 < E; t0 += nwaves * 8) {
    const int e = t0 + g;
    const bool ok = e < E;
    const int ee = ok ? e : E - 1;
    const int s = S[ee], d = D[ee];
    const bf16x8 pa = *(const bf16x8*)(PA + (size_t)s * 64 + c * 8);
    const bf16x8 pb = *(const bf16x8*)(PB + (size_t)d * 64 + c * 8);
    const float4 ef0 = *(const float4*)(EFX + (size_t)ee * 8);
    const float4 ef1 = *(const float4*)(EFX + (size_t)ee * 8 + 4);
    const unsigned* pau = (const unsigned*)&pa;
    const unsigned* pbu = (const unsigned*)&pb;
    float h[8];
#pragma unroll
    for (int q = 0; q < 4; ++q) {
      h[2 * q] = __uint_as_float(pau[q] << 16) + __uint_as_float(pbu[q] << 16);
      h[2 * q + 1] = __uint_as_float(pau[q] & 0xffff0000u) +
                     __uint_as_float(pbu[q] & 0xffff0000u);
    }
    const float ef[8] = {ef0.x, ef0.y, ef0.z, ef0.w, ef1.x, ef1.y, ef1.z, ef1.w};
#pragma unroll
    for (int i = 0; i < 8; ++i)
#pragma unroll
      for (int j = 0; j < 8; ++j) h[j] = fmaf(ef[i], wc[i][j], h[j]);
    float t = 0.0f;
#pragma unroll
    for (int j = 0; j < 8; ++j) t = fmaf(fmaxf(h[j], 0.0f), w2c[j], t);
#pragma unroll
    for (int off = 1; off < 8; off <<= 1) t += __shfl_xor(t, off, 64);
    if (ok && c == 0) EW[e] = sigmoid_f(t + b2);
  }
}

// ======================= CSR aggregation =====================================
// 8 edges x 8 chunks per wave; adj preloaded 64-wide coalesced, then broadcast
// via shfl so the 8 gather batches per chunk are independent (no adj->gather
// dependency chain).  adj entry: (nbr << 14) | w14.
__global__ void __launch_bounds__(256) agg_k(
    const int* __restrict__ row_ptr, const unsigned* __restrict__ adj,
    const float* __restrict__ degi, const unsigned short* __restrict__ MSGb,
    unsigned short* __restrict__ AGGb, int base, int N) {
  const int l = threadIdx.x & 63;
  const int n = blockIdx.x * 4 + (threadIdx.x >> 6);
  if (n >= N) return;
  const int g = l >> 3, c = l & 7;
  const int s = row_ptr[base + n], e = row_ptr[base + n + 1];
  float acc[8];
#pragma unroll
  for (int j = 0; j < 8; ++j) acc[j] = 0.0f;
  for (int p0 = s; p0 < e; p0 += 64) {
    const int myp = p0 + l;
    const unsigned av_l = adj[myp < e ? myp : s];  // coalesced 64-wide
    const int rem = e - p0;
#pragma unroll
    for (int b = 0; b < 8; ++b) {
      if (b * 8 >= rem) break;
      const unsigned av = __shfl(av_l, b * 8 + g, 64);
      const bool ok = b * 8 + g < rem;
      const float w = ok ? (float)(av & 16383u) * WQ_INV : 0.0f;
      const bf16x8 m = *(const bf16x8*)(MSGb + (size_t)(av >> 14) * 64 + c * 8);
      const unsigned* mu = (const unsigned*)&m;
#pragma unroll
      for (int q = 0; q < 4; ++q) {
        const float lo = __uint_as_float(mu[q] << 16);
        const float hi = __uint_as_float(mu[q] & 0xffff0000u);
        acc[2 * q] = fmaf(lo, w, acc[2 * q]);
        acc[2 * q + 1] = fmaf(hi, w, acc[2 * q + 1]);
      }
    }
  }
#pragma unroll
  for (int off = 8; off < 64; off <<= 1)
#pragma unroll
    for (int j = 0; j < 8; ++j) acc[j] += __shfl_xor(acc[j], off, 64);
  if (g == 0) {
    const float di = degi[base + n];
    unsigned out[4];
#pragma unroll
    for (int q = 0; q < 4; ++q)
      out[q] = (unsigned)f2bf(acc[2 * q] * di) |
               ((unsigned)f2bf(acc[2 * q + 1] * di) << 16);
    *(uint4*)(AGGb + (size_t)n * 64 + c * 8) =
        make_uint4(out[0], out[1], out[2], out[3]);
  }
}

// ======================= CSR build: count, scan, fill, deg ===================
__global__ void __launch_bounds__(256) count_k(
    const int* __restrict__ S, const int* __restrict__ D,
    int* __restrict__ counts, int baseD, int baseS, int E) {
  const int e = blockIdx.x * 256 + threadIdx.x;
  if (e >= E) return;
  atomicAdd(&counts[baseD + D[e]], 1);
  atomicAdd(&counts[baseS + S[e]], 1);
}

// Binned fill: bin = blockIdx%8 (XCD-aligned round-robin heuristic). Each bin's
// blocks scan the whole edge list but store only rows in their bin range, so
// each ~1MB adj region is written by one XCD's L2 -> dirty lines accumulate
// fully before writeback (kills the 13x scattered-store amplification).
__global__ void __launch_bounds__(256) fill_binned_k(
    const int* __restrict__ S, const int* __restrict__ D,
    const float* __restrict__ EW, int* __restrict__ cursor,
    unsigned* __restrict__ adj, int baseD, int baseS, int NDrows, int NSrows,
    int E) {
  const int bin = blockIdx.x & (NBIN - 1);
  const int blk = blockIdx.x / NBIN;
  const int nblk = gridDim.x / NBIN;
  const int d_lo = (int)((long long)NDrows * bin / NBIN);
  const int d_hi = (int)((long long)NDrows * (bin + 1) / NBIN);
  const int s_lo = (int)((long long)NSrows * bin / NBIN);
  const int s_hi = (int)((long long)NSrows * (bin + 1) / NBIN);
  for (int e = blk * 256 + threadIdx.x; e < E; e += nblk * 256) {
    const int s = S[e], d = D[e];
    const bool md = (d >= d_lo) & (d < d_hi);
    const bool ms = (s >= s_lo) & (s < s_hi);
    if (md | ms) {
      const unsigned w14 = (unsigned)(EW[e] * WQ_SCALE + 0.5f);
      if (md) {
        const int p = atomicAdd(&cursor[baseD + d], 1);
        adj[p] = ((unsigned)s << 14) | w14;
      }
      if (ms) {
        const int p = atomicAdd(&cursor[baseS + s], 1);
        adj[p] = ((unsigned)d << 14) | w14;
      }
    }
  }
}

__global__ void __launch_bounds__(256) degi_k(const int* __restrict__ row_ptr,
                                             const unsigned* __restrict__ adj,
                                             float* __restrict__ degi) {
  const int r = blockIdx.x * 256 + threadIdx.x;
  if (r >= R_TOT) return;
  const int s = row_ptr[r], e = row_ptr[r + 1];
  float d = 0.0f;
  for (int p = s; p < e; ++p) d += (float)(adj[p] & 16383u) * WQ_INV;
  degi[r] = 1.0f / fmaxf(d, 1.0f);
}

__global__ void __launch_bounds__(256) scan1_k(const int* __restrict__ in,
                                               int* __restrict__ bsum) {
  __shared__ int sd[256];
  const int t = threadIdx.x;
  const int base = blockIdx.x * SCAN_CHUNK + t * 8;
  int s = 0;
#pragma unroll
  for (int i = 0; i < 8; ++i) {
    const int idx = base + i;
    s += (idx < R_TOT) ? in[idx] : 0;
  }
  sd[t] = s;
  __syncthreads();
  for (int off = 128; off > 0; off >>= 1) {
    if (t < off) sd[t] += sd[t + off];
    __syncthreads();
  }
  if (t == 0) bsum[blockIdx.x] = sd[0];
}

__global__ void __launch_bounds__(256) scan2_k(int* __restrict__ bsum,
                                               int* __restrict__ row_ptr) {
  __shared__ int sd[256];
  const int t = threadIdx.x;
  const int v = (t < SCAN_NB) ? bsum[t] : 0;
  sd[t] = v;
  __syncthreads();
  for (int off = 1; off < 256; off <<= 1) {
    const int add = (t >= off) ? sd[t - off] : 0;
    __syncthreads();
    sd[t] += add;
    __syncthreads();
  }
  if (t < SCAN_NB) bsum[t] = sd[t] - v;
  if (t == 255) row_ptr[R_TOT] = sd[255];
}

__global__ void __launch_bounds__(256) scan3_k(const int* __restrict__ in,
                                               const int* __restrict__ bsum,
                                               int* __restrict__ out) {
  __shared__ int sd[256];
  const int t = threadIdx.x;
  const int base = blockIdx.x * SCAN_CHUNK + t * 8;
  int loc[8];
  int s = 0;
#pragma unroll
  for (int i = 0; i < 8; ++i) {
    loc[i] = s;
    const int idx = base + i;
    s += (idx < R_TOT) ? in[idx] : 0;
  }
  sd[t] = s;
  __syncthreads();
  const int v = s;
  for (int off = 1; off < 256; off <<= 1) {
    const int add = (t >= off) ? sd[t - off] : 0;
    __syncthreads();
    sd[t] += add;
    __syncthreads();
  }
  const int off0 = bsum[blockIdx.x] + (sd[t] - v);
#pragma unroll
  for (int i = 0; i < 8; ++i) {
    const int idx = base + i;
    if (idx < R_TOT) out[idx] = off0 + loc[i];
  }
}

}  // namespace

extern "C" void kernel_launch(void* const* d_in, const int* in_sizes, int n_in,
                              void* d_out, int out_size, void* d_ws, size_t ws_size,
                              hipStream_t stream) {
  (void)in_sizes; (void)n_in; (void)out_size; (void)ws_size;

  const float* variable_features   = (const float*)d_in[0];
  const float* constraint_features = (const float*)d_in[1];
  const float* cut_features        = (const float*)d_in[2];
  const float* vc_ef = (const float*)d_in[3];
  const float* vk_ef = (const float*)d_in[4];
  const int* vc_edges = (const int*)d_in[5];
  const int* vk_edges = (const int*)d_in[6];
  const int *vc_s = vc_edges, *vc_d = vc_edges + EVC;
  const int *vk_s = vk_edges, *vk_d = vk_edges + EVK;
  const float* var_w1  = (const float*)d_in[7];
  const float* var_b1  = (const float*)d_in[8];
  const float* var_w2  = (const float*)d_in[9];
  const float* var_b2  = (const float*)d_in[10];
  const float* cons_w1 = (const float*)d_in[11];
  const float* cons_b1 = (const float*)d_in[12];
  const float* cons_w2 = (const float*)d_in[13];
  const float* cons_b2 = (const float*)d_in[14];
  const float* cut_w1  = (const float*)d_in[15];
  const float* cut_b1  = (const float*)d_in[16];
  const float* cut_w2  = (const float*)d_in[17];
  const float* cut_b2  = (const float*)d_in[18];
  const float* ewvc_w1 = (const float*)d_in[19];
  const float* ewvc_b1 = (const float*)d_in[20];
  const float* ewvc_w2 = (const float*)d_in[21];
  const float* ewvc_b2 = (const float*)d_in[22];
  const float* ewvk_w1 = (const float*)d_in[23];
  const float* ewvk_b1 = (const float*)d_in[24];
  const float* ewvk_w2 = (const float*)d_in[25];
  const float* ewvk_b2 = (const float*)d_in[26];
  const float* mp_msg_w1 = (const float*)d_in[27];
  const float* mp_msg_b1 = (const float*)d_in[28];
  const float* mp_msg_w2 = (const float*)d_in[29];
  const float* mp_msg_b2 = (const float*)d_in[30];
  const float* mp_gate_w = (const float*)d_in[31];
  const float* mp_gate_b = (const float*)d_in[32];
  const float* mp_upd_w1 = (const float*)d_in[33];
  const float* mp_upd_b1 = (const float*)d_in[34];
  const float* mp_upd_w2 = (const float*)d_in[35];
  const float* mp_upd_b2 = (const float*)d_in[36];
  const float* mp_ln_g   = (const float*)d_in[37];
  const float* mp_ln_b   = (const float*)d_in[38];

  // ---- workspace carve ----
  char* wp = (char*)d_ws;
  auto take = [&](size_t nbytes) {
    char* p = wp;
    wp += (nbytes + 255) & ~(size_t)255;
    return p;
  };
  unsigned short* h_var_b  = (unsigned short*)take((size_t)NV * 64 * 2);
  unsigned short* h_cons_b = (unsigned short*)take((size_t)NC * 64 * 2);
  unsigned short* h_cut_b  = (unsigned short*)take((size_t)NK * 64 * 2);
  unsigned short* msg_b = (unsigned short*)take((size_t)NV * 64 * 2);
  unsigned short* agg_b = (unsigned short*)take((size_t)NV * 64 * 2);
  unsigned short* pa = (unsigned short*)take((size_t)NV * 64 * 2);
  unsigned short* pb = (unsigned short*)take((size_t)NC * 64 * 2);
  unsigned short* qa = (unsigned short*)take((size_t)NV * 64 * 2);
  unsigned short* qb = (unsigned short*)take((size_t)NK * 64 * 2);
  unsigned short* packW = (unsigned short*)take((size_t)15 * PACK_PER_LAYER * 2);
  float* ew_vc = (float*)take((size_t)EVC * 4);
  float* ew_vk = (float*)take((size_t)EVK * 4);
  int* row_ptr = (int*)take((size_t)(R_TOT + 1) * 4);
  int* cursor  = (int*)take((size_t)R_TOT * 4);
  int* counts  = (int*)take((size_t)R_TOT * 4);
  int* bsum    = (int*)take(256 * 4);
  float* degi  = (float*)take((size_t)R_TOT * 4);
  unsigned* adj = (unsigned*)take((size_t)(2 * EVC + 2 * EVK) * 4);

  // ---- CSR counts + scan ----
  hipMemsetAsync(counts, 0, (size_t)R_TOT * 4, stream);
  count_k<<<(EVC + 255) / 256, 256, 0, stream>>>(vc_s, vc_d, counts, 0, NC, EVC);
  count_k<<<(EVK + 255) / 256, 256, 0, stream>>>(vk_s, vk_d, counts, NC + NV,
                                                 NC + NV + NK, EVK);
  scan1_k<<<SCAN_NB, 256, 0, stream>>>(counts, bsum);
  scan2_k<<<1, 256, 0, stream>>>(bsum, row_ptr);
  scan3_k<<<SCAN_NB, 256, 0, stream>>>(counts, bsum, row_ptr);

  // ---- embeddings (bf16) ----
  mlp2_node_k<19><<<(NV + 255) / 256, 256, 0, stream>>>(
      variable_features, var_w1, var_b1, var_w2, var_b2, h_var_b, NV);
  mlp2_node_k<5><<<(NC + 255) / 256, 256, 0, stream>>>(
      constraint_features, cons_w1, cons_b1, cons_w2, cons_b2, h_cons_b, NC);
  mlp2_node_k<30><<<(NK + 255) / 256, 256, 0, stream>>>(
      cut_features, cut_w1, cut_b1, cut_w2, cut_b2, h_cut_b, NK);

  // ---- pack MP weights to bf16 B-frag streams ----
  pack_k<<<15, 256, 0, stream>>>(mp_msg_w1, mp_msg_w2, mp_gate_w, mp_upd_w1,
                                 mp_upd_w2, packW);

  // ---- edge weights: per-node terms (B1 folded into dst term) ----
  gemv64_k<<<(NV + 255) / 256, 256, 0, stream>>>(h_var_b, ewvc_w1, nullptr, pa, NV);
  gemv64_k<<<(NC + 255) / 256, 256, 0, stream>>>(h_cons_b, ewvc_w1 + 64 * 64,
                                                 ewvc_b1, pb, NC);
  gemv64_k<<<(NV + 255) / 256, 256, 0, stream>>>(h_var_b, ewvk_w1, nullptr, qa, NV);
  gemv64_k<<<(NK + 255) / 256, 256, 0, stream>>>(h_cut_b, ewvk_w1 + 64 * 64,
                                                 ewvk_b1, qb, NK);
  edgew_k<<<1024, 256, 0, stream>>>(vc_s, vc_d, vc_ef, pa, pb,
                                    ewvc_w1 + 128 * 64, ewvc_w2, ewvc_b2,
                                    ew_vc, EVC);
  edgew_k<<<512, 256, 0, stream>>>(vk_s, vk_d, vk_ef, qa, qb,
                                   ewvk_w1 + 128 * 64, ewvk_w2, ewvk_b2,
                                   ew_vk, EVK);

  // ---- CSR fill (binned, XCD-local stores) + per-row 1/deg ----
  hipMemcpyAsync(cursor, row_ptr, (size_t)R_TOT * 4, hipMemcpyDeviceToDevice, stream);
  fill_binned_k<<<NBIN * 128, 256, 0, stream>>>(vc_s, vc_d, ew_vc, cursor, adj,
                                                0, NC, NC, NV, EVC);
  fill_binned_k<<<NBIN * 64, 256, 0, stream>>>(vk_s, vk_d, ew_vk, cursor, adj,
                                               NC + NV, NC + NV + NK, NK, NV, EVK);
  degi_k<<<(R_TOT + 255) / 256, 256, 0, stream>>>(row_ptr, adj, degi);

  // ---- 15 message passes; upd(i) fused with msg(i+1) ----
  unsigned short* nodeb_t[4] = {h_cons_b, h_var_b, h_cut_b, h_var_b};
  const int Nd_t[4] = {NC, NV, NK, NV};
  const int base_t[4] = {0, NC, NC + NV, NC + NV + NK};

  // msg(0): over h_var with layer-0 msg weights
  msg_mfma_k<<<(NV + 63) / 64, 256, 0, stream>>>(
      h_var_b, packW, mp_msg_b1, mp_msg_b2, msg_b, NV);

  for (int i = 0; i < 15; ++i) {
    const int d = i & 3;
    const int Nd = Nd_t[d], base = base_t[d];
    const unsigned short* Wl = packW + (size_t)i * PACK_PER_LAYER;

    agg_k<<<(Nd + 3) / 4, 256, 0, stream>>>(row_ptr, adj, degi, msg_b, agg_b,
                                            base, Nd);
    if (i < 14) {
      const unsigned short* Wn = packW + (size_t)(i + 1) * PACK_PER_LAYER;
      updmsg_mfma_k<1><<<(Nd + 63) / 64, 256, 0, stream>>>(
          agg_b, nodeb_t[d], Wl + 8192, Wl + 16384, Wl + 24576,
          mp_gate_b + (size_t)i * 64, mp_upd_b1 + (size_t)i * 64,
          mp_upd_b2 + (size_t)i * 64, mp_ln_g + (size_t)i * 64,
          mp_ln_b + (size_t)i * 64, Wn, mp_msg_b1 + (size_t)(i + 1) * 64,
          mp_msg_b2 + (size_t)(i + 1) * 64, nullptr, nodeb_t[d], msg_b, Nd);
    } else {
      updmsg_mfma_k<0><<<(Nd + 63) / 64, 256, 0, stream>>>(
          agg_b, nodeb_t[d], Wl + 8192, Wl + 16384, Wl + 24576,
          mp_gate_b + (size_t)i * 64, mp_upd_b1 + (size_t)i * 64,
          mp_upd_b2 + (size_t)i * 64, mp_ln_g + (size_t)i * 64,
          mp_ln_b + (size_t)i * 64, nullptr, nullptr, nullptr,
          (float*)d_out, nullptr, nullptr, Nd);
    }
  }
}

// Round 8
// 1136.289 us; speedup vs baseline: 4.4063x; 1.2790x over previous
//
#include <hip/hip_runtime.h>

#define DEVINL static __device__ __forceinline__

namespace {

typedef __attribute__((ext_vector_type(8))) short bf16x8;
typedef __attribute__((ext_vector_type(4))) float f32x4;

constexpr int NV = 100000;   // variables
constexpr int NC = 50000;    // constraints
constexpr int NK = 20000;    // cuts
constexpr int EVC = 800000;  // var-cons edges
constexpr int EVK = 200000;  // var-cut edges
constexpr int R_TOT = NC + NV + NK + NV;  // 270000 CSR rows
constexpr int SCAN_CHUNK = 2048;
constexpr int SCAN_NB = (R_TOT + SCAN_CHUNK - 1) / SCAN_CHUNK;  // 132
constexpr int PACK_PER_LAYER = 28672;  // ushort per layer of packed MP weights
constexpr float WQ_SCALE = 16383.0f;
constexpr float WQ_INV = 1.0f / 16383.0f;
constexpr int NBIN = 8;  // fill bins; blockIdx%8 aligns with XCD round-robin

// packed embedding/edge-weight matrix offsets (ushort)
constexpr int PE_VAR_W1 = 0;      // Kpad=32 -> 2048
constexpr int PE_VAR_W2 = 2048;   // K=64   -> 4096
constexpr int PE_CONS_W1 = 6144;  // 2048
constexpr int PE_CONS_W2 = 8192;  // 4096
constexpr int PE_CUT_W1 = 12288;  // 2048
constexpr int PE_CUT_W2 = 14336;  // 4096
constexpr int PE_EWVC_A = 18432;  // 4096
constexpr int PE_EWVC_B = 22528;  // 4096
constexpr int PE_EWVK_A = 26624;  // 4096
constexpr int PE_EWVK_B = 30720;  // 4096
constexpr int PE_TOTAL = 34816;

DEVINL unsigned short f2bf(float f) {
  unsigned u = __float_as_uint(f);
  u = u + 0x7fffu + ((u >> 16) & 1u);  // RNE
  return (unsigned short)(u >> 16);
}
DEVINL float bf2f(unsigned short h) {
  return __uint_as_float((unsigned)h << 16);
}

DEVINL float sigmoid_f(float x) { return 1.0f / (1.0f + __expf(-x)); }

// ======================= weight packing (bf16 B-frag streams) ================
DEVINL void pack_mat(const float* __restrict__ src, int K, int Kpad,
                     unsigned short* __restrict__ dst, int tid) {
  const int ntup = (Kpad / 32) * 256;
  for (int tup = tid; tup < ntup; tup += 256) {
    const int lane = tup & 63;
    const int t = (tup >> 6) & 3;
    const int kb = tup >> 8;
    const int c = t * 16 + (lane & 15);
    const int k0 = kb * 32 + (lane >> 4) * 8;
#pragma unroll
    for (int jj = 0; jj < 8; ++jj)
      dst[tup * 8 + jj] =
          (k0 + jj < K) ? f2bf(src[(k0 + jj) * 64 + c]) : (unsigned short)0;
  }
}

__global__ void __launch_bounds__(256) pack_k(
    const float* __restrict__ mW1, const float* __restrict__ mW2,
    const float* __restrict__ gW, const float* __restrict__ uW1,
    const float* __restrict__ uW2, unsigned short* __restrict__ PW) {
  const int layer = blockIdx.x;  // 0..14
  unsigned short* out = PW + (size_t)layer * PACK_PER_LAYER;
  pack_mat(mW1 + (size_t)layer * 4096, 64, 64, out, threadIdx.x);
  pack_mat(mW2 + (size_t)layer * 4096, 64, 64, out + 4096, threadIdx.x);
  pack_mat(gW + (size_t)layer * 8192, 128, 128, out + 8192, threadIdx.x);
  pack_mat(uW1 + (size_t)layer * 8192, 128, 128, out + 16384, threadIdx.x);
  pack_mat(uW2 + (size_t)layer * 4096, 64, 64, out + 24576, threadIdx.x);
}

__global__ void __launch_bounds__(256) pack_emb_k(
    const float* __restrict__ var_w1, const float* __restrict__ var_w2,
    const float* __restrict__ cons_w1, const float* __restrict__ cons_w2,
    const float* __restrict__ cut_w1, const float* __restrict__ cut_w2,
    const float* __restrict__ ewvc_w1, const float* __restrict__ ewvk_w1,
    unsigned short* __restrict__ P) {
  switch (blockIdx.x) {
    case 0: pack_mat(var_w1, 19, 32, P + PE_VAR_W1, threadIdx.x); break;
    case 1: pack_mat(var_w2, 64, 64, P + PE_VAR_W2, threadIdx.x); break;
    case 2: pack_mat(cons_w1, 5, 32, P + PE_CONS_W1, threadIdx.x); break;
    case 3: pack_mat(cons_w2, 64, 64, P + PE_CONS_W2, threadIdx.x); break;
    case 4: pack_mat(cut_w1, 30, 32, P + PE_CUT_W1, threadIdx.x); break;
    case 5: pack_mat(cut_w2, 64, 64, P + PE_CUT_W2, threadIdx.x); break;
    case 6: pack_mat(ewvc_w1, 64, 64, P + PE_EWVC_A, threadIdx.x); break;
    case 7: pack_mat(ewvc_w1 + 64 * 64, 64, 64, P + PE_EWVC_B, threadIdx.x); break;
    case 8: pack_mat(ewvk_w1, 64, 64, P + PE_EWVK_A, threadIdx.x); break;
    case 9: pack_mat(ewvk_w1 + 64 * 64, 64, 64, P + PE_EWVK_B, threadIdx.x); break;
  }
}

// ======================= embedding MLP (MFMA, K1 padded to 32) ===============
template <int DIN>
__global__ void __launch_bounds__(256) emb_mfma_k(
    const float* __restrict__ X, const unsigned short* __restrict__ W1p_,
    const unsigned short* __restrict__ W2p_, const float* __restrict__ B1,
    const float* __restrict__ B2, unsigned short* __restrict__ OUTb, int N) {
  __shared__ unsigned short lds[4][16 * 72];
  const int wave = threadIdx.x >> 6, l = threadIdx.x & 63;
  const int col = l & 15, quad = l >> 4;
  const int n0_raw = blockIdx.x * 64 + wave * 16;
  const bool dead = n0_raw >= N;  // N % 16 == 0 -> waves all-valid or all-dead
  const int n0 = dead ? 0 : n0_raw;

  // layer-1 A-frag: row = n0+col, k = quad*8+j, zero-padded past DIN
  bf16x8 a0;
#pragma unroll
  for (int j = 0; j < 8; ++j) {
    const int k = quad * 8 + j;
    a0[j] = (k < DIN) ? (short)f2bf(X[(size_t)(n0 + col) * DIN + k]) : (short)0;
  }
  const bf16x8* W1p = (const bf16x8*)W1p_;
  const bf16x8* W2p = (const bf16x8*)W2p_;
  f32x4 acc[4];
#pragma unroll
  for (int t = 0; t < 4; ++t) {
    const float b = B1[col + 16 * t];
    acc[t] = f32x4{b, b, b, b};
  }
#pragma unroll
  for (int t = 0; t < 4; ++t)
    acc[t] = __builtin_amdgcn_mfma_f32_16x16x32_bf16(a0, W1p[t * 64 + l], acc[t], 0, 0, 0);
  unsigned short* ld = lds[wave];
#pragma unroll
  for (int t = 0; t < 4; ++t)
#pragma unroll
    for (int r = 0; r < 4; ++r)
      ld[(quad * 4 + r) * 72 + col + 16 * t] = f2bf(fmaxf(acc[t][r], 0.0f));
  __syncthreads();
  const bf16x8 h0 = *(const bf16x8*)&ld[col * 72 + quad * 8];
  const bf16x8 h1 = *(const bf16x8*)&ld[col * 72 + 32 + quad * 8];
  f32x4 o[4];
#pragma unroll
  for (int t = 0; t < 4; ++t) {
    const float b = B2[col + 16 * t];
    o[t] = f32x4{b, b, b, b};
  }
#pragma unroll
  for (int t = 0; t < 4; ++t) {
    o[t] = __builtin_amdgcn_mfma_f32_16x16x32_bf16(h0, W2p[t * 64 + l], o[t], 0, 0, 0);
    o[t] = __builtin_amdgcn_mfma_f32_16x16x32_bf16(h1, W2p[(4 + t) * 64 + l], o[t], 0, 0, 0);
  }
  __syncthreads();
#pragma unroll
  for (int t = 0; t < 4; ++t)
#pragma unroll
    for (int r = 0; r < 4; ++r)
      ld[(quad * 4 + r) * 72 + col + 16 * t] = f2bf(o[t][r]);
  __syncthreads();
  if (!dead) {
#pragma unroll
    for (int cc = 0; cc < 2; ++cc) {
      const bf16x8 v = *(const bf16x8*)&ld[col * 72 + (quad * 2 + cc) * 8];
      *(bf16x8*)(OUTb + (size_t)(n0 + col) * 64 + (quad * 2 + cc) * 8) = v;
    }
  }
}

// ======= edge-weight per-node GEMV (MFMA); NOUT=2 shares the A-frag =========
template <int NOUT>
__global__ void __launch_bounds__(256) gemv_mfma_k(
    const unsigned short* __restrict__ Xb, const unsigned short* __restrict__ WpA_,
    const unsigned short* __restrict__ WpB_, const float* __restrict__ Bias,
    unsigned short* __restrict__ OUT0, unsigned short* __restrict__ OUT1, int N) {
  __shared__ unsigned short lds[4][16 * 72];
  const int wave = threadIdx.x >> 6, l = threadIdx.x & 63;
  const int col = l & 15, quad = l >> 4;
  const int n0_raw = blockIdx.x * 64 + wave * 16;
  const bool dead = n0_raw >= N;
  const int n0 = dead ? 0 : n0_raw;
  const unsigned short* xrow = Xb + (size_t)(n0 + col) * 64 + quad * 8;
  const bf16x8 a0 = *(const bf16x8*)xrow;
  const bf16x8 a1 = *(const bf16x8*)(xrow + 32);
  unsigned short* ld = lds[wave];
#pragma unroll
  for (int m = 0; m < NOUT; ++m) {
    const bf16x8* Wp = (const bf16x8*)(m == 0 ? WpA_ : WpB_);
    unsigned short* OUT = (m == 0) ? OUT0 : OUT1;
    f32x4 acc[4];
#pragma unroll
    for (int t = 0; t < 4; ++t) {
      const float b = (Bias != nullptr) ? Bias[col + 16 * t] : 0.0f;
      acc[t] = f32x4{b, b, b, b};
    }
#pragma unroll
    for (int t = 0; t < 4; ++t) {
      acc[t] = __builtin_amdgcn_mfma_f32_16x16x32_bf16(a0, Wp[t * 64 + l], acc[t], 0, 0, 0);
      acc[t] = __builtin_amdgcn_mfma_f32_16x16x32_bf16(a1, Wp[(4 + t) * 64 + l], acc[t], 0, 0, 0);
    }
    if (m > 0) __syncthreads();
#pragma unroll
    for (int t = 0; t < 4; ++t)
#pragma unroll
      for (int r = 0; r < 4; ++r)
        ld[(quad * 4 + r) * 72 + col + 16 * t] = f2bf(acc[t][r]);
    __syncthreads();
    if (!dead) {
#pragma unroll
      for (int cc = 0; cc < 2; ++cc) {
        const bf16x8 v = *(const bf16x8*)&ld[col * 72 + (quad * 2 + cc) * 8];
        *(bf16x8*)(OUT + (size_t)(n0 + col) * 64 + (quad * 2 + cc) * 8) = v;
      }
    }
  }
}

// ======================= message MLP (MFMA) — used once for pass 0 ===========
__global__ void __launch_bounds__(256) msg_mfma_k(
    const unsigned short* __restrict__ Xb, const unsigned short* __restrict__ Wp,
    const float* __restrict__ B1, const float* __restrict__ B2,
    unsigned short* __restrict__ MSGb, int N) {
  __shared__ unsigned short lds[4][16 * 72];
  const int wave = threadIdx.x >> 6, l = threadIdx.x & 63;
  const int col = l & 15, quad = l >> 4;
  const int n0_raw = blockIdx.x * 64 + wave * 16;
  const bool dead = n0_raw >= N;
  const int n0 = dead ? 0 : n0_raw;

  const unsigned short* xrow = Xb + (size_t)(n0 + col) * 64 + quad * 8;
  const bf16x8 a0 = *(const bf16x8*)xrow;
  const bf16x8 a1 = *(const bf16x8*)(xrow + 32);
  const bf16x8* W1p = (const bf16x8*)Wp;
  const bf16x8* W2p = (const bf16x8*)(Wp + 4096);

  f32x4 acc[4];
#pragma unroll
  for (int t = 0; t < 4; ++t) {
    const float b = B1[col + 16 * t];
    acc[t] = f32x4{b, b, b, b};
  }
#pragma unroll
  for (int t = 0; t < 4; ++t) {
    acc[t] = __builtin_amdgcn_mfma_f32_16x16x32_bf16(a0, W1p[t * 64 + l], acc[t], 0, 0, 0);
    acc[t] = __builtin_amdgcn_mfma_f32_16x16x32_bf16(a1, W1p[(4 + t) * 64 + l], acc[t], 0, 0, 0);
  }
  unsigned short* ld = lds[wave];
#pragma unroll
  for (int t = 0; t < 4; ++t)
#pragma unroll
    for (int r = 0; r < 4; ++r)
      ld[(quad * 4 + r) * 72 + col + 16 * t] = f2bf(fmaxf(acc[t][r], 0.0f));
  __syncthreads();
  const bf16x8 h0 = *(const bf16x8*)&ld[col * 72 + quad * 8];
  const bf16x8 h1 = *(const bf16x8*)&ld[col * 72 + 32 + quad * 8];
  f32x4 o[4];
#pragma unroll
  for (int t = 0; t < 4; ++t) {
    const float b = B2[col + 16 * t];
    o[t] = f32x4{b, b, b, b};
  }
#pragma unroll
  for (int t = 0; t < 4; ++t) {
    o[t] = __builtin_amdgcn_mfma_f32_16x16x32_bf16(h0, W2p[t * 64 + l], o[t], 0, 0, 0);
    o[t] = __builtin_amdgcn_mfma_f32_16x16x32_bf16(h1, W2p[(4 + t) * 64 + l], o[t], 0, 0, 0);
  }
  __syncthreads();
#pragma unroll
  for (int t = 0; t < 4; ++t)
#pragma unroll
    for (int r = 0; r < 4; ++r)
      ld[(quad * 4 + r) * 72 + col + 16 * t] = f2bf(o[t][r]);
  __syncthreads();
  if (!dead) {
#pragma unroll
    for (int cc = 0; cc < 2; ++cc) {
      const bf16x8 v = *(const bf16x8*)&ld[col * 72 + (quad * 2 + cc) * 8];
      *(bf16x8*)(MSGb + (size_t)(n0 + col) * 64 + (quad * 2 + cc) * 8) = v;
    }
  }
}

// ==== fused: upd(i) [gate+upd1+upd2+mix+LN] + msg(i+1) over the same rows ====
template <int WITH_MSG>
__global__ void __launch_bounds__(256) updmsg_mfma_k(
    const unsigned short* __restrict__ AGGb, const unsigned short* __restrict__ NODEb,
    const unsigned short* __restrict__ gWp, const unsigned short* __restrict__ uW1p,
    const unsigned short* __restrict__ uW2p, const float* __restrict__ gB,
    const float* __restrict__ uB1, const float* __restrict__ uB2,
    const float* __restrict__ LNG, const float* __restrict__ LNB,
    const unsigned short* __restrict__ mWp,  // next layer msg W1|W2 (packed)
    const float* __restrict__ mB1, const float* __restrict__ mB2,
    float* __restrict__ OUTf, unsigned short* __restrict__ OUTb,
    unsigned short* __restrict__ MSGb, int N) {
  __shared__ unsigned short lds[4][16 * 72];
  const int wave = threadIdx.x >> 6, l = threadIdx.x & 63;
  const int col = l & 15, quad = l >> 4;
  const int n0_raw = blockIdx.x * 64 + wave * 16;
  const bool dead = n0_raw >= N;
  const int n0 = dead ? 0 : n0_raw;

  const unsigned short* arow = AGGb + (size_t)(n0 + col) * 64 + quad * 8;
  const unsigned short* nrow = NODEb + (size_t)(n0 + col) * 64 + quad * 8;
  const bf16x8 aA0 = *(const bf16x8*)arow;
  const bf16x8 aA1 = *(const bf16x8*)(arow + 32);
  const bf16x8 aN0 = *(const bf16x8*)nrow;
  const bf16x8 aN1 = *(const bf16x8*)(nrow + 32);
  const bf16x8* gW = (const bf16x8*)gWp;
  const bf16x8* uW1 = (const bf16x8*)uW1p;
  const bf16x8* uW2 = (const bf16x8*)uW2p;

  f32x4 g[4], u[4];
#pragma unroll
  for (int t = 0; t < 4; ++t) {
    const float bg = gB[col + 16 * t], bu = uB1[col + 16 * t];
    g[t] = f32x4{bg, bg, bg, bg};
    u[t] = f32x4{bu, bu, bu, bu};
  }
#pragma unroll
  for (int t = 0; t < 4; ++t) {
    g[t] = __builtin_amdgcn_mfma_f32_16x16x32_bf16(aA0, gW[t * 64 + l], g[t], 0, 0, 0);
    g[t] = __builtin_amdgcn_mfma_f32_16x16x32_bf16(aA1, gW[(4 + t) * 64 + l], g[t], 0, 0, 0);
    g[t] = __builtin_amdgcn_mfma_f32_16x16x32_bf16(aN0, gW[(8 + t) * 64 + l], g[t], 0, 0, 0);
    g[t] = __builtin_amdgcn_mfma_f32_16x16x32_bf16(aN1, gW[(12 + t) * 64 + l], g[t], 0, 0, 0);
    u[t] = __builtin_amdgcn_mfma_f32_16x16x32_bf16(aA0, uW1[t * 64 + l], u[t], 0, 0, 0);
    u[t] = __builtin_amdgcn_mfma_f32_16x16x32_bf16(aA1, uW1[(4 + t) * 64 + l], u[t], 0, 0, 0);
    u[t] = __builtin_amdgcn_mfma_f32_16x16x32_bf16(aN0, uW1[(8 + t) * 64 + l], u[t], 0, 0, 0);
    u[t] = __builtin_amdgcn_mfma_f32_16x16x32_bf16(aN1, uW1[(12 + t) * 64 + l], u[t], 0, 0, 0);
  }
#pragma unroll
  for (int t = 0; t < 4; ++t)
#pragma unroll
    for (int r = 0; r < 4; ++r) g[t][r] = sigmoid_f(g[t][r]);

  unsigned short* ld = lds[wave];
#pragma unroll
  for (int t = 0; t < 4; ++t)
#pragma unroll
    for (int r = 0; r < 4; ++r)
      ld[(quad * 4 + r) * 72 + col + 16 * t] = f2bf(fmaxf(u[t][r], 0.0f));
  __syncthreads();
  const bf16x8 h0 = *(const bf16x8*)&ld[col * 72 + quad * 8];
  const bf16x8 h1 = *(const bf16x8*)&ld[col * 72 + 32 + quad * 8];
  f32x4 o[4];
#pragma unroll
  for (int t = 0; t < 4; ++t) {
    const float b = uB2[col + 16 * t];
    o[t] = f32x4{b, b, b, b};
  }
#pragma unroll
  for (int t = 0; t < 4; ++t) {
    o[t] = __builtin_amdgcn_mfma_f32_16x16x32_bf16(h0, uW2[t * 64 + l], o[t], 0, 0, 0);
    o[t] = __builtin_amdgcn_mfma_f32_16x16x32_bf16(h1, uW2[(4 + t) * 64 + l], o[t], 0, 0, 0);
  }
  // gate mix (bf16 node carry, C-layout gather) + LayerNorm
  float om[4][4];
#pragma unroll
  for (int t = 0; t < 4; ++t)
#pragma unroll
    for (int r = 0; r < 4; ++r) {
      const float nd =
          bf2f(NODEb[(size_t)(n0 + quad * 4 + r) * 64 + col + 16 * t]);
      om[t][r] = fmaf(g[t][r], o[t][r] - nd, nd);
    }
  float outv[4][4];
#pragma unroll
  for (int r = 0; r < 4; ++r) {
    float s1 = (om[0][r] + om[1][r]) + (om[2][r] + om[3][r]);
    float s2 = fmaf(om[0][r], om[0][r], fmaf(om[1][r], om[1][r],
                fmaf(om[2][r], om[2][r], om[3][r] * om[3][r])));
#pragma unroll
    for (int off = 1; off < 16; off <<= 1) {
      s1 += __shfl_xor(s1, off, 64);
      s2 += __shfl_xor(s2, off, 64);
    }
    const float m = s1 * (1.0f / 64.0f);
    const float var = s2 * (1.0f / 64.0f) - m * m;
    const float rr = rsqrtf(var + 1e-3f);
#pragma unroll
    for (int t = 0; t < 4; ++t)
      outv[t][r] = fmaf((om[t][r] - m) * rr, LNG[col + 16 * t], LNB[col + 16 * t]);
  }
  if (OUTf != nullptr && !dead) {
#pragma unroll
    for (int t = 0; t < 4; ++t)
#pragma unroll
      for (int r = 0; r < 4; ++r)
        OUTf[(size_t)(n0 + quad * 4 + r) * 64 + col + 16 * t] = outv[t][r];
  }
  __syncthreads();
#pragma unroll
  for (int t = 0; t < 4; ++t)
#pragma unroll
    for (int r = 0; r < 4; ++r)
      ld[(quad * 4 + r) * 72 + col + 16 * t] = f2bf(outv[t][r]);
  __syncthreads();
  if (OUTb != nullptr && !dead) {
#pragma unroll
    for (int cc = 0; cc < 2; ++cc) {
      const bf16x8 v = *(const bf16x8*)&ld[col * 72 + (quad * 2 + cc) * 8];
      *(bf16x8*)(OUTb + (size_t)(n0 + col) * 64 + (quad * 2 + cc) * 8) = v;
    }
  }

  if constexpr (WITH_MSG) {
    const bf16x8 x0 = *(const bf16x8*)&ld[col * 72 + quad * 8];
    const bf16x8 x1 = *(const bf16x8*)&ld[col * 72 + 32 + quad * 8];
    const bf16x8* W1p = (const bf16x8*)mWp;
    const bf16x8* W2p = (const bf16x8*)(mWp + 4096);
    f32x4 macc[4];
#pragma unroll
    for (int t = 0; t < 4; ++t) {
      const float b = mB1[col + 16 * t];
      macc[t] = f32x4{b, b, b, b};
    }
#pragma unroll
    for (int t = 0; t < 4; ++t) {
      macc[t] = __builtin_amdgcn_mfma_f32_16x16x32_bf16(x0, W1p[t * 64 + l], macc[t], 0, 0, 0);
      macc[t] = __builtin_amdgcn_mfma_f32_16x16x32_bf16(x1, W1p[(4 + t) * 64 + l], macc[t], 0, 0, 0);
    }
    __syncthreads();
#pragma unroll
    for (int t = 0; t < 4; ++t)
#pragma unroll
      for (int r = 0; r < 4; ++r)
        ld[(quad * 4 + r) * 72 + col + 16 * t] = f2bf(fmaxf(macc[t][r], 0.0f));
    __syncthreads();
    const bf16x8 mh0 = *(const bf16x8*)&ld[col * 72 + quad * 8];
    const bf16x8 mh1 = *(const bf16x8*)&ld[col * 72 + 32 + quad * 8];
    f32x4 mo[4];
#pragma unroll
    for (int t = 0; t < 4; ++t) {
      const float b = mB2[col + 16 * t];
      mo[t] = f32x4{b, b, b, b};
    }
#pragma unroll
    for (int t = 0; t < 4; ++t) {
      mo[t] = __builtin_amdgcn_mfma_f32_16x16x32_bf16(mh0, W2p[t * 64 + l], mo[t], 0, 0, 0);
      mo[t] = __builtin_amdgcn_mfma_f32_16x16x32_bf16(mh1, W2p[(4 + t) * 64 + l], mo[t], 0, 0, 0);
    }
    __syncthreads();
#pragma unroll
    for (int t = 0; t < 4; ++t)
#pragma unroll
      for (int r = 0; r < 4; ++r)
        ld[(quad * 4 + r) * 72 + col + 16 * t] = f2bf(mo[t][r]);
    __syncthreads();
    if (!dead) {
#pragma unroll
      for (int cc = 0; cc < 2; ++cc) {
        const bf16x8 v = *(const bf16x8*)&ld[col * 72 + (quad * 2 + cc) * 8];
        *(bf16x8*)(MSGb + (size_t)(n0 + col) * 64 + (quad * 2 + cc) * 8) = v;
      }
    }
  }
}

// ======================= edge weight: 8 edges x 8 chunks per wave ============
__global__ void __launch_bounds__(256) edgew_k(
    const int* __restrict__ S, const int* __restrict__ D,
    const float* __restrict__ EFX, const unsigned short* __restrict__ PA,
    const unsigned short* __restrict__ PB, const float* __restrict__ W1C,
    const float* __restrict__ W2, const float* __restrict__ B2,
    float* __restrict__ EW, int E) {
  const int l = threadIdx.x & 63;
  const int g = l >> 3, c = l & 7;
  float wc[8][8];
#pragma unroll
  for (int i = 0; i < 8; ++i) {
    const float4 v0 = *(const float4*)(W1C + i * 64 + c * 8);
    const float4 v1 = *(const float4*)(W1C + i * 64 + c * 8 + 4);
    wc[i][0] = v0.x; wc[i][1] = v0.y; wc[i][2] = v0.z; wc[i][3] = v0.w;
    wc[i][4] = v1.x; wc[i][5] = v1.y; wc[i][6] = v1.z; wc[i][7] = v1.w;
  }
  float w2c[8];
  {
    const float4 a0 = *(const float4*)(W2 + c * 8);
    const float4 a1 = *(const float4*)(W2 + c * 8 + 4);
    w2c[0] = a0.x; w2c[1] = a0.y; w2c[2] = a0.z; w2c[3] = a0.w;
    w2c[4] = a1.x; w2c[5] = a1.y; w2c[6] = a1.z; w2c[7] = a1.w;
  }
  const float b2 = B2[0];
  const int wave_id = blockIdx.x * 4 + (threadIdx.x >> 6);
  const int nwaves = gridDim.x * 4;
  for (int t0 = wave_id * 8; t0 < E; t0 += nwaves * 8) {
    const int e = t0 + g;
    const bool ok = e < E;
    const int ee = ok ? e : E - 1;
    const int s = S[ee], d = D[ee];
    const bf16x8 pa = *(const bf16x8*)(PA + (size_t)s * 64 + c * 8);
    const bf16x8 pb = *(const bf16x8*)(PB + (size_t)d * 64 + c * 8);
    const float4 ef0 = *(const float4*)(EFX + (size_t)ee * 8);
    const float4 ef1 = *(const float4*)(EFX + (size_t)ee * 8 + 4);
    const unsigned* pau = (const unsigned*)&pa;
    const unsigned* pbu = (const unsigned*)&pb;
    float h[8];
#pragma unroll
    for (int q = 0; q < 4; ++q) {
      h[2 * q] = __uint_as_float(pau[q] << 16) + __uint_as_float(pbu[q] << 16);
      h[2 * q + 1] = __uint_as_float(pau[q] & 0xffff0000u) +
                     __uint_as_float(pbu[q] & 0xffff0000u);
    }
    const float ef[8] = {ef0.x, ef0.y, ef0.z, ef0.w, ef1.x, ef1.y, ef1.z, ef1.w};
#pragma unroll
    for (int i = 0; i < 8; ++i)
#pragma unroll
      for (int j = 0; j < 8; ++j) h[j] = fmaf(ef[i], wc[i][j], h[j]);
    float t = 0.0f;
#pragma unroll
    for (int j = 0; j < 8; ++j) t = fmaf(fmaxf(h[j], 0.0f), w2c[j], t);
#pragma unroll
    for (int off = 1; off < 8; off <<= 1) t += __shfl_xor(t, off, 64);
    if (ok && c == 0) EW[e] = sigmoid_f(t + b2);
  }
}

// ======================= CSR aggregation =====================================
__global__ void __launch_bounds__(256) agg_k(
    const int* __restrict__ row_ptr, const unsigned* __restrict__ adj,
    const float* __restrict__ degi, const unsigned short* __restrict__ MSGb,
    unsigned short* __restrict__ AGGb, int base, int N) {
  const int l = threadIdx.x & 63;
  const int n = blockIdx.x * 4 + (threadIdx.x >> 6);
  if (n >= N) return;
  const int g = l >> 3, c = l & 7;
  const int s = row_ptr[base + n], e = row_ptr[base + n + 1];
  float acc[8];
#pragma unroll
  for (int j = 0; j < 8; ++j) acc[j] = 0.0f;
  for (int p0 = s; p0 < e; p0 += 64) {
    const int myp = p0 + l;
    const unsigned av_l = adj[myp < e ? myp : s];  // coalesced 64-wide
    const int rem = e - p0;
#pragma unroll
    for (int b = 0; b < 8; ++b) {
      if (b * 8 >= rem) break;
      const unsigned av = __shfl(av_l, b * 8 + g, 64);
      const bool ok = b * 8 + g < rem;
      const float w = ok ? (float)(av & 16383u) * WQ_INV : 0.0f;
      const bf16x8 m = *(const bf16x8*)(MSGb + (size_t)(av >> 14) * 64 + c * 8);
      const unsigned* mu = (const unsigned*)&m;
#pragma unroll
      for (int q = 0; q < 4; ++q) {
        const float lo = __uint_as_float(mu[q] << 16);
        const float hi = __uint_as_float(mu[q] & 0xffff0000u);
        acc[2 * q] = fmaf(lo, w, acc[2 * q]);
        acc[2 * q + 1] = fmaf(hi, w, acc[2 * q + 1]);
      }
    }
  }
#pragma unroll
  for (int off = 8; off < 64; off <<= 1)
#pragma unroll
    for (int j = 0; j < 8; ++j) acc[j] += __shfl_xor(acc[j], off, 64);
  if (g == 0) {
    const float di = degi[base + n];
    unsigned out[4];
#pragma unroll
    for (int q = 0; q < 4; ++q)
      out[q] = (unsigned)f2bf(acc[2 * q] * di) |
               ((unsigned)f2bf(acc[2 * q + 1] * di) << 16);
    *(uint4*)(AGGb + (size_t)n * 64 + c * 8) =
        make_uint4(out[0], out[1], out[2], out[3]);
  }
}

// ======================= CSR build: count, scan, fill, deg ===================
__global__ void __launch_bounds__(256) count_k(
    const int* __restrict__ S, const int* __restrict__ D,
    int* __restrict__ counts, int baseD, int baseS, int E) {
  const int e = blockIdx.x * 256 + threadIdx.x;
  if (e >= E) return;
  atomicAdd(&counts[baseD + D[e]], 1);
  atomicAdd(&counts[baseS + S[e]], 1);
}

__global__ void __launch_bounds__(256) fill_binned_k(
    const int* __restrict__ S, const int* __restrict__ D,
    const float* __restrict__ EW, int* __restrict__ cursor,
    unsigned* __restrict__ adj, int baseD, int baseS, int NDrows, int NSrows,
    int E) {
  const int bin = blockIdx.x & (NBIN - 1);
  const int blk = blockIdx.x / NBIN;
  const int nblk = gridDim.x / NBIN;
  const int d_lo = (int)((long long)NDrows * bin / NBIN);
  const int d_hi = (int)((long long)NDrows * (bin + 1) / NBIN);
  const int s_lo = (int)((long long)NSrows * bin / NBIN);
  const int s_hi = (int)((long long)NSrows * (bin + 1) / NBIN);
  for (int e = blk * 256 + threadIdx.x; e < E; e += nblk * 256) {
    const int s = S[e], d = D[e];
    const bool md = (d >= d_lo) & (d < d_hi);
    const bool ms = (s >= s_lo) & (s < s_hi);
    if (md | ms) {
      const unsigned w14 = (unsigned)(EW[e] * WQ_SCALE + 0.5f);
      if (md) {
        const int p = atomicAdd(&cursor[baseD + d], 1);
        adj[p] = ((unsigned)s << 14) | w14;
      }
      if (ms) {
        const int p = atomicAdd(&cursor[baseS + s], 1);
        adj[p] = ((unsigned)d << 14) | w14;
      }
    }
  }
}

__global__ void __launch_bounds__(256) degi_k(const int* __restrict__ row_ptr,
                                             const unsigned* __restrict__ adj,
                                             float* __restrict__ degi) {
  const int r = blockIdx.x * 256 + threadIdx.x;
  if (r >= R_TOT) return;
  const int s = row_ptr[r], e = row_ptr[r + 1];
  float d = 0.0f;
  for (int p = s; p < e; ++p) d += (float)(adj[p] & 16383u) * WQ_INV;
  degi[r] = 1.0f / fmaxf(d, 1.0f);
}

__global__ void __launch_bounds__(256) scan1_k(const int* __restrict__ in,
                                               int* __restrict__ bsum) {
  __shared__ int sd[256];
  const int t = threadIdx.x;
  const int base = blockIdx.x * SCAN_CHUNK + t * 8;
  int s = 0;
#pragma unroll
  for (int i = 0; i < 8; ++i) {
    const int idx = base + i;
    s += (idx < R_TOT) ? in[idx] : 0;
  }
  sd[t] = s;
  __syncthreads();
  for (int off = 128; off > 0; off >>= 1) {
    if (t < off) sd[t] += sd[t + off];
    __syncthreads();
  }
  if (t == 0) bsum[blockIdx.x] = sd[0];
}

__global__ void __launch_bounds__(256) scan2_k(int* __restrict__ bsum,
                                               int* __restrict__ row_ptr) {
  __shared__ int sd[256];
  const int t = threadIdx.x;
  const int v = (t < SCAN_NB) ? bsum[t] : 0;
  sd[t] = v;
  __syncthreads();
  for (int off = 1; off < 256; off <<= 1) {
    const int add = (t >= off) ? sd[t - off] : 0;
    __syncthreads();
    sd[t] += add;
    __syncthreads();
  }
  if (t < SCAN_NB) bsum[t] = sd[t] - v;
  if (t == 255) row_ptr[R_TOT] = sd[255];
}

__global__ void __launch_bounds__(256) scan3_k(const int* __restrict__ in,
                                               const int* __restrict__ bsum,
                                               int* __restrict__ out) {
  __shared__ int sd[256];
  const int t = threadIdx.x;
  const int base = blockIdx.x * SCAN_CHUNK + t * 8;
  int loc[8];
  int s = 0;
#pragma unroll
  for (int i = 0; i < 8; ++i) {
    loc[i] = s;
    const int idx = base + i;
    s += (idx < R_TOT) ? in[idx] : 0;
  }
  sd[t] = s;
  __syncthreads();
  const int v = s;
  for (int off = 1; off < 256; off <<= 1) {
    const int add = (t >= off) ? sd[t - off] : 0;
    __syncthreads();
    sd[t] += add;
    __syncthreads();
  }
  const int off0 = bsum[blockIdx.x] + (sd[t] - v);
#pragma unroll
  for (int i = 0; i < 8; ++i) {
    const int idx = base + i;
    if (idx < R_TOT) out[idx] = off0 + loc[i];
  }
}

}  // namespace

extern "C" void kernel_launch(void* const* d_in, const int* in_sizes, int n_in,
                              void* d_out, int out_size, void* d_ws, size_t ws_size,
                              hipStream_t stream) {
  (void)in_sizes; (void)n_in; (void)out_size; (void)ws_size;

  const float* variable_features   = (const float*)d_in[0];
  const float* constraint_features = (const float*)d_in[1];
  const float* cut_features        = (const float*)d_in[2];
  const float* vc_ef = (const float*)d_in[3];
  const float* vk_ef = (const float*)d_in[4];
  const int* vc_edges = (const int*)d_in[5];
  const int* vk_edges = (const int*)d_in[6];
  const int *vc_s = vc_edges, *vc_d = vc_edges + EVC;
  const int *vk_s = vk_edges, *vk_d = vk_edges + EVK;
  const float* var_w1  = (const float*)d_in[7];
  const float* var_b1  = (const float*)d_in[8];
  const float* var_w2  = (const float*)d_in[9];
  const float* var_b2  = (const float*)d_in[10];
  const float* cons_w1 = (const float*)d_in[11];
  const float* cons_b1 = (const float*)d_in[12];
  const float* cons_w2 = (const float*)d_in[13];
  const float* cons_b2 = (const float*)d_in[14];
  const float* cut_w1  = (const float*)d_in[15];
  const float* cut_b1  = (const float*)d_in[16];
  const float* cut_w2  = (const float*)d_in[17];
  const float* cut_b2  = (const float*)d_in[18];
  const float* ewvc_w1 = (const float*)d_in[19];
  const float* ewvc_b1 = (const float*)d_in[20];
  const float* ewvc_w2 = (const float*)d_in[21];
  const float* ewvc_b2 = (const float*)d_in[22];
  const float* ewvk_w1 = (const float*)d_in[23];
  const float* ewvk_b1 = (const float*)d_in[24];
  const float* ewvk_w2 = (const float*)d_in[25];
  const float* ewvk_b2 = (const float*)d_in[26];
  const float* mp_msg_w1 = (const float*)d_in[27];
  const float* mp_msg_b1 = (const float*)d_in[28];
  const float* mp_msg_w2 = (const float*)d_in[29];
  const float* mp_msg_b2 = (const float*)d_in[30];
  const float* mp_gate_w = (const float*)d_in[31];
  const float* mp_gate_b = (const float*)d_in[32];
  const float* mp_upd_w1 = (const float*)d_in[33];
  const float* mp_upd_b1 = (const float*)d_in[34];
  const float* mp_upd_w2 = (const float*)d_in[35];
  const float* mp_upd_b2 = (const float*)d_in[36];
  const float* mp_ln_g   = (const float*)d_in[37];
  const float* mp_ln_b   = (const float*)d_in[38];

  // ---- workspace carve ----
  char* wp = (char*)d_ws;
  auto take = [&](size_t nbytes) {
    char* p = wp;
    wp += (nbytes + 255) & ~(size_t)255;
    return p;
  };
  unsigned short* h_var_b  = (unsigned short*)take((size_t)NV * 64 * 2);
  unsigned short* h_cons_b = (unsigned short*)take((size_t)NC * 64 * 2);
  unsigned short* h_cut_b  = (unsigned short*)take((size_t)NK * 64 * 2);
  unsigned short* msg_b = (unsigned short*)take((size_t)NV * 64 * 2);
  unsigned short* agg_b = (unsigned short*)take((size_t)NV * 64 * 2);
  unsigned short* pa = (unsigned short*)take((size_t)NV * 64 * 2);
  unsigned short* pb = (unsigned short*)take((size_t)NC * 64 * 2);
  unsigned short* qa = (unsigned short*)take((size_t)NV * 64 * 2);
  unsigned short* qb = (unsigned short*)take((size_t)NK * 64 * 2);
  unsigned short* packW = (unsigned short*)take((size_t)15 * PACK_PER_LAYER * 2);
  unsigned short* packE = (unsigned short*)take((size_t)PE_TOTAL * 2);
  float* ew_vc = (float*)take((size_t)EVC * 4);
  float* ew_vk = (float*)take((size_t)EVK * 4);
  int* row_ptr = (int*)take((size_t)(R_TOT + 1) * 4);
  int* cursor  = (int*)take((size_t)R_TOT * 4);
  int* counts  = (int*)take((size_t)R_TOT * 4);
  int* bsum    = (int*)take(256 * 4);
  float* degi  = (float*)take((size_t)R_TOT * 4);
  unsigned* adj = (unsigned*)take((size_t)(2 * EVC + 2 * EVK) * 4);

  // ---- CSR counts + scan ----
  hipMemsetAsync(counts, 0, (size_t)R_TOT * 4, stream);
  count_k<<<(EVC + 255) / 256, 256, 0, stream>>>(vc_s, vc_d, counts, 0, NC, EVC);
  count_k<<<(EVK + 255) / 256, 256, 0, stream>>>(vk_s, vk_d, counts, NC + NV,
                                                 NC + NV + NK, EVK);
  scan1_k<<<SCAN_NB, 256, 0, stream>>>(counts, bsum);
  scan2_k<<<1, 256, 0, stream>>>(bsum, row_ptr);
  scan3_k<<<SCAN_NB, 256, 0, stream>>>(counts, bsum, row_ptr);

  // ---- pack weights (MP layers + embeddings/edge-weight mats) ----
  pack_k<<<15, 256, 0, stream>>>(mp_msg_w1, mp_msg_w2, mp_gate_w, mp_upd_w1,
                                 mp_upd_w2, packW);
  pack_emb_k<<<10, 256, 0, stream>>>(var_w1, var_w2, cons_w1, cons_w2, cut_w1,
                                     cut_w2, ewvc_w1, ewvk_w1, packE);

  // ---- embeddings (MFMA, bf16 out) ----
  emb_mfma_k<19><<<(NV + 63) / 64, 256, 0, stream>>>(
      variable_features, packE + PE_VAR_W1, packE + PE_VAR_W2, var_b1, var_b2,
      h_var_b, NV);
  emb_mfma_k<5><<<(NC + 63) / 64, 256, 0, stream>>>(
      constraint_features, packE + PE_CONS_W1, packE + PE_CONS_W2, cons_b1,
      cons_b2, h_cons_b, NC);
  emb_mfma_k<30><<<(NK + 63) / 64, 256, 0, stream>>>(
      cut_features, packE + PE_CUT_W1, packE + PE_CUT_W2, cut_b1, cut_b2,
      h_cut_b, NK);

  // ---- edge-weight per-node terms (MFMA; var does both projections) ----
  gemv_mfma_k<2><<<(NV + 63) / 64, 256, 0, stream>>>(
      h_var_b, packE + PE_EWVC_A, packE + PE_EWVK_A, nullptr, pa, qa, NV);
  gemv_mfma_k<1><<<(NC + 63) / 64, 256, 0, stream>>>(
      h_cons_b, packE + PE_EWVC_B, nullptr, ewvc_b1, pb, nullptr, NC);
  gemv_mfma_k<1><<<(NK + 63) / 64, 256, 0, stream>>>(
      h_cut_b, packE + PE_EWVK_B, nullptr, ewvk_b1, qb, nullptr, NK);

  edgew_k<<<1024, 256, 0, stream>>>(vc_s, vc_d, vc_ef, pa, pb,
                                    ewvc_w1 + 128 * 64, ewvc_w2, ewvc_b2,
                                    ew_vc, EVC);
  edgew_k<<<512, 256, 0, stream>>>(vk_s, vk_d, vk_ef, qa, qb,
                                   ewvk_w1 + 128 * 64, ewvk_w2, ewvk_b2,
                                   ew_vk, EVK);

  // ---- CSR fill (binned, XCD-local stores) + per-row 1/deg ----
  hipMemcpyAsync(cursor, row_ptr, (size_t)R_TOT * 4, hipMemcpyDeviceToDevice, stream);
  fill_binned_k<<<NBIN * 128, 256, 0, stream>>>(vc_s, vc_d, ew_vc, cursor, adj,
                                                0, NC, NC, NV, EVC);
  fill_binned_k<<<NBIN * 64, 256, 0, stream>>>(vk_s, vk_d, ew_vk, cursor, adj,
                                               NC + NV, NC + NV + NK, NK, NV, EVK);
  degi_k<<<(R_TOT + 255) / 256, 256, 0, stream>>>(row_ptr, adj, degi);

  // ---- 15 message passes; upd(i) fused with msg(i+1) ----
  unsigned short* nodeb_t[4] = {h_cons_b, h_var_b, h_cut_b, h_var_b};
  const int Nd_t[4] = {NC, NV, NK, NV};
  const int base_t[4] = {0, NC, NC + NV, NC + NV + NK};

  // msg(0): over h_var with layer-0 msg weights
  msg_mfma_k<<<(NV + 63) / 64, 256, 0, stream>>>(
      h_var_b, packW, mp_msg_b1, mp_msg_b2, msg_b, NV);

  for (int i = 0; i < 15; ++i) {
    const int d = i & 3;
    const int Nd = Nd_t[d], base = base_t[d];
    const unsigned short* Wl = packW + (size_t)i * PACK_PER_LAYER;

    agg_k<<<(Nd + 3) / 4, 256, 0, stream>>>(row_ptr, adj, degi, msg_b, agg_b,
                                            base, Nd);
    if (i < 14) {
      const unsigned short* Wn = packW + (size_t)(i + 1) * PACK_PER_LAYER;
      updmsg_mfma_k<1><<<(Nd + 63) / 64, 256, 0, stream>>>(
          agg_b, nodeb_t[d], Wl + 8192, Wl + 16384, Wl + 24576,
          mp_gate_b + (size_t)i * 64, mp_upd_b1 + (size_t)i * 64,
          mp_upd_b2 + (size_t)i * 64, mp_ln_g + (size_t)i * 64,
          mp_ln_b + (size_t)i * 64, Wn, mp_msg_b1 + (size_t)(i + 1) * 64,
          mp_msg_b2 + (size_t)(i + 1) * 64, nullptr, nodeb_t[d], msg_b, Nd);
    } else {
      updmsg_mfma_k<0><<<(Nd + 63) / 64, 256, 0, stream>>>(
          agg_b, nodeb_t[d], Wl + 8192, Wl + 16384, Wl + 24576,
          mp_gate_b + (size_t)i * 64, mp_upd_b1 + (size_t)i * 64,
          mp_upd_b2 + (size_t)i * 64, mp_ln_g + (size_t)i * 64,
          mp_ln_b + (size_t)i * 64, nullptr, nullptr, nullptr,
          (float*)d_out, nullptr, nullptr, Nd);
    }
  }
}

// Round 9
// 942.285 us; speedup vs baseline: 5.3135x; 1.2059x over previous
//
#include <hip/hip_runtime.h>

#define DEVINL static __device__ __forceinline__

namespace {

typedef __attribute__((ext_vector_type(8))) short bf16x8;
typedef __attribute__((ext_vector_type(4))) float f32x4;

constexpr int NV = 100000;   // variables
constexpr int NC = 50000;    // constraints
constexpr int NK = 20000;    // cuts
constexpr int EVC = 800000;  // var-cons edges
constexpr int EVK = 200000;  // var-cut edges
constexpr int R_TOT = NC + NV + NK + NV;  // 270000 CSR rows
constexpr int SCAN_CHUNK = 2048;
constexpr int SCAN_NB = (R_TOT + SCAN_CHUNK - 1) / SCAN_CHUNK;  // 132
constexpr int PACK_PER_LAYER = 28672;  // ushort per layer of packed MP weights
constexpr float WQ_SCALE = 16383.0f;
constexpr float WQ_INV = 1.0f / 16383.0f;
constexpr int NBIN = 8;  // fill bins; blockIdx%8 aligns with XCD round-robin

// packed embedding/edge-weight matrix offsets (ushort)
constexpr int PE_VAR_W1 = 0;      // Kpad=32 -> 2048
constexpr int PE_VAR_W2 = 2048;   // K=64   -> 4096
constexpr int PE_CONS_W1 = 6144;  // 2048
constexpr int PE_CONS_W2 = 8192;  // 4096
constexpr int PE_CUT_W1 = 12288;  // 2048
constexpr int PE_CUT_W2 = 14336;  // 4096
constexpr int PE_EWVC_A = 18432;  // 4096
constexpr int PE_EWVC_B = 22528;  // 4096
constexpr int PE_EWVK_A = 26624;  // 4096
constexpr int PE_EWVK_B = 30720;  // 4096
constexpr int PE_TOTAL = 34816;

DEVINL unsigned short f2bf(float f) {
  unsigned u = __float_as_uint(f);
  u = u + 0x7fffu + ((u >> 16) & 1u);  // RNE
  return (unsigned short)(u >> 16);
}
DEVINL float bf2f(unsigned short h) {
  return __uint_as_float((unsigned)h << 16);
}

DEVINL float sigmoid_f(float x) { return 1.0f / (1.0f + __expf(-x)); }

// ======================= weight packing (bf16 B-frag streams) ================
DEVINL void pack_mat(const float* __restrict__ src, int K, int Kpad,
                     unsigned short* __restrict__ dst, int tid) {
  const int ntup = (Kpad / 32) * 256;
  for (int tup = tid; tup < ntup; tup += 256) {
    const int lane = tup & 63;
    const int t = (tup >> 6) & 3;
    const int kb = tup >> 8;
    const int c = t * 16 + (lane & 15);
    const int k0 = kb * 32 + (lane >> 4) * 8;
#pragma unroll
    for (int jj = 0; jj < 8; ++jj)
      dst[tup * 8 + jj] =
          (k0 + jj < K) ? f2bf(src[(k0 + jj) * 64 + c]) : (unsigned short)0;
  }
}

__global__ void __launch_bounds__(256) pack_k(
    const float* __restrict__ mW1, const float* __restrict__ mW2,
    const float* __restrict__ gW, const float* __restrict__ uW1,
    const float* __restrict__ uW2, unsigned short* __restrict__ PW) {
  const int layer = blockIdx.x;  // 0..14
  unsigned short* out = PW + (size_t)layer * PACK_PER_LAYER;
  pack_mat(mW1 + (size_t)layer * 4096, 64, 64, out, threadIdx.x);
  pack_mat(mW2 + (size_t)layer * 4096, 64, 64, out + 4096, threadIdx.x);
  pack_mat(gW + (size_t)layer * 8192, 128, 128, out + 8192, threadIdx.x);
  pack_mat(uW1 + (size_t)layer * 8192, 128, 128, out + 16384, threadIdx.x);
  pack_mat(uW2 + (size_t)layer * 4096, 64, 64, out + 24576, threadIdx.x);
}

__global__ void __launch_bounds__(256) pack_emb_k(
    const float* __restrict__ var_w1, const float* __restrict__ var_w2,
    const float* __restrict__ cons_w1, const float* __restrict__ cons_w2,
    const float* __restrict__ cut_w1, const float* __restrict__ cut_w2,
    const float* __restrict__ ewvc_w1, const float* __restrict__ ewvk_w1,
    unsigned short* __restrict__ P) {
  switch (blockIdx.x) {
    case 0: pack_mat(var_w1, 19, 32, P + PE_VAR_W1, threadIdx.x); break;
    case 1: pack_mat(var_w2, 64, 64, P + PE_VAR_W2, threadIdx.x); break;
    case 2: pack_mat(cons_w1, 5, 32, P + PE_CONS_W1, threadIdx.x); break;
    case 3: pack_mat(cons_w2, 64, 64, P + PE_CONS_W2, threadIdx.x); break;
    case 4: pack_mat(cut_w1, 30, 32, P + PE_CUT_W1, threadIdx.x); break;
    case 5: pack_mat(cut_w2, 64, 64, P + PE_CUT_W2, threadIdx.x); break;
    case 6: pack_mat(ewvc_w1, 64, 64, P + PE_EWVC_A, threadIdx.x); break;
    case 7: pack_mat(ewvc_w1 + 64 * 64, 64, 64, P + PE_EWVC_B, threadIdx.x); break;
    case 8: pack_mat(ewvk_w1, 64, 64, P + PE_EWVK_A, threadIdx.x); break;
    case 9: pack_mat(ewvk_w1 + 64 * 64, 64, 64, P + PE_EWVK_B, threadIdx.x); break;
  }
}

// ======================= embedding MLP (MFMA, K1 padded to 32) ===============
template <int DIN>
__global__ void __launch_bounds__(256) emb_mfma_k(
    const float* __restrict__ X, const unsigned short* __restrict__ W1p_,
    const unsigned short* __restrict__ W2p_, const float* __restrict__ B1,
    const float* __restrict__ B2, unsigned short* __restrict__ OUTb, int N) {
  __shared__ unsigned short lds[4][16 * 72];
  const int wave = threadIdx.x >> 6, l = threadIdx.x & 63;
  const int col = l & 15, quad = l >> 4;
  const int n0_raw = blockIdx.x * 64 + wave * 16;
  const bool dead = n0_raw >= N;
  const int n0 = dead ? 0 : n0_raw;

  bf16x8 a0;
#pragma unroll
  for (int j = 0; j < 8; ++j) {
    const int k = quad * 8 + j;
    a0[j] = (k < DIN) ? (short)f2bf(X[(size_t)(n0 + col) * DIN + k]) : (short)0;
  }
  const bf16x8* W1p = (const bf16x8*)W1p_;
  const bf16x8* W2p = (const bf16x8*)W2p_;
  f32x4 acc[4];
#pragma unroll
  for (int t = 0; t < 4; ++t) {
    const float b = B1[col + 16 * t];
    acc[t] = f32x4{b, b, b, b};
  }
#pragma unroll
  for (int t = 0; t < 4; ++t)
    acc[t] = __builtin_amdgcn_mfma_f32_16x16x32_bf16(a0, W1p[t * 64 + l], acc[t], 0, 0, 0);
  unsigned short* ld = lds[wave];
#pragma unroll
  for (int t = 0; t < 4; ++t)
#pragma unroll
    for (int r = 0; r < 4; ++r)
      ld[(quad * 4 + r) * 72 + col + 16 * t] = f2bf(fmaxf(acc[t][r], 0.0f));
  __syncthreads();
  const bf16x8 h0 = *(const bf16x8*)&ld[col * 72 + quad * 8];
  const bf16x8 h1 = *(const bf16x8*)&ld[col * 72 + 32 + quad * 8];
  f32x4 o[4];
#pragma unroll
  for (int t = 0; t < 4; ++t) {
    const float b = B2[col + 16 * t];
    o[t] = f32x4{b, b, b, b};
  }
#pragma unroll
  for (int t = 0; t < 4; ++t) {
    o[t] = __builtin_amdgcn_mfma_f32_16x16x32_bf16(h0, W2p[t * 64 + l], o[t], 0, 0, 0);
    o[t] = __builtin_amdgcn_mfma_f32_16x16x32_bf16(h1, W2p[(4 + t) * 64 + l], o[t], 0, 0, 0);
  }
  __syncthreads();
#pragma unroll
  for (int t = 0; t < 4; ++t)
#pragma unroll
    for (int r = 0; r < 4; ++r)
      ld[(quad * 4 + r) * 72 + col + 16 * t] = f2bf(o[t][r]);
  __syncthreads();
  if (!dead) {
#pragma unroll
    for (int cc = 0; cc < 2; ++cc) {
      const bf16x8 v = *(const bf16x8*)&ld[col * 72 + (quad * 2 + cc) * 8];
      *(bf16x8*)(OUTb + (size_t)(n0 + col) * 64 + (quad * 2 + cc) * 8) = v;
    }
  }
}

// ======= edge-weight per-node GEMV (MFMA); NOUT=2 shares the A-frag =========
template <int NOUT>
__global__ void __launch_bounds__(256) gemv_mfma_k(
    const unsigned short* __restrict__ Xb, const unsigned short* __restrict__ WpA_,
    const unsigned short* __restrict__ WpB_, const float* __restrict__ Bias,
    unsigned short* __restrict__ OUT0, unsigned short* __restrict__ OUT1, int N) {
  __shared__ unsigned short lds[4][16 * 72];
  const int wave = threadIdx.x >> 6, l = threadIdx.x & 63;
  const int col = l & 15, quad = l >> 4;
  const int n0_raw = blockIdx.x * 64 + wave * 16;
  const bool dead = n0_raw >= N;
  const int n0 = dead ? 0 : n0_raw;
  const unsigned short* xrow = Xb + (size_t)(n0 + col) * 64 + quad * 8;
  const bf16x8 a0 = *(const bf16x8*)xrow;
  const bf16x8 a1 = *(const bf16x8*)(xrow + 32);
  unsigned short* ld = lds[wave];
#pragma unroll
  for (int m = 0; m < NOUT; ++m) {
    const bf16x8* Wp = (const bf16x8*)(m == 0 ? WpA_ : WpB_);
    unsigned short* OUT = (m == 0) ? OUT0 : OUT1;
    f32x4 acc[4];
#pragma unroll
    for (int t = 0; t < 4; ++t) {
      const float b = (Bias != nullptr) ? Bias[col + 16 * t] : 0.0f;
      acc[t] = f32x4{b, b, b, b};
    }
#pragma unroll
    for (int t = 0; t < 4; ++t) {
      acc[t] = __builtin_amdgcn_mfma_f32_16x16x32_bf16(a0, Wp[t * 64 + l], acc[t], 0, 0, 0);
      acc[t] = __builtin_amdgcn_mfma_f32_16x16x32_bf16(a1, Wp[(4 + t) * 64 + l], acc[t], 0, 0, 0);
    }
    if (m > 0) __syncthreads();
#pragma unroll
    for (int t = 0; t < 4; ++t)
#pragma unroll
      for (int r = 0; r < 4; ++r)
        ld[(quad * 4 + r) * 72 + col + 16 * t] = f2bf(acc[t][r]);
    __syncthreads();
    if (!dead) {
#pragma unroll
      for (int cc = 0; cc < 2; ++cc) {
        const bf16x8 v = *(const bf16x8*)&ld[col * 72 + (quad * 2 + cc) * 8];
        *(bf16x8*)(OUT + (size_t)(n0 + col) * 64 + (quad * 2 + cc) * 8) = v;
      }
    }
  }
}

// ======================= message MLP (MFMA) — used once for pass 0 ===========
__global__ void __launch_bounds__(256) msg_mfma_k(
    const unsigned short* __restrict__ Xb, const unsigned short* __restrict__ Wp,
    const float* __restrict__ B1, const float* __restrict__ B2,
    unsigned short* __restrict__ MSGb, int N) {
  __shared__ unsigned short lds[4][16 * 72];
  const int wave = threadIdx.x >> 6, l = threadIdx.x & 63;
  const int col = l & 15, quad = l >> 4;
  const int n0_raw = blockIdx.x * 64 + wave * 16;
  const bool dead = n0_raw >= N;
  const int n0 = dead ? 0 : n0_raw;

  const unsigned short* xrow = Xb + (size_t)(n0 + col) * 64 + quad * 8;
  const bf16x8 a0 = *(const bf16x8*)xrow;
  const bf16x8 a1 = *(const bf16x8*)(xrow + 32);
  const bf16x8* W1p = (const bf16x8*)Wp;
  const bf16x8* W2p = (const bf16x8*)(Wp + 4096);

  f32x4 acc[4];
#pragma unroll
  for (int t = 0; t < 4; ++t) {
    const float b = B1[col + 16 * t];
    acc[t] = f32x4{b, b, b, b};
  }
#pragma unroll
  for (int t = 0; t < 4; ++t) {
    acc[t] = __builtin_amdgcn_mfma_f32_16x16x32_bf16(a0, W1p[t * 64 + l], acc[t], 0, 0, 0);
    acc[t] = __builtin_amdgcn_mfma_f32_16x16x32_bf16(a1, W1p[(4 + t) * 64 + l], acc[t], 0, 0, 0);
  }
  unsigned short* ld = lds[wave];
#pragma unroll
  for (int t = 0; t < 4; ++t)
#pragma unroll
    for (int r = 0; r < 4; ++r)
      ld[(quad * 4 + r) * 72 + col + 16 * t] = f2bf(fmaxf(acc[t][r], 0.0f));
  __syncthreads();
  const bf16x8 h0 = *(const bf16x8*)&ld[col * 72 + quad * 8];
  const bf16x8 h1 = *(const bf16x8*)&ld[col * 72 + 32 + quad * 8];
  f32x4 o[4];
#pragma unroll
  for (int t = 0; t < 4; ++t) {
    const float b = B2[col + 16 * t];
    o[t] = f32x4{b, b, b, b};
  }
#pragma unroll
  for (int t = 0; t < 4; ++t) {
    o[t] = __builtin_amdgcn_mfma_f32_16x16x32_bf16(h0, W2p[t * 64 + l], o[t], 0, 0, 0);
    o[t] = __builtin_amdgcn_mfma_f32_16x16x32_bf16(h1, W2p[(4 + t) * 64 + l], o[t], 0, 0, 0);
  }
  __syncthreads();
#pragma unroll
  for (int t = 0; t < 4; ++t)
#pragma unroll
    for (int r = 0; r < 4; ++r)
      ld[(quad * 4 + r) * 72 + col + 16 * t] = f2bf(o[t][r]);
  __syncthreads();
  if (!dead) {
#pragma unroll
    for (int cc = 0; cc < 2; ++cc) {
      const bf16x8 v = *(const bf16x8*)&ld[col * 72 + (quad * 2 + cc) * 8];
      *(bf16x8*)(MSGb + (size_t)(n0 + col) * 64 + (quad * 2 + cc) * 8) = v;
    }
  }
}

// ==== fully-fused pass: CSR-aggregate + gate/upd/mix/LN + next-layer msg =====
// Aggregation builds the A-frags in-register: lane (col,quad) walks row
// n0+col's edges accumulating channels quad*8..+8 and 32+quad*8..+8.
// MSGsrc/MSGdst must be DIFFERENT buffers (ping-pong): blocks read src rows
// of the source type while other blocks write dst rows concurrently.
template <int WITH_MSG>
__global__ void __launch_bounds__(256) pass_mfma_k(
    const int* __restrict__ row_ptr, const unsigned* __restrict__ adj,
    const float* __restrict__ degi, const unsigned short* __restrict__ MSGsrc,
    const unsigned short* __restrict__ NODEb,
    const unsigned short* __restrict__ gWp, const unsigned short* __restrict__ uW1p,
    const unsigned short* __restrict__ uW2p, const float* __restrict__ gB,
    const float* __restrict__ uB1, const float* __restrict__ uB2,
    const float* __restrict__ LNG, const float* __restrict__ LNB,
    const unsigned short* __restrict__ mWp,  // next layer msg W1|W2 (packed)
    const float* __restrict__ mB1, const float* __restrict__ mB2,
    float* __restrict__ OUTf, unsigned short* __restrict__ OUTb,
    unsigned short* __restrict__ MSGdst, int base, int N) {
  __shared__ unsigned short lds[4][16 * 72];
  const int wave = threadIdx.x >> 6, l = threadIdx.x & 63;
  const int col = l & 15, quad = l >> 4;
  const int n0_raw = blockIdx.x * 64 + wave * 16;
  const bool dead = n0_raw >= N;
  const int n0 = dead ? 0 : n0_raw;

  // ---- phase 1: aggregate (replaces agg_k + AGGb round-trip) ----
  const int r = base + n0 + col;
  const int ps = row_ptr[r], pe = row_ptr[r + 1];
  float acc0[8], acc1[8];
#pragma unroll
  for (int j = 0; j < 8; ++j) { acc0[j] = 0.0f; acc1[j] = 0.0f; }
  int p = ps;
  for (; p + 2 <= pe; p += 2) {  // x2 unroll for load ILP
    const unsigned avA = adj[p], avB = adj[p + 1];
    const unsigned short* mA = MSGsrc + (size_t)(avA >> 14) * 64 + quad * 8;
    const unsigned short* mB = MSGsrc + (size_t)(avB >> 14) * 64 + quad * 8;
    const bf16x8 mA0 = *(const bf16x8*)mA;
    const bf16x8 mA1 = *(const bf16x8*)(mA + 32);
    const bf16x8 mB0 = *(const bf16x8*)mB;
    const bf16x8 mB1v = *(const bf16x8*)(mB + 32);
    const float wA = (float)(avA & 16383u) * WQ_INV;
    const float wB = (float)(avB & 16383u) * WQ_INV;
    const unsigned* uA0 = (const unsigned*)&mA0;
    const unsigned* uA1 = (const unsigned*)&mA1;
    const unsigned* uB0 = (const unsigned*)&mB0;
    const unsigned* uB1v = (const unsigned*)&mB1v;
#pragma unroll
    for (int q = 0; q < 4; ++q) {
      acc0[2 * q] = fmaf(__uint_as_float(uA0[q] << 16), wA, acc0[2 * q]);
      acc0[2 * q + 1] = fmaf(__uint_as_float(uA0[q] & 0xffff0000u), wA, acc0[2 * q + 1]);
      acc1[2 * q] = fmaf(__uint_as_float(uA1[q] << 16), wA, acc1[2 * q]);
      acc1[2 * q + 1] = fmaf(__uint_as_float(uA1[q] & 0xffff0000u), wA, acc1[2 * q + 1]);
      acc0[2 * q] = fmaf(__uint_as_float(uB0[q] << 16), wB, acc0[2 * q]);
      acc0[2 * q + 1] = fmaf(__uint_as_float(uB0[q] & 0xffff0000u), wB, acc0[2 * q + 1]);
      acc1[2 * q] = fmaf(__uint_as_float(uB1v[q] << 16), wB, acc1[2 * q]);
      acc1[2 * q + 1] = fmaf(__uint_as_float(uB1v[q] & 0xffff0000u), wB, acc1[2 * q + 1]);
    }
  }
  if (p < pe) {
    const unsigned av = adj[p];
    const unsigned short* m = MSGsrc + (size_t)(av >> 14) * 64 + quad * 8;
    const bf16x8 m0 = *(const bf16x8*)m;
    const bf16x8 m1 = *(const bf16x8*)(m + 32);
    const float w = (float)(av & 16383u) * WQ_INV;
    const unsigned* u0 = (const unsigned*)&m0;
    const unsigned* u1 = (const unsigned*)&m1;
#pragma unroll
    for (int q = 0; q < 4; ++q) {
      acc0[2 * q] = fmaf(__uint_as_float(u0[q] << 16), w, acc0[2 * q]);
      acc0[2 * q + 1] = fmaf(__uint_as_float(u0[q] & 0xffff0000u), w, acc0[2 * q + 1]);
      acc1[2 * q] = fmaf(__uint_as_float(u1[q] << 16), w, acc1[2 * q]);
      acc1[2 * q + 1] = fmaf(__uint_as_float(u1[q] & 0xffff0000u), w, acc1[2 * q + 1]);
    }
  }
  const float di = degi[r];
  bf16x8 aA0, aA1;
#pragma unroll
  for (int j = 0; j < 8; ++j) {
    aA0[j] = (short)f2bf(acc0[j] * di);
    aA1[j] = (short)f2bf(acc1[j] * di);
  }

  // ---- phase 2: gate + upd1 (MFMA) ----
  const unsigned short* nrow = NODEb + (size_t)(n0 + col) * 64 + quad * 8;
  const bf16x8 aN0 = *(const bf16x8*)nrow;
  const bf16x8 aN1 = *(const bf16x8*)(nrow + 32);
  const bf16x8* gW = (const bf16x8*)gWp;
  const bf16x8* uW1 = (const bf16x8*)uW1p;
  const bf16x8* uW2 = (const bf16x8*)uW2p;

  f32x4 g[4], u[4];
#pragma unroll
  for (int t = 0; t < 4; ++t) {
    const float bg = gB[col + 16 * t], bu = uB1[col + 16 * t];
    g[t] = f32x4{bg, bg, bg, bg};
    u[t] = f32x4{bu, bu, bu, bu};
  }
#pragma unroll
  for (int t = 0; t < 4; ++t) {
    g[t] = __builtin_amdgcn_mfma_f32_16x16x32_bf16(aA0, gW[t * 64 + l], g[t], 0, 0, 0);
    g[t] = __builtin_amdgcn_mfma_f32_16x16x32_bf16(aA1, gW[(4 + t) * 64 + l], g[t], 0, 0, 0);
    g[t] = __builtin_amdgcn_mfma_f32_16x16x32_bf16(aN0, gW[(8 + t) * 64 + l], g[t], 0, 0, 0);
    g[t] = __builtin_amdgcn_mfma_f32_16x16x32_bf16(aN1, gW[(12 + t) * 64 + l], g[t], 0, 0, 0);
    u[t] = __builtin_amdgcn_mfma_f32_16x16x32_bf16(aA0, uW1[t * 64 + l], u[t], 0, 0, 0);
    u[t] = __builtin_amdgcn_mfma_f32_16x16x32_bf16(aA1, uW1[(4 + t) * 64 + l], u[t], 0, 0, 0);
    u[t] = __builtin_amdgcn_mfma_f32_16x16x32_bf16(aN0, uW1[(8 + t) * 64 + l], u[t], 0, 0, 0);
    u[t] = __builtin_amdgcn_mfma_f32_16x16x32_bf16(aN1, uW1[(12 + t) * 64 + l], u[t], 0, 0, 0);
  }
#pragma unroll
  for (int t = 0; t < 4; ++t)
#pragma unroll
    for (int r2 = 0; r2 < 4; ++r2) g[t][r2] = sigmoid_f(g[t][r2]);

  unsigned short* ld = lds[wave];
#pragma unroll
  for (int t = 0; t < 4; ++t)
#pragma unroll
    for (int r2 = 0; r2 < 4; ++r2)
      ld[(quad * 4 + r2) * 72 + col + 16 * t] = f2bf(fmaxf(u[t][r2], 0.0f));
  __syncthreads();
  const bf16x8 h0 = *(const bf16x8*)&ld[col * 72 + quad * 8];
  const bf16x8 h1 = *(const bf16x8*)&ld[col * 72 + 32 + quad * 8];
  f32x4 o[4];
#pragma unroll
  for (int t = 0; t < 4; ++t) {
    const float b = uB2[col + 16 * t];
    o[t] = f32x4{b, b, b, b};
  }
#pragma unroll
  for (int t = 0; t < 4; ++t) {
    o[t] = __builtin_amdgcn_mfma_f32_16x16x32_bf16(h0, uW2[t * 64 + l], o[t], 0, 0, 0);
    o[t] = __builtin_amdgcn_mfma_f32_16x16x32_bf16(h1, uW2[(4 + t) * 64 + l], o[t], 0, 0, 0);
  }
  // gate mix (bf16 node carry, C-layout gather) + LayerNorm
  float om[4][4];
#pragma unroll
  for (int t = 0; t < 4; ++t)
#pragma unroll
    for (int r2 = 0; r2 < 4; ++r2) {
      const float nd =
          bf2f(NODEb[(size_t)(n0 + quad * 4 + r2) * 64 + col + 16 * t]);
      om[t][r2] = fmaf(g[t][r2], o[t][r2] - nd, nd);
    }
  float outv[4][4];
#pragma unroll
  for (int r2 = 0; r2 < 4; ++r2) {
    float s1 = (om[0][r2] + om[1][r2]) + (om[2][r2] + om[3][r2]);
    float s2 = fmaf(om[0][r2], om[0][r2], fmaf(om[1][r2], om[1][r2],
                fmaf(om[2][r2], om[2][r2], om[3][r2] * om[3][r2])));
#pragma unroll
    for (int off = 1; off < 16; off <<= 1) {
      s1 += __shfl_xor(s1, off, 64);
      s2 += __shfl_xor(s2, off, 64);
    }
    const float m = s1 * (1.0f / 64.0f);
    const float var = s2 * (1.0f / 64.0f) - m * m;
    const float rr = rsqrtf(var + 1e-3f);
#pragma unroll
    for (int t = 0; t < 4; ++t)
      outv[t][r2] = fmaf((om[t][r2] - m) * rr, LNG[col + 16 * t], LNB[col + 16 * t]);
  }
  if (OUTf != nullptr && !dead) {
#pragma unroll
    for (int t = 0; t < 4; ++t)
#pragma unroll
      for (int r2 = 0; r2 < 4; ++r2)
        OUTf[(size_t)(n0 + quad * 4 + r2) * 64 + col + 16 * t] = outv[t][r2];
  }
  __syncthreads();
#pragma unroll
  for (int t = 0; t < 4; ++t)
#pragma unroll
    for (int r2 = 0; r2 < 4; ++r2)
      ld[(quad * 4 + r2) * 72 + col + 16 * t] = f2bf(outv[t][r2]);
  __syncthreads();
  if (OUTb != nullptr && !dead) {
#pragma unroll
    for (int cc = 0; cc < 2; ++cc) {
      const bf16x8 v = *(const bf16x8*)&ld[col * 72 + (quad * 2 + cc) * 8];
      *(bf16x8*)(OUTb + (size_t)(n0 + col) * 64 + (quad * 2 + cc) * 8) = v;
    }
  }

  if constexpr (WITH_MSG) {
    // ---- phase 3: next layer's message MLP on the just-updated rows ----
    const bf16x8 x0 = *(const bf16x8*)&ld[col * 72 + quad * 8];
    const bf16x8 x1 = *(const bf16x8*)&ld[col * 72 + 32 + quad * 8];
    const bf16x8* W1p = (const bf16x8*)mWp;
    const bf16x8* W2p = (const bf16x8*)(mWp + 4096);
    f32x4 macc[4];
#pragma unroll
    for (int t = 0; t < 4; ++t) {
      const float b = mB1[col + 16 * t];
      macc[t] = f32x4{b, b, b, b};
    }
#pragma unroll
    for (int t = 0; t < 4; ++t) {
      macc[t] = __builtin_amdgcn_mfma_f32_16x16x32_bf16(x0, W1p[t * 64 + l], macc[t], 0, 0, 0);
      macc[t] = __builtin_amdgcn_mfma_f32_16x16x32_bf16(x1, W1p[(4 + t) * 64 + l], macc[t], 0, 0, 0);
    }
    __syncthreads();
#pragma unroll
    for (int t = 0; t < 4; ++t)
#pragma unroll
      for (int r2 = 0; r2 < 4; ++r2)
        ld[(quad * 4 + r2) * 72 + col + 16 * t] = f2bf(fmaxf(macc[t][r2], 0.0f));
    __syncthreads();
    const bf16x8 mh0 = *(const bf16x8*)&ld[col * 72 + quad * 8];
    const bf16x8 mh1 = *(const bf16x8*)&ld[col * 72 + 32 + quad * 8];
    f32x4 mo[4];
#pragma unroll
    for (int t = 0; t < 4; ++t) {
      const float b = mB2[col + 16 * t];
      mo[t] = f32x4{b, b, b, b};
    }
#pragma unroll
    for (int t = 0; t < 4; ++t) {
      mo[t] = __builtin_amdgcn_mfma_f32_16x16x32_bf16(mh0, W2p[t * 64 + l], mo[t], 0, 0, 0);
      mo[t] = __builtin_amdgcn_mfma_f32_16x16x32_bf16(mh1, W2p[(4 + t) * 64 + l], mo[t], 0, 0, 0);
    }
    __syncthreads();
#pragma unroll
    for (int t = 0; t < 4; ++t)
#pragma unroll
      for (int r2 = 0; r2 < 4; ++r2)
        ld[(quad * 4 + r2) * 72 + col + 16 * t] = f2bf(mo[t][r2]);
    __syncthreads();
    if (!dead) {
#pragma unroll
      for (int cc = 0; cc < 2; ++cc) {
        const bf16x8 v = *(const bf16x8*)&ld[col * 72 + (quad * 2 + cc) * 8];
        *(bf16x8*)(MSGdst + (size_t)(n0 + col) * 64 + (quad * 2 + cc) * 8) = v;
      }
    }
  }
}

// ======================= edge weight: 8 edges x 8 chunks per wave ============
__global__ void __launch_bounds__(256) edgew_k(
    const int* __restrict__ S, const int* __restrict__ D,
    const float* __restrict__ EFX, const unsigned short* __restrict__ PA,
    const unsigned short* __restrict__ PB, const float* __restrict__ W1C,
    const float* __restrict__ W2, const float* __restrict__ B2,
    float* __restrict__ EW, int E) {
  const int l = threadIdx.x & 63;
  const int g = l >> 3, c = l & 7;
  float wc[8][8];
#pragma unroll
  for (int i = 0; i < 8; ++i) {
    const float4 v0 = *(const float4*)(W1C + i * 64 + c * 8);
    const float4 v1 = *(const float4*)(W1C + i * 64 + c * 8 + 4);
    wc[i][0] = v0.x; wc[i][1] = v0.y; wc[i][2] = v0.z; wc[i][3] = v0.w;
    wc[i][4] = v1.x; wc[i][5] = v1.y; wc[i][6] = v1.z; wc[i][7] = v1.w;
  }
  float w2c[8];
  {
    const float4 a0 = *(const float4*)(W2 + c * 8);
    const float4 a1 = *(const float4*)(W2 + c * 8 + 4);
    w2c[0] = a0.x; w2c[1] = a0.y; w2c[2] = a0.z; w2c[3] = a0.w;
    w2c[4] = a1.x; w2c[5] = a1.y; w2c[6] = a1.z; w2c[7] = a1.w;
  }
  const float b2 = B2[0];
  const int wave_id = blockIdx.x * 4 + (threadIdx.x >> 6);
  const int nwaves = gridDim.x * 4;
  for (int t0 = wave_id * 8; t0 < E; t0 += nwaves * 8) {
    const int e = t0 + g;
    const bool ok = e < E;
    const int ee = ok ? e : E - 1;
    const int s = S[ee], d = D[ee];
    const bf16x8 pa = *(const bf16x8*)(PA + (size_t)s * 64 + c * 8);
    const bf16x8 pb = *(const bf16x8*)(PB + (size_t)d * 64 + c * 8);
    const float4 ef0 = *(const float4*)(EFX + (size_t)ee * 8);
    const float4 ef1 = *(const float4*)(EFX + (size_t)ee * 8 + 4);
    const unsigned* pau = (const unsigned*)&pa;
    const unsigned* pbu = (const unsigned*)&pb;
    float h[8];
#pragma unroll
    for (int q = 0; q < 4; ++q) {
      h[2 * q] = __uint_as_float(pau[q] << 16) + __uint_as_float(pbu[q] << 16);
      h[2 * q + 1] = __uint_as_float(pau[q] & 0xffff0000u) +
                     __uint_as_float(pbu[q] & 0xffff0000u);
    }
    const float ef[8] = {ef0.x, ef0.y, ef0.z, ef0.w, ef1.x, ef1.y, ef1.z, ef1.w};
#pragma unroll
    for (int i = 0; i < 8; ++i)
#pragma unroll
      for (int j = 0; j < 8; ++j) h[j] = fmaf(ef[i], wc[i][j], h[j]);
    float t = 0.0f;
#pragma unroll
    for (int j = 0; j < 8; ++j) t = fmaf(fmaxf(h[j], 0.0f), w2c[j], t);
#pragma unroll
    for (int off = 1; off < 8; off <<= 1) t += __shfl_xor(t, off, 64);
    if (ok && c == 0) EW[e] = sigmoid_f(t + b2);
  }
}

// ======================= CSR build: count, scan, fill, deg ===================
__global__ void __launch_bounds__(256) count_k(
    const int* __restrict__ S, const int* __restrict__ D,
    int* __restrict__ counts, int baseD, int baseS, int E) {
  const int e = blockIdx.x * 256 + threadIdx.x;
  if (e >= E) return;
  atomicAdd(&counts[baseD + D[e]], 1);
  atomicAdd(&counts[baseS + S[e]], 1);
}

__global__ void __launch_bounds__(256) fill_binned_k(
    const int* __restrict__ S, const int* __restrict__ D,
    const float* __restrict__ EW, int* __restrict__ cursor,
    unsigned* __restrict__ adj, int baseD, int baseS, int NDrows, int NSrows,
    int E) {
  const int bin = blockIdx.x & (NBIN - 1);
  const int blk = blockIdx.x / NBIN;
  const int nblk = gridDim.x / NBIN;
  const int d_lo = (int)((long long)NDrows * bin / NBIN);
  const int d_hi = (int)((long long)NDrows * (bin + 1) / NBIN);
  const int s_lo = (int)((long long)NSrows * bin / NBIN);
  const int s_hi = (int)((long long)NSrows * (bin + 1) / NBIN);
  for (int e = blk * 256 + threadIdx.x; e < E; e += nblk * 256) {
    const int s = S[e], d = D[e];
    const bool md = (d >= d_lo) & (d < d_hi);
    const bool ms = (s >= s_lo) & (s < s_hi);
    if (md | ms) {
      const unsigned w14 = (unsigned)(EW[e] * WQ_SCALE + 0.5f);
      if (md) {
        const int p = atomicAdd(&cursor[baseD + d], 1);
        adj[p] = ((unsigned)s << 14) | w14;
      }
      if (ms) {
        const int p = atomicAdd(&cursor[baseS + s], 1);
        adj[p] = ((unsigned)d << 14) | w14;
      }
    }
  }
}

__global__ void __launch_bounds__(256) degi_k(const int* __restrict__ row_ptr,
                                             const unsigned* __restrict__ adj,
                                             float* __restrict__ degi) {
  const int r = blockIdx.x * 256 + threadIdx.x;
  if (r >= R_TOT) return;
  const int s = row_ptr[r], e = row_ptr[r + 1];
  float d = 0.0f;
  for (int p = s; p < e; ++p) d += (float)(adj[p] & 16383u) * WQ_INV;
  degi[r] = 1.0f / fmaxf(d, 1.0f);
}

__global__ void __launch_bounds__(256) scan1_k(const int* __restrict__ in,
                                               int* __restrict__ bsum) {
  __shared__ int sd[256];
  const int t = threadIdx.x;
  const int base = blockIdx.x * SCAN_CHUNK + t * 8;
  int s = 0;
#pragma unroll
  for (int i = 0; i < 8; ++i) {
    const int idx = base + i;
    s += (idx < R_TOT) ? in[idx] : 0;
  }
  sd[t] = s;
  __syncthreads();
  for (int off = 128; off > 0; off >>= 1) {
    if (t < off) sd[t] += sd[t + off];
    __syncthreads();
  }
  if (t == 0) bsum[blockIdx.x] = sd[0];
}

__global__ void __launch_bounds__(256) scan2_k(int* __restrict__ bsum,
                                               int* __restrict__ row_ptr) {
  __shared__ int sd[256];
  const int t = threadIdx.x;
  const int v = (t < SCAN_NB) ? bsum[t] : 0;
  sd[t] = v;
  __syncthreads();
  for (int off = 1; off < 256; off <<= 1) {
    const int add = (t >= off) ? sd[t - off] : 0;
    __syncthreads();
    sd[t] += add;
    __syncthreads();
  }
  if (t < SCAN_NB) bsum[t] = sd[t] - v;
  if (t == 255) row_ptr[R_TOT] = sd[255];
}

__global__ void __launch_bounds__(256) scan3_k(const int* __restrict__ in,
                                               const int* __restrict__ bsum,
                                               int* __restrict__ out) {
  __shared__ int sd[256];
  const int t = threadIdx.x;
  const int base = blockIdx.x * SCAN_CHUNK + t * 8;
  int loc[8];
  int s = 0;
#pragma unroll
  for (int i = 0; i < 8; ++i) {
    loc[i] = s;
    const int idx = base + i;
    s += (idx < R_TOT) ? in[idx] : 0;
  }
  sd[t] = s;
  __syncthreads();
  const int v = s;
  for (int off = 1; off < 256; off <<= 1) {
    const int add = (t >= off) ? sd[t - off] : 0;
    __syncthreads();
    sd[t] += add;
    __syncthreads();
  }
  const int off0 = bsum[blockIdx.x] + (sd[t] - v);
#pragma unroll
  for (int i = 0; i < 8; ++i) {
    const int idx = base + i;
    if (idx < R_TOT) out[idx] = off0 + loc[i];
  }
}

}  // namespace

extern "C" void kernel_launch(void* const* d_in, const int* in_sizes, int n_in,
                              void* d_out, int out_size, void* d_ws, size_t ws_size,
                              hipStream_t stream) {
  (void)in_sizes; (void)n_in; (void)out_size; (void)ws_size;

  const float* variable_features   = (const float*)d_in[0];
  const float* constraint_features = (const float*)d_in[1];
  const float* cut_features        = (const float*)d_in[2];
  const float* vc_ef = (const float*)d_in[3];
  const float* vk_ef = (const float*)d_in[4];
  const int* vc_edges = (const int*)d_in[5];
  const int* vk_edges = (const int*)d_in[6];
  const int *vc_s = vc_edges, *vc_d = vc_edges + EVC;
  const int *vk_s = vk_edges, *vk_d = vk_edges + EVK;
  const float* var_w1  = (const float*)d_in[7];
  const float* var_b1  = (const float*)d_in[8];
  const float* var_w2  = (const float*)d_in[9];
  const float* var_b2  = (const float*)d_in[10];
  const float* cons_w1 = (const float*)d_in[11];
  const float* cons_b1 = (const float*)d_in[12];
  const float* cons_w2 = (const float*)d_in[13];
  const float* cons_b2 = (const float*)d_in[14];
  const float* cut_w1  = (const float*)d_in[15];
  const float* cut_b1  = (const float*)d_in[16];
  const float* cut_w2  = (const float*)d_in[17];
  const float* cut_b2  = (const float*)d_in[18];
  const float* ewvc_w1 = (const float*)d_in[19];
  const float* ewvc_b1 = (const float*)d_in[20];
  const float* ewvc_w2 = (const float*)d_in[21];
  const float* ewvc_b2 = (const float*)d_in[22];
  const float* ewvk_w1 = (const float*)d_in[23];
  const float* ewvk_b1 = (const float*)d_in[24];
  const float* ewvk_w2 = (const float*)d_in[25];
  const float* ewvk_b2 = (const float*)d_in[26];
  const float* mp_msg_w1 = (const float*)d_in[27];
  const float* mp_msg_b1 = (const float*)d_in[28];
  const float* mp_msg_w2 = (const float*)d_in[29];
  const float* mp_msg_b2 = (const float*)d_in[30];
  const float* mp_gate_w = (const float*)d_in[31];
  const float* mp_gate_b = (const float*)d_in[32];
  const float* mp_upd_w1 = (const float*)d_in[33];
  const float* mp_upd_b1 = (const float*)d_in[34];
  const float* mp_upd_w2 = (const float*)d_in[35];
  const float* mp_upd_b2 = (const float*)d_in[36];
  const float* mp_ln_g   = (const float*)d_in[37];
  const float* mp_ln_b   = (const float*)d_in[38];

  // ---- workspace carve ----
  char* wp = (char*)d_ws;
  auto take = [&](size_t nbytes) {
    char* p = wp;
    wp += (nbytes + 255) & ~(size_t)255;
    return p;
  };
  unsigned short* h_var_b  = (unsigned short*)take((size_t)NV * 64 * 2);
  unsigned short* h_cons_b = (unsigned short*)take((size_t)NC * 64 * 2);
  unsigned short* h_cut_b  = (unsigned short*)take((size_t)NK * 64 * 2);
  unsigned short* msg_ping = (unsigned short*)take((size_t)NV * 64 * 2);
  unsigned short* msg_pong = (unsigned short*)take((size_t)NV * 64 * 2);
  unsigned short* pa = (unsigned short*)take((size_t)NV * 64 * 2);
  unsigned short* pb = (unsigned short*)take((size_t)NC * 64 * 2);
  unsigned short* qa = (unsigned short*)take((size_t)NV * 64 * 2);
  unsigned short* qb = (unsigned short*)take((size_t)NK * 64 * 2);
  unsigned short* packW = (unsigned short*)take((size_t)15 * PACK_PER_LAYER * 2);
  unsigned short* packE = (unsigned short*)take((size_t)PE_TOTAL * 2);
  float* ew_vc = (float*)take((size_t)EVC * 4);
  float* ew_vk = (float*)take((size_t)EVK * 4);
  int* row_ptr = (int*)take((size_t)(R_TOT + 1) * 4);
  int* cursor  = (int*)take((size_t)R_TOT * 4);
  int* counts  = (int*)take((size_t)R_TOT * 4);
  int* bsum    = (int*)take(256 * 4);
  float* degi  = (float*)take((size_t)R_TOT * 4);
  unsigned* adj = (unsigned*)take((size_t)(2 * EVC + 2 * EVK) * 4);

  // ---- CSR counts + scan ----
  hipMemsetAsync(counts, 0, (size_t)R_TOT * 4, stream);
  count_k<<<(EVC + 255) / 256, 256, 0, stream>>>(vc_s, vc_d, counts, 0, NC, EVC);
  count_k<<<(EVK + 255) / 256, 256, 0, stream>>>(vk_s, vk_d, counts, NC + NV,
                                                 NC + NV + NK, EVK);
  scan1_k<<<SCAN_NB, 256, 0, stream>>>(counts, bsum);
  scan2_k<<<1, 256, 0, stream>>>(bsum, row_ptr);
  scan3_k<<<SCAN_NB, 256, 0, stream>>>(counts, bsum, row_ptr);

  // ---- pack weights (MP layers + embeddings/edge-weight mats) ----
  pack_k<<<15, 256, 0, stream>>>(mp_msg_w1, mp_msg_w2, mp_gate_w, mp_upd_w1,
                                 mp_upd_w2, packW);
  pack_emb_k<<<10, 256, 0, stream>>>(var_w1, var_w2, cons_w1, cons_w2, cut_w1,
                                     cut_w2, ewvc_w1, ewvk_w1, packE);

  // ---- embeddings (MFMA, bf16 out) ----
  emb_mfma_k<19><<<(NV + 63) / 64, 256, 0, stream>>>(
      variable_features, packE + PE_VAR_W1, packE + PE_VAR_W2, var_b1, var_b2,
      h_var_b, NV);
  emb_mfma_k<5><<<(NC + 63) / 64, 256, 0, stream>>>(
      constraint_features, packE + PE_CONS_W1, packE + PE_CONS_W2, cons_b1,
      cons_b2, h_cons_b, NC);
  emb_mfma_k<30><<<(NK + 63) / 64, 256, 0, stream>>>(
      cut_features, packE + PE_CUT_W1, packE + PE_CUT_W2, cut_b1, cut_b2,
      h_cut_b, NK);

  // ---- edge-weight per-node terms (MFMA; var does both projections) ----
  gemv_mfma_k<2><<<(NV + 63) / 64, 256, 0, stream>>>(
      h_var_b, packE + PE_EWVC_A, packE + PE_EWVK_A, nullptr, pa, qa, NV);
  gemv_mfma_k<1><<<(NC + 63) / 64, 256, 0, stream>>>(
      h_cons_b, packE + PE_EWVC_B, nullptr, ewvc_b1, pb, nullptr, NC);
  gemv_mfma_k<1><<<(NK + 63) / 64, 256, 0, stream>>>(
      h_cut_b, packE + PE_EWVK_B, nullptr, ewvk_b1, qb, nullptr, NK);

  edgew_k<<<1024, 256, 0, stream>>>(vc_s, vc_d, vc_ef, pa, pb,
                                    ewvc_w1 + 128 * 64, ewvc_w2, ewvc_b2,
                                    ew_vc, EVC);
  edgew_k<<<512, 256, 0, stream>>>(vk_s, vk_d, vk_ef, qa, qb,
                                   ewvk_w1 + 128 * 64, ewvk_w2, ewvk_b2,
                                   ew_vk, EVK);

  // ---- CSR fill (binned, XCD-local stores) + per-row 1/deg ----
  hipMemcpyAsync(cursor, row_ptr, (size_t)R_TOT * 4, hipMemcpyDeviceToDevice, stream);
  fill_binned_k<<<NBIN * 128, 256, 0, stream>>>(vc_s, vc_d, ew_vc, cursor, adj,
                                                0, NC, NC, NV, EVC);
  fill_binned_k<<<NBIN * 64, 256, 0, stream>>>(vk_s, vk_d, ew_vk, cursor, adj,
                                               NC + NV, NC + NV + NK, NK, NV, EVK);
  degi_k<<<(R_TOT + 255) / 256, 256, 0, stream>>>(row_ptr, adj, degi);

  // ---- 15 fully-fused passes (agg + upd + next msg), msg ping-pong ----
  unsigned short* nodeb_t[4] = {h_cons_b, h_var_b, h_cut_b, h_var_b};
  const int Nd_t[4] = {NC, NV, NK, NV};
  const int base_t[4] = {0, NC, NC + NV, NC + NV + NK};

  // msg(0): over h_var with layer-0 msg weights -> ping
  msg_mfma_k<<<(NV + 63) / 64, 256, 0, stream>>>(
      h_var_b, packW, mp_msg_b1, mp_msg_b2, msg_ping, NV);

  for (int i = 0; i < 15; ++i) {
    const int d = i & 3;
    const int Nd = Nd_t[d], base = base_t[d];
    const unsigned short* Wl = packW + (size_t)i * PACK_PER_LAYER;
    const unsigned short* src = (i % 2 == 0) ? msg_ping : msg_pong;
    unsigned short* dst = (i % 2 == 0) ? msg_pong : msg_ping;

    if (i < 14) {
      const unsigned short* Wn = packW + (size_t)(i + 1) * PACK_PER_LAYER;
      pass_mfma_k<1><<<(Nd + 63) / 64, 256, 0, stream>>>(
          row_ptr, adj, degi, src, nodeb_t[d], Wl + 8192, Wl + 16384,
          Wl + 24576, mp_gate_b + (size_t)i * 64, mp_upd_b1 + (size_t)i * 64,
          mp_upd_b2 + (size_t)i * 64, mp_ln_g + (size_t)i * 64,
          mp_ln_b + (size_t)i * 64, Wn, mp_msg_b1 + (size_t)(i + 1) * 64,
          mp_msg_b2 + (size_t)(i + 1) * 64, nullptr, nodeb_t[d], dst, base, Nd);
    } else {
      pass_mfma_k<0><<<(Nd + 63) / 64, 256, 0, stream>>>(
          row_ptr, adj, degi, src, nodeb_t[d], Wl + 8192, Wl + 16384,
          Wl + 24576, mp_gate_b + (size_t)i * 64, mp_upd_b1 + (size_t)i * 64,
          mp_upd_b2 + (size_t)i * 64, mp_ln_g + (size_t)i * 64,
          mp_ln_b + (size_t)i * 64, nullptr, nullptr, nullptr,
          (float*)d_out, nullptr, nullptr, base, Nd);
    }
  }
}

// Round 11
// 928.417 us; speedup vs baseline: 5.3929x; 1.0149x over previous
//
#include <hip/hip_runtime.h>

#define DEVINL static __device__ __forceinline__

namespace {

typedef __attribute__((ext_vector_type(8))) short bf16x8;
typedef __attribute__((ext_vector_type(4))) float f32x4;

constexpr int NV = 100000;   // variables
constexpr int NC = 50000;    // constraints
constexpr int NK = 20000;    // cuts
constexpr int EVC = 800000;  // var-cons edges
constexpr int EVK = 200000;  // var-cut edges
constexpr int R_TOT = NC + NV + NK + NV;  // 270000 CSR rows
constexpr int SCAN_CHUNK = 2048;
constexpr int SCAN_NB = (R_TOT + SCAN_CHUNK - 1) / SCAN_CHUNK;  // 132
constexpr int PACK_PER_LAYER = 28672;  // ushort per layer of packed MP weights
constexpr float WQ_SCALE = 16383.0f;
constexpr float WQ_INV = 1.0f / 16383.0f;
constexpr int NBIN = 8;  // fill bins; blockIdx%8 aligns with XCD round-robin

// packed embedding/edge-weight matrix offsets (ushort)
constexpr int PE_VAR_W1 = 0;      // Kpad=32 -> 2048
constexpr int PE_VAR_W2 = 2048;   // K=64   -> 4096
constexpr int PE_CONS_W1 = 6144;  // 2048
constexpr int PE_CONS_W2 = 8192;  // 4096
constexpr int PE_CUT_W1 = 12288;  // 2048
constexpr int PE_CUT_W2 = 14336;  // 4096
constexpr int PE_EWVC_A = 18432;  // 4096
constexpr int PE_EWVC_B = 22528;  // 4096
constexpr int PE_EWVK_A = 26624;  // 4096
constexpr int PE_EWVK_B = 30720;  // 4096
constexpr int PE_TOTAL = 34816;

DEVINL unsigned short f2bf(float f) {
  unsigned u = __float_as_uint(f);
  u = u + 0x7fffu + ((u >> 16) & 1u);  // RNE
  return (unsigned short)(u >> 16);
}
DEVINL float bf2f(unsigned short h) {
  return __uint_as_float((unsigned)h << 16);
}

DEVINL float sigmoid_f(float x) { return 1.0f / (1.0f + __expf(-x)); }

// ======================= weight packing (bf16 B-frag streams) ================
DEVINL void pack_mat(const float* __restrict__ src, int K, int Kpad,
                     unsigned short* __restrict__ dst, int tid) {
  const int ntup = (Kpad / 32) * 256;
  for (int tup = tid; tup < ntup; tup += 256) {
    const int lane = tup & 63;
    const int t = (tup >> 6) & 3;
    const int kb = tup >> 8;
    const int c = t * 16 + (lane & 15);
    const int k0 = kb * 32 + (lane >> 4) * 8;
#pragma unroll
    for (int jj = 0; jj < 8; ++jj)
      dst[tup * 8 + jj] =
          (k0 + jj < K) ? f2bf(src[(k0 + jj) * 64 + c]) : (unsigned short)0;
  }
}

__global__ void __launch_bounds__(256) pack_k(
    const float* __restrict__ mW1, const float* __restrict__ mW2,
    const float* __restrict__ gW, const float* __restrict__ uW1,
    const float* __restrict__ uW2, unsigned short* __restrict__ PW) {
  const int layer = blockIdx.x;  // 0..14
  unsigned short* out = PW + (size_t)layer * PACK_PER_LAYER;
  pack_mat(mW1 + (size_t)layer * 4096, 64, 64, out, threadIdx.x);
  pack_mat(mW2 + (size_t)layer * 4096, 64, 64, out + 4096, threadIdx.x);
  pack_mat(gW + (size_t)layer * 8192, 128, 128, out + 8192, threadIdx.x);
  pack_mat(uW1 + (size_t)layer * 8192, 128, 128, out + 16384, threadIdx.x);
  pack_mat(uW2 + (size_t)layer * 4096, 64, 64, out + 24576, threadIdx.x);
}

__global__ void __launch_bounds__(256) pack_emb_k(
    const float* __restrict__ var_w1, const float* __restrict__ var_w2,
    const float* __restrict__ cons_w1, const float* __restrict__ cons_w2,
    const float* __restrict__ cut_w1, const float* __restrict__ cut_w2,
    const float* __restrict__ ewvc_w1, const float* __restrict__ ewvk_w1,
    unsigned short* __restrict__ P) {
  switch (blockIdx.x) {
    case 0: pack_mat(var_w1, 19, 32, P + PE_VAR_W1, threadIdx.x); break;
    case 1: pack_mat(var_w2, 64, 64, P + PE_VAR_W2, threadIdx.x); break;
    case 2: pack_mat(cons_w1, 5, 32, P + PE_CONS_W1, threadIdx.x); break;
    case 3: pack_mat(cons_w2, 64, 64, P + PE_CONS_W2, threadIdx.x); break;
    case 4: pack_mat(cut_w1, 30, 32, P + PE_CUT_W1, threadIdx.x); break;
    case 5: pack_mat(cut_w2, 64, 64, P + PE_CUT_W2, threadIdx.x); break;
    case 6: pack_mat(ewvc_w1, 64, 64, P + PE_EWVC_A, threadIdx.x); break;
    case 7: pack_mat(ewvc_w1 + 64 * 64, 64, 64, P + PE_EWVC_B, threadIdx.x); break;
    case 8: pack_mat(ewvk_w1, 64, 64, P + PE_EWVK_A, threadIdx.x); break;
    case 9: pack_mat(ewvk_w1 + 64 * 64, 64, 64, P + PE_EWVK_B, threadIdx.x); break;
  }
}

// ======================= embedding MLP (MFMA, K1 padded to 32) ===============
template <int DIN>
__global__ void __launch_bounds__(256) emb_mfma_k(
    const float* __restrict__ X, const unsigned short* __restrict__ W1p_,
    const unsigned short* __restrict__ W2p_, const float* __restrict__ B1,
    const float* __restrict__ B2, unsigned short* __restrict__ OUTb, int N) {
  __shared__ unsigned short lds[4][16 * 72];
  const int wave = threadIdx.x >> 6, l = threadIdx.x & 63;
  const int col = l & 15, quad = l >> 4;
  const int n0_raw = blockIdx.x * 64 + wave * 16;
  const bool dead = n0_raw >= N;
  const int n0 = dead ? 0 : n0_raw;

  bf16x8 a0;
#pragma unroll
  for (int j = 0; j < 8; ++j) {
    const int k = quad * 8 + j;
    a0[j] = (k < DIN) ? (short)f2bf(X[(size_t)(n0 + col) * DIN + k]) : (short)0;
  }
  const bf16x8* W1p = (const bf16x8*)W1p_;
  const bf16x8* W2p = (const bf16x8*)W2p_;
  f32x4 acc[4];
#pragma unroll
  for (int t = 0; t < 4; ++t) {
    const float b = B1[col + 16 * t];
    acc[t] = f32x4{b, b, b, b};
  }
#pragma unroll
  for (int t = 0; t < 4; ++t)
    acc[t] = __builtin_amdgcn_mfma_f32_16x16x32_bf16(a0, W1p[t * 64 + l], acc[t], 0, 0, 0);
  unsigned short* ld = lds[wave];
#pragma unroll
  for (int t = 0; t < 4; ++t)
#pragma unroll
    for (int r = 0; r < 4; ++r)
      ld[(quad * 4 + r) * 72 + col + 16 * t] = f2bf(fmaxf(acc[t][r], 0.0f));
  __syncthreads();
  const bf16x8 h0 = *(const bf16x8*)&ld[col * 72 + quad * 8];
  const bf16x8 h1 = *(const bf16x8*)&ld[col * 72 + 32 + quad * 8];
  f32x4 o[4];
#pragma unroll
  for (int t = 0; t < 4; ++t) {
    const float b = B2[col + 16 * t];
    o[t] = f32x4{b, b, b, b};
  }
#pragma unroll
  for (int t = 0; t < 4; ++t) {
    o[t] = __builtin_amdgcn_mfma_f32_16x16x32_bf16(h0, W2p[t * 64 + l], o[t], 0, 0, 0);
    o[t] = __builtin_amdgcn_mfma_f32_16x16x32_bf16(h1, W2p[(4 + t) * 64 + l], o[t], 0, 0, 0);
  }
  __syncthreads();
#pragma unroll
  for (int t = 0; t < 4; ++t)
#pragma unroll
    for (int r = 0; r < 4; ++r)
      ld[(quad * 4 + r) * 72 + col + 16 * t] = f2bf(o[t][r]);
  __syncthreads();
  if (!dead) {
#pragma unroll
    for (int cc = 0; cc < 2; ++cc) {
      const bf16x8 v = *(const bf16x8*)&ld[col * 72 + (quad * 2 + cc) * 8];
      *(bf16x8*)(OUTb + (size_t)(n0 + col) * 64 + (quad * 2 + cc) * 8) = v;
    }
  }
}

// ======= edge-weight per-node GEMV (MFMA); NOUT=2 shares the A-frag =========
template <int NOUT>
__global__ void __launch_bounds__(256) gemv_mfma_k(
    const unsigned short* __restrict__ Xb, const unsigned short* __restrict__ WpA_,
    const unsigned short* __restrict__ WpB_, const float* __restrict__ Bias,
    unsigned short* __restrict__ OUT0, unsigned short* __restrict__ OUT1, int N) {
  __shared__ unsigned short lds[4][16 * 72];
  const int wave = threadIdx.x >> 6, l = threadIdx.x & 63;
  const int col = l & 15, quad = l >> 4;
  const int n0_raw = blockIdx.x * 64 + wave * 16;
  const bool dead = n0_raw >= N;
  const int n0 = dead ? 0 : n0_raw;
  const unsigned short* xrow = Xb + (size_t)(n0 + col) * 64 + quad * 8;
  const bf16x8 a0 = *(const bf16x8*)xrow;
  const bf16x8 a1 = *(const bf16x8*)(xrow + 32);
  unsigned short* ld = lds[wave];
#pragma unroll
  for (int m = 0; m < NOUT; ++m) {
    const bf16x8* Wp = (const bf16x8*)(m == 0 ? WpA_ : WpB_);
    unsigned short* OUT = (m == 0) ? OUT0 : OUT1;
    f32x4 acc[4];
#pragma unroll
    for (int t = 0; t < 4; ++t) {
      const float b = (Bias != nullptr) ? Bias[col + 16 * t] : 0.0f;
      acc[t] = f32x4{b, b, b, b};
    }
#pragma unroll
    for (int t = 0; t < 4; ++t) {
      acc[t] = __builtin_amdgcn_mfma_f32_16x16x32_bf16(a0, Wp[t * 64 + l], acc[t], 0, 0, 0);
      acc[t] = __builtin_amdgcn_mfma_f32_16x16x32_bf16(a1, Wp[(4 + t) * 64 + l], acc[t], 0, 0, 0);
    }
    if (m > 0) __syncthreads();
#pragma unroll
    for (int t = 0; t < 4; ++t)
#pragma unroll
      for (int r = 0; r < 4; ++r)
        ld[(quad * 4 + r) * 72 + col + 16 * t] = f2bf(acc[t][r]);
    __syncthreads();
    if (!dead) {
#pragma unroll
      for (int cc = 0; cc < 2; ++cc) {
        const bf16x8 v = *(const bf16x8*)&ld[col * 72 + (quad * 2 + cc) * 8];
        *(bf16x8*)(OUT + (size_t)(n0 + col) * 64 + (quad * 2 + cc) * 8) = v;
      }
    }
  }
}

// ======================= message MLP (MFMA) — used once for pass 0 ===========
__global__ void __launch_bounds__(256) msg_mfma_k(
    const unsigned short* __restrict__ Xb, const unsigned short* __restrict__ Wp,
    const float* __restrict__ B1, const float* __restrict__ B2,
    unsigned short* __restrict__ MSGb, int N) {
  __shared__ unsigned short lds[4][16 * 72];
  const int wave = threadIdx.x >> 6, l = threadIdx.x & 63;
  const int col = l & 15, quad = l >> 4;
  const int n0_raw = blockIdx.x * 64 + wave * 16;
  const bool dead = n0_raw >= N;
  const int n0 = dead ? 0 : n0_raw;

  const unsigned short* xrow = Xb + (size_t)(n0 + col) * 64 + quad * 8;
  const bf16x8 a0 = *(const bf16x8*)xrow;
  const bf16x8 a1 = *(const bf16x8*)(xrow + 32);
  const bf16x8* W1p = (const bf16x8*)Wp;
  const bf16x8* W2p = (const bf16x8*)(Wp + 4096);

  f32x4 acc[4];
#pragma unroll
  for (int t = 0; t < 4; ++t) {
    const float b = B1[col + 16 * t];
    acc[t] = f32x4{b, b, b, b};
  }
#pragma unroll
  for (int t = 0; t < 4; ++t) {
    acc[t] = __builtin_amdgcn_mfma_f32_16x16x32_bf16(a0, W1p[t * 64 + l], acc[t], 0, 0, 0);
    acc[t] = __builtin_amdgcn_mfma_f32_16x16x32_bf16(a1, W1p[(4 + t) * 64 + l], acc[t], 0, 0, 0);
  }
  unsigned short* ld = lds[wave];
#pragma unroll
  for (int t = 0; t < 4; ++t)
#pragma unroll
    for (int r = 0; r < 4; ++r)
      ld[(quad * 4 + r) * 72 + col + 16 * t] = f2bf(fmaxf(acc[t][r], 0.0f));
  __syncthreads();
  const bf16x8 h0 = *(const bf16x8*)&ld[col * 72 + quad * 8];
  const bf16x8 h1 = *(const bf16x8*)&ld[col * 72 + 32 + quad * 8];
  f32x4 o[4];
#pragma unroll
  for (int t = 0; t < 4; ++t) {
    const float b = B2[col + 16 * t];
    o[t] = f32x4{b, b, b, b};
  }
#pragma unroll
  for (int t = 0; t < 4; ++t) {
    o[t] = __builtin_amdgcn_mfma_f32_16x16x32_bf16(h0, W2p[t * 64 + l], o[t], 0, 0, 0);
    o[t] = __builtin_amdgcn_mfma_f32_16x16x32_bf16(h1, W2p[(4 + t) * 64 + l], o[t], 0, 0, 0);
  }
  __syncthreads();
#pragma unroll
  for (int t = 0; t < 4; ++t)
#pragma unroll
    for (int r = 0; r < 4; ++r)
      ld[(quad * 4 + r) * 72 + col + 16 * t] = f2bf(o[t][r]);
  __syncthreads();
  if (!dead) {
#pragma unroll
    for (int cc = 0; cc < 2; ++cc) {
      const bf16x8 v = *(const bf16x8*)&ld[col * 72 + (quad * 2 + cc) * 8];
      *(bf16x8*)(MSGb + (size_t)(n0 + col) * 64 + (quad * 2 + cc) * 8) = v;
    }
  }
}

// ==== fully-fused pass: CSR-aggregate + gate/upd/mix/LN + next-layer msg =====
template <int WITH_MSG>
__global__ void __launch_bounds__(256) pass_mfma_k(
    const int* __restrict__ row_ptr, const unsigned* __restrict__ adj,
    const float* __restrict__ degi, const unsigned short* __restrict__ MSGsrc,
    const unsigned short* __restrict__ NODEb,
    const unsigned short* __restrict__ gWp, const unsigned short* __restrict__ uW1p,
    const unsigned short* __restrict__ uW2p, const float* __restrict__ gB,
    const float* __restrict__ uB1, const float* __restrict__ uB2,
    const float* __restrict__ LNG, const float* __restrict__ LNB,
    const unsigned short* __restrict__ mWp,  // next layer msg W1|W2 (packed)
    const float* __restrict__ mB1, const float* __restrict__ mB2,
    float* __restrict__ OUTf, unsigned short* __restrict__ OUTb,
    unsigned short* __restrict__ MSGdst, int base, int N) {
  __shared__ unsigned short lds[4][16 * 72];
  const int wave = threadIdx.x >> 6, l = threadIdx.x & 63;
  const int col = l & 15, quad = l >> 4;
  const int n0_raw = blockIdx.x * 64 + wave * 16;
  const bool dead = n0_raw >= N;
  const int n0 = dead ? 0 : n0_raw;

  // ---- phase 1: aggregate (in-register A-frag build) ----
  const int r = base + n0 + col;
  const int ps = row_ptr[r], pe = row_ptr[r + 1];
  float acc0[8], acc1[8];
#pragma unroll
  for (int j = 0; j < 8; ++j) { acc0[j] = 0.0f; acc1[j] = 0.0f; }
  int p = ps;
  for (; p + 2 <= pe; p += 2) {  // x2 unroll for load ILP
    const unsigned avA = adj[p], avB = adj[p + 1];
    const unsigned short* mA = MSGsrc + (size_t)(avA >> 14) * 64 + quad * 8;
    const unsigned short* mB = MSGsrc + (size_t)(avB >> 14) * 64 + quad * 8;
    const bf16x8 mA0 = *(const bf16x8*)mA;
    const bf16x8 mA1 = *(const bf16x8*)(mA + 32);
    const bf16x8 mB0 = *(const bf16x8*)mB;
    const bf16x8 mB1v = *(const bf16x8*)(mB + 32);
    const float wA = (float)(avA & 16383u) * WQ_INV;
    const float wB = (float)(avB & 16383u) * WQ_INV;
    const unsigned* uA0 = (const unsigned*)&mA0;
    const unsigned* uA1 = (const unsigned*)&mA1;
    const unsigned* uB0 = (const unsigned*)&mB0;
    const unsigned* uB1v = (const unsigned*)&mB1v;
#pragma unroll
    for (int q = 0; q < 4; ++q) {
      acc0[2 * q] = fmaf(__uint_as_float(uA0[q] << 16), wA, acc0[2 * q]);
      acc0[2 * q + 1] = fmaf(__uint_as_float(uA0[q] & 0xffff0000u), wA, acc0[2 * q + 1]);
      acc1[2 * q] = fmaf(__uint_as_float(uA1[q] << 16), wA, acc1[2 * q]);
      acc1[2 * q + 1] = fmaf(__uint_as_float(uA1[q] & 0xffff0000u), wA, acc1[2 * q + 1]);
      acc0[2 * q] = fmaf(__uint_as_float(uB0[q] << 16), wB, acc0[2 * q]);
      acc0[2 * q + 1] = fmaf(__uint_as_float(uB0[q] & 0xffff0000u), wB, acc0[2 * q + 1]);
      acc1[2 * q] = fmaf(__uint_as_float(uB1v[q] << 16), wB, acc1[2 * q]);
      acc1[2 * q + 1] = fmaf(__uint_as_float(uB1v[q] & 0xffff0000u), wB, acc1[2 * q + 1]);
    }
  }
  if (p < pe) {
    const unsigned av = adj[p];
    const unsigned short* m = MSGsrc + (size_t)(av >> 14) * 64 + quad * 8;
    const bf16x8 m0 = *(const bf16x8*)m;
    const bf16x8 m1 = *(const bf16x8*)(m + 32);
    const float w = (float)(av & 16383u) * WQ_INV;
    const unsigned* u0 = (const unsigned*)&m0;
    const unsigned* u1 = (const unsigned*)&m1;
#pragma unroll
    for (int q = 0; q < 4; ++q) {
      acc0[2 * q] = fmaf(__uint_as_float(u0[q] << 16), w, acc0[2 * q]);
      acc0[2 * q + 1] = fmaf(__uint_as_float(u0[q] & 0xffff0000u), w, acc0[2 * q + 1]);
      acc1[2 * q] = fmaf(__uint_as_float(u1[q] << 16), w, acc1[2 * q]);
      acc1[2 * q + 1] = fmaf(__uint_as_float(u1[q] & 0xffff0000u), w, acc1[2 * q + 1]);
    }
  }
  const float di = degi[r];
  bf16x8 aA0, aA1;
#pragma unroll
  for (int j = 0; j < 8; ++j) {
    aA0[j] = (short)f2bf(acc0[j] * di);
    aA1[j] = (short)f2bf(acc1[j] * di);
  }

  // ---- phase 2: gate + upd1 (MFMA) ----
  const unsigned short* nrow = NODEb + (size_t)(n0 + col) * 64 + quad * 8;
  const bf16x8 aN0 = *(const bf16x8*)nrow;
  const bf16x8 aN1 = *(const bf16x8*)(nrow + 32);
  const bf16x8* gW = (const bf16x8*)gWp;
  const bf16x8* uW1 = (const bf16x8*)uW1p;
  const bf16x8* uW2 = (const bf16x8*)uW2p;

  f32x4 g[4], u[4];
#pragma unroll
  for (int t = 0; t < 4; ++t) {
    const float bg = gB[col + 16 * t], bu = uB1[col + 16 * t];
    g[t] = f32x4{bg, bg, bg, bg};
    u[t] = f32x4{bu, bu, bu, bu};
  }
#pragma unroll
  for (int t = 0; t < 4; ++t) {
    g[t] = __builtin_amdgcn_mfma_f32_16x16x32_bf16(aA0, gW[t * 64 + l], g[t], 0, 0, 0);
    g[t] = __builtin_amdgcn_mfma_f32_16x16x32_bf16(aA1, gW[(4 + t) * 64 + l], g[t], 0, 0, 0);
    g[t] = __builtin_amdgcn_mfma_f32_16x16x32_bf16(aN0, gW[(8 + t) * 64 + l], g[t], 0, 0, 0);
    g[t] = __builtin_amdgcn_mfma_f32_16x16x32_bf16(aN1, gW[(12 + t) * 64 + l], g[t], 0, 0, 0);
    u[t] = __builtin_amdgcn_mfma_f32_16x16x32_bf16(aA0, uW1[t * 64 + l], u[t], 0, 0, 0);
    u[t] = __builtin_amdgcn_mfma_f32_16x16x32_bf16(aA1, uW1[(4 + t) * 64 + l], u[t], 0, 0, 0);
    u[t] = __builtin_amdgcn_mfma_f32_16x16x32_bf16(aN0, uW1[(8 + t) * 64 + l], u[t], 0, 0, 0);
    u[t] = __builtin_amdgcn_mfma_f32_16x16x32_bf16(aN1, uW1[(12 + t) * 64 + l], u[t], 0, 0, 0);
  }
#pragma unroll
  for (int t = 0; t < 4; ++t)
#pragma unroll
    for (int r2 = 0; r2 < 4; ++r2) g[t][r2] = sigmoid_f(g[t][r2]);

  unsigned short* ld = lds[wave];
#pragma unroll
  for (int t = 0; t < 4; ++t)
#pragma unroll
    for (int r2 = 0; r2 < 4; ++r2)
      ld[(quad * 4 + r2) * 72 + col + 16 * t] = f2bf(fmaxf(u[t][r2], 0.0f));
  __syncthreads();
  const bf16x8 h0 = *(const bf16x8*)&ld[col * 72 + quad * 8];
  const bf16x8 h1 = *(const bf16x8*)&ld[col * 72 + 32 + quad * 8];
  f32x4 o[4];
#pragma unroll
  for (int t = 0; t < 4; ++t) {
    const float b = uB2[col + 16 * t];
    o[t] = f32x4{b, b, b, b};
  }
#pragma unroll
  for (int t = 0; t < 4; ++t) {
    o[t] = __builtin_amdgcn_mfma_f32_16x16x32_bf16(h0, uW2[t * 64 + l], o[t], 0, 0, 0);
    o[t] = __builtin_amdgcn_mfma_f32_16x16x32_bf16(h1, uW2[(4 + t) * 64 + l], o[t], 0, 0, 0);
  }
  // gate mix (bf16 node carry, C-layout gather) + LayerNorm
  float om[4][4];
#pragma unroll
  for (int t = 0; t < 4; ++t)
#pragma unroll
    for (int r2 = 0; r2 < 4; ++r2) {
      const float nd =
          bf2f(NODEb[(size_t)(n0 + quad * 4 + r2) * 64 + col + 16 * t]);
      om[t][r2] = fmaf(g[t][r2], o[t][r2] - nd, nd);
    }
  float outv[4][4];
#pragma unroll
  for (int r2 = 0; r2 < 4; ++r2) {
    float s1 = (om[0][r2] + om[1][r2]) + (om[2][r2] + om[3][r2]);
    float s2 = fmaf(om[0][r2], om[0][r2], fmaf(om[1][r2], om[1][r2],
                fmaf(om[2][r2], om[2][r2], om[3][r2] * om[3][r2])));
#pragma unroll
    for (int off = 1; off < 16; off <<= 1) {
      s1 += __shfl_xor(s1, off, 64);
      s2 += __shfl_xor(s2, off, 64);
    }
    const float m = s1 * (1.0f / 64.0f);
    const float var = s2 * (1.0f / 64.0f) - m * m;
    const float rr = rsqrtf(var + 1e-3f);
#pragma unroll
    for (int t = 0; t < 4; ++t)
      outv[t][r2] = fmaf((om[t][r2] - m) * rr, LNG[col + 16 * t], LNB[col + 16 * t]);
  }
  if (OUTf != nullptr && !dead) {
#pragma unroll
    for (int t = 0; t < 4; ++t)
#pragma unroll
      for (int r2 = 0; r2 < 4; ++r2)
        OUTf[(size_t)(n0 + quad * 4 + r2) * 64 + col + 16 * t] = outv[t][r2];
  }
  __syncthreads();
#pragma unroll
  for (int t = 0; t < 4; ++t)
#pragma unroll
    for (int r2 = 0; r2 < 4; ++r2)
      ld[(quad * 4 + r2) * 72 + col + 16 * t] = f2bf(outv[t][r2]);
  __syncthreads();
  if (OUTb != nullptr && !dead) {
#pragma unroll
    for (int cc = 0; cc < 2; ++cc) {
      const bf16x8 v = *(const bf16x8*)&ld[col * 72 + (quad * 2 + cc) * 8];
      *(bf16x8*)(OUTb + (size_t)(n0 + col) * 64 + (quad * 2 + cc) * 8) = v;
    }
  }

  if constexpr (WITH_MSG) {
    // ---- phase 3: next layer's message MLP on the just-updated rows ----
    const bf16x8 x0 = *(const bf16x8*)&ld[col * 72 + quad * 8];
    const bf16x8 x1 = *(const bf16x8*)&ld[col * 72 + 32 + quad * 8];
    const bf16x8* W1p = (const bf16x8*)mWp;
    const bf16x8* W2p = (const bf16x8*)(mWp + 4096);
    f32x4 macc[4];
#pragma unroll
    for (int t = 0; t < 4; ++t) {
      const float b = mB1[col + 16 * t];
      macc[t] = f32x4{b, b, b, b};
    }
#pragma unroll
    for (int t = 0; t < 4; ++t) {
      macc[t] = __builtin_amdgcn_mfma_f32_16x16x32_bf16(x0, W1p[t * 64 + l], macc[t], 0, 0, 0);
      macc[t] = __builtin_amdgcn_mfma_f32_16x16x32_bf16(x1, W1p[(4 + t) * 64 + l], macc[t], 0, 0, 0);
    }
    __syncthreads();
#pragma unroll
    for (int t = 0; t < 4; ++t)
#pragma unroll
      for (int r2 = 0; r2 < 4; ++r2)
        ld[(quad * 4 + r2) * 72 + col + 16 * t] = f2bf(fmaxf(macc[t][r2], 0.0f));
    __syncthreads();
    const bf16x8 mh0 = *(const bf16x8*)&ld[col * 72 + quad * 8];
    const bf16x8 mh1 = *(const bf16x8*)&ld[col * 72 + 32 + quad * 8];
    f32x4 mo[4];
#pragma unroll
    for (int t = 0; t < 4; ++t) {
      const float b = mB2[col + 16 * t];
      mo[t] = f32x4{b, b, b, b};
    }
#pragma unroll
    for (int t = 0; t < 4; ++t) {
      mo[t] = __builtin_amdgcn_mfma_f32_16x16x32_bf16(mh0, W2p[t * 64 + l], mo[t], 0, 0, 0);
      mo[t] = __builtin_amdgcn_mfma_f32_16x16x32_bf16(mh1, W2p[(4 + t) * 64 + l], mo[t], 0, 0, 0);
    }
    __syncthreads();
#pragma unroll
    for (int t = 0; t < 4; ++t)
#pragma unroll
      for (int r2 = 0; r2 < 4; ++r2)
        ld[(quad * 4 + r2) * 72 + col + 16 * t] = f2bf(mo[t][r2]);
    __syncthreads();
    if (!dead) {
#pragma unroll
      for (int cc = 0; cc < 2; ++cc) {
        const bf16x8 v = *(const bf16x8*)&ld[col * 72 + (quad * 2 + cc) * 8];
        *(bf16x8*)(MSGdst + (size_t)(n0 + col) * 64 + (quad * 2 + cc) * 8) = v;
      }
    }
  }
}

// ===== edge weight (+ fused CSR degree count): 8 edges x 8 chunks per wave ===
// Streams (S, D, EFX) are nontemporal so they don't evict PA/PB gather lines.
__global__ void __launch_bounds__(256) edgew_k(
    const int* __restrict__ S, const int* __restrict__ D,
    const float* __restrict__ EFX, const unsigned short* __restrict__ PA,
    const unsigned short* __restrict__ PB, const float* __restrict__ W1C,
    const float* __restrict__ W2, const float* __restrict__ B2,
    float* __restrict__ EW, int* __restrict__ counts, int baseD, int baseS,
    int E) {
  const int l = threadIdx.x & 63;
  const int g = l >> 3, c = l & 7;
  float wc[8][8];
#pragma unroll
  for (int i = 0; i < 8; ++i) {
    const float4 v0 = *(const float4*)(W1C + i * 64 + c * 8);
    const float4 v1 = *(const float4*)(W1C + i * 64 + c * 8 + 4);
    wc[i][0] = v0.x; wc[i][1] = v0.y; wc[i][2] = v0.z; wc[i][3] = v0.w;
    wc[i][4] = v1.x; wc[i][5] = v1.y; wc[i][6] = v1.z; wc[i][7] = v1.w;
  }
  float w2c[8];
  {
    const float4 a0 = *(const float4*)(W2 + c * 8);
    const float4 a1 = *(const float4*)(W2 + c * 8 + 4);
    w2c[0] = a0.x; w2c[1] = a0.y; w2c[2] = a0.z; w2c[3] = a0.w;
    w2c[4] = a1.x; w2c[5] = a1.y; w2c[6] = a1.z; w2c[7] = a1.w;
  }
  const float b2 = B2[0];
  const int wave_id = blockIdx.x * 4 + (threadIdx.x >> 6);
  const int nwaves = gridDim.x * 4;
  for (int t0 = wave_id * 8; t0 < E; t0 += nwaves * 8) {
    const int e = t0 + g;
    const bool ok = e < E;
    const int ee = ok ? e : E - 1;
    const int s = __builtin_nontemporal_load(S + ee);
    const int d = __builtin_nontemporal_load(D + ee);
    const bf16x8 pa = *(const bf16x8*)(PA + (size_t)s * 64 + c * 8);
    const bf16x8 pb = *(const bf16x8*)(PB + (size_t)d * 64 + c * 8);
    const f32x4 ef0 =
        __builtin_nontemporal_load((const f32x4*)(EFX + (size_t)ee * 8));
    const f32x4 ef1 =
        __builtin_nontemporal_load((const f32x4*)(EFX + (size_t)ee * 8 + 4));
    const unsigned* pau = (const unsigned*)&pa;
    const unsigned* pbu = (const unsigned*)&pb;
    float h[8];
#pragma unroll
    for (int q = 0; q < 4; ++q) {
      h[2 * q] = __uint_as_float(pau[q] << 16) + __uint_as_float(pbu[q] << 16);
      h[2 * q + 1] = __uint_as_float(pau[q] & 0xffff0000u) +
                     __uint_as_float(pbu[q] & 0xffff0000u);
    }
    const float ef[8] = {ef0[0], ef0[1], ef0[2], ef0[3],
                         ef1[0], ef1[1], ef1[2], ef1[3]};
#pragma unroll
    for (int i = 0; i < 8; ++i)
#pragma unroll
      for (int j = 0; j < 8; ++j) h[j] = fmaf(ef[i], wc[i][j], h[j]);
    float t = 0.0f;
#pragma unroll
    for (int j = 0; j < 8; ++j) t = fmaf(fmaxf(h[j], 0.0f), w2c[j], t);
#pragma unroll
    for (int off = 1; off < 8; off <<= 1) t += __shfl_xor(t, off, 64);
    if (ok && c == 0) {
      EW[e] = sigmoid_f(t + b2);
      atomicAdd(&counts[baseD + d], 1);  // fused CSR degree count
      atomicAdd(&counts[baseS + s], 1);
    }
  }
}

// ======================= CSR build: fill (binned, nt streams), deg ===========
__global__ void __launch_bounds__(256) fill_binned_k(
    const int* __restrict__ S, const int* __restrict__ D,
    const float* __restrict__ EW, int* __restrict__ cursor,
    unsigned* __restrict__ adj, int baseD, int baseS, int NDrows, int NSrows,
    int E) {
  const int bin = blockIdx.x & (NBIN - 1);
  const int blk = blockIdx.x / NBIN;
  const int nblk = gridDim.x / NBIN;
  const int d_lo = (int)((long long)NDrows * bin / NBIN);
  const int d_hi = (int)((long long)NDrows * (bin + 1) / NBIN);
  const int s_lo = (int)((long long)NSrows * bin / NBIN);
  const int s_hi = (int)((long long)NSrows * (bin + 1) / NBIN);
  for (int e = blk * 256 + threadIdx.x; e < E; e += nblk * 256) {
    const int s = __builtin_nontemporal_load(S + e);
    const int d = __builtin_nontemporal_load(D + e);
    const bool md = (d >= d_lo) & (d < d_hi);
    const bool ms = (s >= s_lo) & (s < s_hi);
    if (md | ms) {
      const float w = __builtin_nontemporal_load(EW + e);
      const unsigned w14 = (unsigned)(w * WQ_SCALE + 0.5f);
      if (md) {
        const int p = atomicAdd(&cursor[baseD + d], 1);
        adj[p] = ((unsigned)s << 14) | w14;
      }
      if (ms) {
        const int p = atomicAdd(&cursor[baseS + s], 1);
        adj[p] = ((unsigned)d << 14) | w14;
      }
    }
  }
}

__global__ void __launch_bounds__(256) degi_k(const int* __restrict__ row_ptr,
                                             const unsigned* __restrict__ adj,
                                             float* __restrict__ degi) {
  const int r = blockIdx.x * 256 + threadIdx.x;
  if (r >= R_TOT) return;
  const int s = row_ptr[r], e = row_ptr[r + 1];
  float d = 0.0f;
  for (int p = s; p < e; ++p) d += (float)(adj[p] & 16383u) * WQ_INV;
  degi[r] = 1.0f / fmaxf(d, 1.0f);
}

__global__ void __launch_bounds__(256) scan1_k(const int* __restrict__ in,
                                               int* __restrict__ bsum) {
  __shared__ int sd[256];
  const int t = threadIdx.x;
  const int base = blockIdx.x * SCAN_CHUNK + t * 8;
  int s = 0;
#pragma unroll
  for (int i = 0; i < 8; ++i) {
    const int idx = base + i;
    s += (idx < R_TOT) ? in[idx] : 0;
  }
  sd[t] = s;
  __syncthreads();
  for (int off = 128; off > 0; off >>= 1) {
    if (t < off) sd[t] += sd[t + off];
    __syncthreads();
  }
  if (t == 0) bsum[blockIdx.x] = sd[0];
}

__global__ void __launch_bounds__(256) scan2_k(int* __restrict__ bsum,
                                               int* __restrict__ row_ptr) {
  __shared__ int sd[256];
  const int t = threadIdx.x;
  const int v = (t < SCAN_NB) ? bsum[t] : 0;
  sd[t] = v;
  __syncthreads();
  for (int off = 1; off < 256; off <<= 1) {
    const int add = (t >= off) ? sd[t - off] : 0;
    __syncthreads();
    sd[t] += add;
    __syncthreads();
  }
  if (t < SCAN_NB) bsum[t] = sd[t] - v;
  if (t == 255) row_ptr[R_TOT] = sd[255];
}

__global__ void __launch_bounds__(256) scan3_k(const int* __restrict__ in,
                                               const int* __restrict__ bsum,
                                               int* __restrict__ out) {
  __shared__ int sd[256];
  const int t = threadIdx.x;
  const int base = blockIdx.x * SCAN_CHUNK + t * 8;
  int loc[8];
  int s = 0;
#pragma unroll
  for (int i = 0; i < 8; ++i) {
    loc[i] = s;
    const int idx = base + i;
    s += (idx < R_TOT) ? in[idx] : 0;
  }
  sd[t] = s;
  __syncthreads();
  const int v = s;
  for (int off = 1; off < 256; off <<= 1) {
    const int add = (t >= off) ? sd[t - off] : 0;
    __syncthreads();
    sd[t] += add;
    __syncthreads();
  }
  const int off0 = bsum[blockIdx.x] + (sd[t] - v);
#pragma unroll
  for (int i = 0; i < 8; ++i) {
    const int idx = base + i;
    if (idx < R_TOT) out[idx] = off0 + loc[i];
  }
}

}  // namespace

extern "C" void kernel_launch(void* const* d_in, const int* in_sizes, int n_in,
                              void* d_out, int out_size, void* d_ws, size_t ws_size,
                              hipStream_t stream) {
  (void)in_sizes; (void)n_in; (void)out_size; (void)ws_size;

  const float* variable_features   = (const float*)d_in[0];
  const float* constraint_features = (const float*)d_in[1];
  const float* cut_features        = (const float*)d_in[2];
  const float* vc_ef = (const float*)d_in[3];
  const float* vk_ef = (const float*)d_in[4];
  const int* vc_edges = (const int*)d_in[5];
  const int* vk_edges = (const int*)d_in[6];
  const int *vc_s = vc_edges, *vc_d = vc_edges + EVC;
  const int *vk_s = vk_edges, *vk_d = vk_edges + EVK;
  const float* var_w1  = (const float*)d_in[7];
  const float* var_b1  = (const float*)d_in[8];
  const float* var_w2  = (const float*)d_in[9];
  const float* var_b2  = (const float*)d_in[10];
  const float* cons_w1 = (const float*)d_in[11];
  const float* cons_b1 = (const float*)d_in[12];
  const float* cons_w2 = (const float*)d_in[13];
  const float* cons_b2 = (const float*)d_in[14];
  const float* cut_w1  = (const float*)d_in[15];
  const float* cut_b1  = (const float*)d_in[16];
  const float* cut_w2  = (const float*)d_in[17];
  const float* cut_b2  = (const float*)d_in[18];
  const float* ewvc_w1 = (const float*)d_in[19];
  const float* ewvc_b1 = (const float*)d_in[20];
  const float* ewvc_w2 = (const float*)d_in[21];
  const float* ewvc_b2 = (const float*)d_in[22];
  const float* ewvk_w1 = (const float*)d_in[23];
  const float* ewvk_b1 = (const float*)d_in[24];
  const float* ewvk_w2 = (const float*)d_in[25];
  const float* ewvk_b2 = (const float*)d_in[26];
  const float* mp_msg_w1 = (const float*)d_in[27];
  const float* mp_msg_b1 = (const float*)d_in[28];
  const float* mp_msg_w2 = (const float*)d_in[29];
  const float* mp_msg_b2 = (const float*)d_in[30];
  const float* mp_gate_w = (const float*)d_in[31];
  const float* mp_gate_b = (const float*)d_in[32];
  const float* mp_upd_w1 = (const float*)d_in[33];
  const float* mp_upd_b1 = (const float*)d_in[34];
  const float* mp_upd_w2 = (const float*)d_in[35];
  const float* mp_upd_b2 = (const float*)d_in[36];
  const float* mp_ln_g   = (const float*)d_in[37];
  const float* mp_ln_b   = (const float*)d_in[38];

  // ---- workspace carve ----
  char* wp = (char*)d_ws;
  auto take = [&](size_t nbytes) {
    char* p = wp;
    wp += (nbytes + 255) & ~(size_t)255;
    return p;
  };
  unsigned short* h_var_b  = (unsigned short*)take((size_t)NV * 64 * 2);
  unsigned short* h_cons_b = (unsigned short*)take((size_t)NC * 64 * 2);
  unsigned short* h_cut_b  = (unsigned short*)take((size_t)NK * 64 * 2);
  unsigned short* msg_ping = (unsigned short*)take((size_t)NV * 64 * 2);
  unsigned short* msg_pong = (unsigned short*)take((size_t)NV * 64 * 2);
  unsigned short* pa = (unsigned short*)take((size_t)NV * 64 * 2);
  unsigned short* pb = (unsigned short*)take((size_t)NC * 64 * 2);
  unsigned short* qa = (unsigned short*)take((size_t)NV * 64 * 2);
  unsigned short* qb = (unsigned short*)take((size_t)NK * 64 * 2);
  unsigned short* packW = (unsigned short*)take((size_t)15 * PACK_PER_LAYER * 2);
  unsigned short* packE = (unsigned short*)take((size_t)PE_TOTAL * 2);
  float* ew_vc = (float*)take((size_t)EVC * 4);
  float* ew_vk = (float*)take((size_t)EVK * 4);
  int* row_ptr = (int*)take((size_t)(R_TOT + 1) * 4);
  int* cursor  = (int*)take((size_t)R_TOT * 4);
  int* counts  = (int*)take((size_t)R_TOT * 4);
  int* bsum    = (int*)take(256 * 4);
  float* degi  = (float*)take((size_t)R_TOT * 4);
  unsigned* adj = (unsigned*)take((size_t)(2 * EVC + 2 * EVK) * 4);

  // ---- init counts (filled during edgew) ----
  hipMemsetAsync(counts, 0, (size_t)R_TOT * 4, stream);

  // ---- pack weights (MP layers + embeddings/edge-weight mats) ----
  pack_k<<<15, 256, 0, stream>>>(mp_msg_w1, mp_msg_w2, mp_gate_w, mp_upd_w1,
                                 mp_upd_w2, packW);
  pack_emb_k<<<10, 256, 0, stream>>>(var_w1, var_w2, cons_w1, cons_w2, cut_w1,
                                     cut_w2, ewvc_w1, ewvk_w1, packE);

  // ---- embeddings (MFMA, bf16 out) ----
  emb_mfma_k<19><<<(NV + 63) / 64, 256, 0, stream>>>(
      variable_features, packE + PE_VAR_W1, packE + PE_VAR_W2, var_b1, var_b2,
      h_var_b, NV);
  emb_mfma_k<5><<<(NC + 63) / 64, 256, 0, stream>>>(
      constraint_features, packE + PE_CONS_W1, packE + PE_CONS_W2, cons_b1,
      cons_b2, h_cons_b, NC);
  emb_mfma_k<30><<<(NK + 63) / 64, 256, 0, stream>>>(
      cut_features, packE + PE_CUT_W1, packE + PE_CUT_W2, cut_b1, cut_b2,
      h_cut_b, NK);

  // ---- edge-weight per-node terms (MFMA; var does both projections) ----
  gemv_mfma_k<2><<<(NV + 63) / 64, 256, 0, stream>>>(
      h_var_b, packE + PE_EWVC_A, packE + PE_EWVK_A, nullptr, pa, qa, NV);
  gemv_mfma_k<1><<<(NC + 63) / 64, 256, 0, stream>>>(
      h_cons_b, packE + PE_EWVC_B, nullptr, ewvc_b1, pb, nullptr, NC);
  gemv_mfma_k<1><<<(NK + 63) / 64, 256, 0, stream>>>(
      h_cut_b, packE + PE_EWVK_B, nullptr, ewvk_b1, qb, nullptr, NK);

  // ---- edge weights + fused degree counting ----
  edgew_k<<<1024, 256, 0, stream>>>(vc_s, vc_d, vc_ef, pa, pb,
                                    ewvc_w1 + 128 * 64, ewvc_w2, ewvc_b2,
                                    ew_vc, counts, 0, NC, EVC);
  edgew_k<<<512, 256, 0, stream>>>(vk_s, vk_d, vk_ef, qa, qb,
                                   ewvk_w1 + 128 * 64, ewvk_w2, ewvk_b2,
                                   ew_vk, counts, NC + NV, NC + NV + NK, EVK);

  // ---- CSR scan + fill (binned, XCD-local stores, nt streams) + 1/deg ----
  scan1_k<<<SCAN_NB, 256, 0, stream>>>(counts, bsum);
  scan2_k<<<1, 256, 0, stream>>>(bsum, row_ptr);
  scan3_k<<<SCAN_NB, 256, 0, stream>>>(counts, bsum, row_ptr);
  hipMemcpyAsync(cursor, row_ptr, (size_t)R_TOT * 4, hipMemcpyDeviceToDevice, stream);
  fill_binned_k<<<NBIN * 128, 256, 0, stream>>>(vc_s, vc_d, ew_vc, cursor, adj,
                                                0, NC, NC, NV, EVC);
  fill_binned_k<<<NBIN * 64, 256, 0, stream>>>(vk_s, vk_d, ew_vk, cursor, adj,
                                               NC + NV, NC + NV + NK, NK, NV, EVK);
  degi_k<<<(R_TOT + 255) / 256, 256, 0, stream>>>(row_ptr, adj, degi);

  // ---- 15 fully-fused passes (agg + upd + next msg), msg ping-pong ----
  unsigned short* nodeb_t[4] = {h_cons_b, h_var_b, h_cut_b, h_var_b};
  const int Nd_t[4] = {NC, NV, NK, NV};
  const int base_t[4] = {0, NC, NC + NV, NC + NV + NK};

  // msg(0): over h_var with layer-0 msg weights -> ping
  msg_mfma_k<<<(NV + 63) / 64, 256, 0, stream>>>(
      h_var_b, packW, mp_msg_b1, mp_msg_b2, msg_ping, NV);

  for (int i = 0; i < 15; ++i) {
    const int d = i & 3;
    const int Nd = Nd_t[d], base = base_t[d];
    const unsigned short* Wl = packW + (size_t)i * PACK_PER_LAYER;
    const unsigned short* src = (i % 2 == 0) ? msg_ping : msg_pong;
    unsigned short* dst = (i % 2 == 0) ? msg_pong : msg_ping;

    if (i < 14) {
      const unsigned short* Wn = packW + (size_t)(i + 1) * PACK_PER_LAYER;
      pass_mfma_k<1><<<(Nd + 63) / 64, 256, 0, stream>>>(
          row_ptr, adj, degi, src, nodeb_t[d], Wl + 8192, Wl + 16384,
          Wl + 24576, mp_gate_b + (size_t)i * 64, mp_upd_b1 + (size_t)i * 64,
          mp_upd_b2 + (size_t)i * 64, mp_ln_g + (size_t)i * 64,
          mp_ln_b + (size_t)i * 64, Wn, mp_msg_b1 + (size_t)(i + 1) * 64,
          mp_msg_b2 + (size_t)(i + 1) * 64, nullptr, nodeb_t[d], dst, base, Nd);
    } else {
      pass_mfma_k<0><<<(Nd + 63) / 64, 256, 0, stream>>>(
          row_ptr, adj, degi, src, nodeb_t[d], Wl + 8192, Wl + 16384,
          Wl + 24576, mp_gate_b + (size_t)i * 64, mp_upd_b1 + (size_t)i * 64,
          mp_upd_b2 + (size_t)i * 64, mp_ln_g + (size_t)i * 64,
          mp_ln_b + (size_t)i * 64, nullptr, nullptr, nullptr,
          (float*)d_out, nullptr, nullptr, base, Nd);
    }
  }
}